// Round 10
// baseline (426.823 us; speedup 1.0000x reference)
//
#include <hip/hip_runtime.h>
#include <hip/hip_bf16.h>
#include <math.h>

#define N_NODES 10000
#define N_EDGES 64000
#define H 128
#define L 8
#define NL (N_NODES * L)

typedef __attribute__((ext_vector_type(4))) float f32x4;
typedef __attribute__((ext_vector_type(8))) __bf16 bf16x8;

__device__ __forceinline__ float silu_f(float x) { return x / (1.f + __expf(-x)); }

// ---------------- LayerNorm: one wave per node ----------------
__global__ __launch_bounds__(256) void ln_kernel(const float* __restrict__ x,
                                                 const float* __restrict__ g,
                                                 const float* __restrict__ b,
                                                 float* __restrict__ out, int n_nodes) {
  int wave = threadIdx.x >> 6;
  int lane = threadIdx.x & 63;
  int n = blockIdx.x * 4 + wave;
  if (n >= n_nodes) return;
  const float* xr = x + (size_t)n * H;
  float a0 = xr[lane], a1 = xr[lane + 64];
  float s = a0 + a1;
#pragma unroll
  for (int off = 32; off >= 1; off >>= 1) s += __shfl_xor(s, off, 64);
  float mu = s * (1.f / H);
  float d0 = a0 - mu, d1 = a1 - mu;
  float v = d0 * d0 + d1 * d1;
#pragma unroll
  for (int off = 32; off >= 1; off >>= 1) v += __shfl_xor(v, off, 64);
  float rstd = rsqrtf(v * (1.f / H) + 1e-5f);
  float* orow = out + (size_t)n * H;
  orow[lane] = d0 * rstd * g[lane] + b[lane];
  orow[lane + 64] = d1 * rstd * g[lane + 64] + b[lane + 64];
}

// ---------------- vecw = vec * vln_w  -> bf16 ----------------
__global__ __launch_bounds__(256) void vecw_kernel(const float* __restrict__ vec,
                                                   const float* __restrict__ w,
                                                   __bf16* __restrict__ out, size_t total8) {
  size_t i = (size_t)blockIdx.x * blockDim.x + threadIdx.x;
  size_t stride = (size_t)gridDim.x * blockDim.x;
  for (; i < total8; i += stride) {
    size_t base = i * 8;
    f32x4 a = *(const f32x4*)(vec + base);
    f32x4 b = *(const f32x4*)(vec + base + 4);
    int c = (int)(base & 127);
    bf16x8 h;
    h[0] = (__bf16)(a[0] * w[c + 0]); h[1] = (__bf16)(a[1] * w[c + 1]);
    h[2] = (__bf16)(a[2] * w[c + 2]); h[3] = (__bf16)(a[3] * w[c + 3]);
    h[4] = (__bf16)(b[0] * w[c + 4]); h[5] = (__bf16)(b[1] * w[c + 5]);
    h[6] = (__bf16)(b[2] * w[c + 6]); h[7] = (__bf16)(b[3] * w[c + 7]);
    *(bf16x8*)(out + base) = h;
  }
}

// ---------------- weight convert into one [2048][128] bf16 table ----------------
// col map: [0,384) Wvec | [384,512) Wtrg | [512,640) Wsrc | [640,768) Wq | [768,896) Wk
//          | [896,1024) Wv | [1024,1152) Wdk | [1152,1280) Wdv | [1280,1408) Wf
//          | [1408,1664) Ws | [1664,2048) Wo
__global__ __launch_bounds__(256) void wconv_kernel(
    const float* __restrict__ Wvec, const float* __restrict__ Wq, const float* __restrict__ Wk,
    const float* __restrict__ Wv, const float* __restrict__ Wdk, const float* __restrict__ Wdv,
    const float* __restrict__ Ws, const float* __restrict__ Wtrg, const float* __restrict__ Wsrc,
    const float* __restrict__ Wf, const float* __restrict__ Wo,
    const float* __restrict__ bq, const float* __restrict__ bk, const float* __restrict__ bv,
    const float* __restrict__ bdk, const float* __restrict__ bdv, const float* __restrict__ bf,
    __bf16* __restrict__ Wt, float* __restrict__ bqkv, float* __restrict__ bfm) {
  int bid = blockIdx.x;
  int t = threadIdx.x;
  if (bid >= 256) {
    if (bid == 256) {
      if (t < 128) { bqkv[t] = bq[t]; bqkv[128 + t] = bk[t]; bqkv[256 + t] = bv[t]; }
    } else {
      if (t < 128) { bfm[t] = bdk[t]; bfm[128 + t] = bdv[t]; bfm[256 + t] = bf[t]; }
    }
    return;
  }
  int ct = bid >> 2, kt = bid & 3;
  int gc0 = ct * 32;
  const float* W; int ldw, sc0;
  if      (gc0 < 384)  { W = Wvec; ldw = 384; sc0 = gc0; }
  else if (gc0 < 512)  { W = Wtrg; ldw = 128; sc0 = gc0 - 384; }
  else if (gc0 < 640)  { W = Wsrc; ldw = 128; sc0 = gc0 - 512; }
  else if (gc0 < 768)  { W = Wq;   ldw = 128; sc0 = gc0 - 640; }
  else if (gc0 < 896)  { W = Wk;   ldw = 128; sc0 = gc0 - 768; }
  else if (gc0 < 1024) { W = Wv;   ldw = 128; sc0 = gc0 - 896; }
  else if (gc0 < 1152) { W = Wdk;  ldw = 128; sc0 = gc0 - 1024; }
  else if (gc0 < 1280) { W = Wdv;  ldw = 128; sc0 = gc0 - 1152; }
  else if (gc0 < 1408) { W = Wf;   ldw = 128; sc0 = gc0 - 1280; }
  else if (gc0 < 1664) { W = Ws;   ldw = 256; sc0 = gc0 - 1408; }
  else                 { W = Wo;   ldw = 384; sc0 = gc0 - 1664; }
  __shared__ float tile[32][33];
  int tx = t & 31, ty = t >> 5;
#pragma unroll
  for (int i = 0; i < 4; ++i)
    tile[ty + i * 8][tx] = W[(size_t)(kt * 32 + ty + i * 8) * ldw + sc0 + tx];
  __syncthreads();
#pragma unroll
  for (int i = 0; i < 4; ++i)
    Wt[(size_t)(gc0 + ty + i * 8) * 128 + kt * 32 + tx] = (__bf16)tile[tx][ty + i * 8];
}

// ---------------- MFMA GEMM v6: 1D XCD-swizzled grid; one 128x128 tile per block ----------
// bid = xg*(ny*8) + y*8 + xi, x = xg*8+xi: all ny y-siblings of an x share bid%8 (same XCD)
// so the A-tile is fetched to that XCD's L2 once. As-only LDS (32KB, swizzled); Cs staging
// aliased into As (dead after epilogue barrier) -> 4 blocks/CU. bf16-C stores nontemporal.
// FUSE: y==0 computes ct0,ct1 -> vdot only; y>=1 computes ct=y+1, stores col (y-1)*128.
template <typename AT, typename CT, bool FUSE>
__global__ __launch_bounds__(256, 4) void gemm_v6(const AT* __restrict__ A,
                                                  const __bf16* __restrict__ Bt,
                                                  const float* __restrict__ bias,
                                                  CT* __restrict__ C,
                                                  float* __restrict__ vdot, int M, int nx,
                                                  int ny, int ldc, int act) {
  __shared__ __bf16 As[128 * 128];
  __bf16* Cs = As;  // reused for C staging after MFMA (post-barrier; 32*136 <= 128*128)
  const int bid = blockIdx.x;
  const int xi = bid & 7;
  const int rem = bid >> 3;
  const int y = rem % ny;
  const int x = (rem / ny) * 8 + xi;
  if (x >= nx) return;
  const int tid = threadIdx.x;
  const int lane = tid & 63;
  const int wave = tid >> 6;
  const int wm = wave >> 1, wn = wave & 1;
  const int row0 = x * 128;

  if constexpr (sizeof(AT) == 2) {
#pragma unroll
    for (int i = 0; i < 8; ++i) {
      int c = tid + i * 256;  // 16B chunk; LDS dest linear
      int row = c >> 4, k8 = c & 15;
      int k8s = k8 ^ (row & 7);  // inverse-swizzled source == read-side XOR
      const AT* src = A + (size_t)(row0 + row) * 128 + k8s * 8;
      __builtin_amdgcn_global_load_lds((const __attribute__((address_space(1))) void*)src,
                                       (__attribute__((address_space(3))) void*)(As + c * 8),
                                       16, 0, 0);
    }
  } else {
#pragma unroll
    for (int i = 0; i < 8; ++i) {
      int c = tid + i * 256;
      int row = c >> 4, k8 = c & 15;
      int gm = row0 + row;
      bf16x8 h = {};
      if (gm < M) {
        f32x4 f0 = *(const f32x4*)(A + (size_t)gm * 128 + k8 * 8);
        f32x4 f1 = *(const f32x4*)(A + (size_t)gm * 128 + k8 * 8 + 4);
        h[0] = (__bf16)f0[0]; h[1] = (__bf16)f0[1]; h[2] = (__bf16)f0[2]; h[3] = (__bf16)f0[3];
        h[4] = (__bf16)f1[0]; h[5] = (__bf16)f1[1]; h[6] = (__bf16)f1[2]; h[7] = (__bf16)f1[3];
      }
      int byte = (c * 16) ^ ((row & 7) << 4);
      *(bf16x8*)((char*)As + byte) = h;
    }
  }
  __syncthreads();

  if constexpr (FUSE) {
    if (y == 0) {
      // ct=0 (vec1) and ct=1 (vec2) -> vdot; per-ks B loads (VGPR budget)
      f32x4 pacc[4][4], acc[4][4];
#pragma unroll
      for (int mi = 0; mi < 4; ++mi)
#pragma unroll
        for (int ni = 0; ni < 4; ++ni) {
          pacc[mi][ni] = f32x4{0.f, 0.f, 0.f, 0.f};
          acc[mi][ni] = f32x4{0.f, 0.f, 0.f, 0.f};
        }
#pragma unroll
      for (int ct = 0; ct < 2; ++ct) {
        const __bf16* Bbase =
            Bt + ((size_t)(ct * 128 + wn * 64 + (lane & 15)) << 7) + ((lane >> 4) << 3);
#pragma unroll
        for (int ks = 0; ks < 4; ++ks) {
          bf16x8 b[4];
#pragma unroll
          for (int ni = 0; ni < 4; ++ni) b[ni] = *(const bf16x8*)(Bbase + (ni << 11) + (ks << 5));
          bf16x8 a[4];
#pragma unroll
          for (int mi = 0; mi < 4; ++mi) {
            int row = wm * 64 + mi * 16 + (lane & 15);
            int byte = (row * 256 + ks * 64 + ((lane >> 4) << 4)) ^ ((row & 7) << 4);
            a[mi] = *(const bf16x8*)((const char*)As + byte);
          }
          if (ct == 0) {
#pragma unroll
            for (int mi = 0; mi < 4; ++mi)
#pragma unroll
              for (int ni = 0; ni < 4; ++ni)
                pacc[mi][ni] =
                    __builtin_amdgcn_mfma_f32_16x16x32_bf16(a[mi], b[ni], pacc[mi][ni], 0, 0, 0);
          } else {
#pragma unroll
            for (int mi = 0; mi < 4; ++mi)
#pragma unroll
              for (int ni = 0; ni < 4; ++ni)
                acc[mi][ni] =
                    __builtin_amdgcn_mfma_f32_16x16x32_bf16(a[mi], b[ni], acc[mi][ni], 0, 0, 0);
          }
        }
      }
      // vdot[node][c] = sum over 8 L-rows of vec1*vec2
#pragma unroll
      for (int mi = 0; mi < 4; ++mi) {
#pragma unroll
        for (int ni = 0; ni < 4; ++ni) {
          float sr = pacc[mi][ni][0] * acc[mi][ni][0] + pacc[mi][ni][1] * acc[mi][ni][1] +
                     pacc[mi][ni][2] * acc[mi][ni][2] + pacc[mi][ni][3] * acc[mi][ni][3];
          sr += __shfl_xor(sr, 16, 64);
          if ((lane & 16) == 0) {
            int node = (row0 >> 3) + wm * 8 + mi * 2 + (lane >> 5);
            int col = wn * 64 + ni * 16 + (lane & 15);
            vdot[(size_t)node * 128 + col] = sr;
          }
        }
      }
      return;
    }
  }

  const int ct = FUSE ? y + 1 : y;
  const int cstore = FUSE ? (y - 1) * 128 : y * 128;

  // hoist all 16 B fragments (one wait; weights L2-hot)
  const __bf16* Bbase =
      Bt + ((size_t)(ct * 128 + wn * 64 + (lane & 15)) << 7) + ((lane >> 4) << 3);
  bf16x8 b[4][4];
#pragma unroll
  for (int ks = 0; ks < 4; ++ks)
#pragma unroll
    for (int ni = 0; ni < 4; ++ni) b[ks][ni] = *(const bf16x8*)(Bbase + (ni << 11) + (ks << 5));

  f32x4 acc[4][4];
#pragma unroll
  for (int mi = 0; mi < 4; ++mi)
#pragma unroll
    for (int ni = 0; ni < 4; ++ni) acc[mi][ni] = f32x4{0.f, 0.f, 0.f, 0.f};

#pragma unroll
  for (int ks = 0; ks < 4; ++ks) {
    bf16x8 a[4];
#pragma unroll
    for (int mi = 0; mi < 4; ++mi) {
      int row = wm * 64 + mi * 16 + (lane & 15);
      int byte = (row * 256 + ks * 64 + ((lane >> 4) << 4)) ^ ((row & 7) << 4);
      a[mi] = *(const bf16x8*)((const char*)As + byte);
    }
#pragma unroll
    for (int mi = 0; mi < 4; ++mi)
#pragma unroll
      for (int ni = 0; ni < 4; ++ni)
        acc[mi][ni] =
            __builtin_amdgcn_mfma_f32_16x16x32_bf16(a[mi], b[ks][ni], acc[mi][ni], 0, 0, 0);
  }

  if constexpr (sizeof(CT) == 2) {
    // staged epilogue: acc -> LDS (padded, aliases As) -> 16B nontemporal stores
#pragma unroll
    for (int mi = 0; mi < 4; ++mi) {
      __syncthreads();  // all MFMA-reads of As done / previous stage consumed
      int rl = (wm << 4) | ((lane >> 4) << 2);
#pragma unroll
      for (int ni = 0; ni < 4; ++ni) {
        int col = wn * 64 + ni * 16 + (lane & 15);
        float bv = bias ? bias[ct * 128 + col] : 0.f;
#pragma unroll
        for (int r = 0; r < 4; ++r) {
          float xv = acc[mi][ni][r] + bv;
          if (act) xv = silu_f(xv);
          Cs[(rl + r) * 136 + col] = (__bf16)xv;
        }
      }
      __syncthreads();
      // 32 rows x 16 chunks of 8 bf16 = 512 stores; 2 per thread
#pragma unroll
      for (int rr = 0; rr < 2; ++rr) {
        int row = (tid >> 4) + rr * 16;
        int chunk = tid & 15;
        bf16x8 v = *(const bf16x8*)(Cs + row * 136 + chunk * 8);
        int grow = row0 + (row >> 4) * 64 + mi * 16 + (row & 15);
        if (grow < M)
          __builtin_nontemporal_store(v, (bf16x8*)(C + (size_t)grow * ldc + cstore + chunk * 8));
      }
    }
  } else {
#pragma unroll
    for (int mi = 0; mi < 4; ++mi) {
      int rbase = row0 + wm * 64 + mi * 16 + ((lane >> 4) << 2);
#pragma unroll
      for (int ni = 0; ni < 4; ++ni) {
        int gcol = cstore + wn * 64 + ni * 16 + (lane & 15);
        float bv = bias ? bias[ct * 128 + wn * 64 + ni * 16 + (lane & 15)] : 0.f;
#pragma unroll
        for (int r = 0; r < 4; ++r) {
          int grow = rbase + r;
          if (grow < M) {
            float xv = acc[mi][ni][r] + bv;
            if (act) xv = silu_f(xv);
            C[(size_t)grow * ldc + gcol] = (CT)xv;
          }
        }
      }
    }
  }
}

// helper: swizzled grid size
static inline int swz_grid(int nx, int ny) { return ((nx + 7) / 8) * ny * 8; }

// ---------------- message: attn + vm per edge (qkv bf16 [N][384]; dk/dv = fm cols 0..255) ----------
__global__ __launch_bounds__(256) void msg_kernel(const __bf16* __restrict__ qkv,
                                                  const __bf16* __restrict__ fm,
                                                  const float* __restrict__ r_ij,
                                                  const int* __restrict__ ei,
                                                  __bf16* __restrict__ vm) {
  int e = blockIdx.x * 2 + (threadIdx.x >> 7);
  int h = threadIdx.x & 127;
  int src = ei[e], dst = ei[N_EDGES + e];
  float qv = (float)qkv[(size_t)dst * 384 + h];
  float kv = (float)qkv[(size_t)src * 384 + 128 + h];
  float vv = (float)qkv[(size_t)src * 384 + 256 + h];
  float t = qv * kv * (float)fm[(size_t)e * 384 + h];
#pragma unroll
  for (int off = 8; off >= 1; off >>= 1) t += __shfl_xor(t, off, 16);
  float r = r_ij[e];
  float cut = 0.5f * (__cosf(0.6283185307f * r) + 1.f);
  cut = (r < 5.f) ? cut : 0.f;
  float attn = silu_f(t) * cut;
  vm[(size_t)e * H + h] = (__bf16)(vv * (float)fm[(size_t)e * 384 + 128 + h] * attn);
}

// ---------------- CSR build: histogram, scan, fill ----------------
__global__ __launch_bounds__(256) void hist_kernel(const int* __restrict__ ei,
                                                   int* __restrict__ cnt) {
  int e = blockIdx.x * 256 + threadIdx.x;
  if (e < N_EDGES) atomicAdd(&cnt[ei[N_EDGES + e]], 1);
}

__global__ __launch_bounds__(1024) void scan_kernel(const int* __restrict__ cnt,
                                                    int* __restrict__ rowptr) {
  __shared__ int wsum[16];
  int t = threadIdx.x;
  int base = t * 10;
  int local[10];
  int s = 0;
#pragma unroll
  for (int i = 0; i < 10; ++i) {
    int v = (base + i < N_NODES) ? cnt[base + i] : 0;
    local[i] = s;
    s += v;
  }
  int lane = t & 63, wave = t >> 6;
  int inc = s;
#pragma unroll
  for (int off = 1; off < 64; off <<= 1) {
    int u = __shfl_up(inc, off, 64);
    if (lane >= off) inc += u;
  }
  if (lane == 63) wsum[wave] = inc;
  __syncthreads();
  if (t == 0) {
    int acc = 0;
#pragma unroll
    for (int w = 0; w < 16; ++w) { int v = wsum[w]; wsum[w] = acc; acc += v; }
  }
  __syncthreads();
  int excl = inc - s + wsum[wave];
#pragma unroll
  for (int i = 0; i < 10; ++i)
    if (base + i <= N_NODES) rowptr[base + i] = excl + local[i];
}

__global__ __launch_bounds__(256) void fill_kernel(const int* __restrict__ ei,
                                                   const int* __restrict__ rowptr,
                                                   int* __restrict__ cursor,
                                                   int* __restrict__ elist) {
  int e = blockIdx.x * 256 + threadIdx.x;
  if (e < N_EDGES) {
    int d = ei[N_EDGES + e];
    int p = atomicAdd(&cursor[d], 1);
    elist[rowptr[d] + p] = e;
  }
}

// ---------------- gather: x_agg = Σ vm ; dvec = Σ vec_m (no atomics) ----------------
__global__ __launch_bounds__(256) void gather_kernel(const __bf16* __restrict__ vm,
                                                     const __bf16* __restrict__ s,
                                                     const __bf16* __restrict__ vecw,
                                                     const float* __restrict__ d_ij,
                                                     const int* __restrict__ ei,
                                                     const int* __restrict__ rowptr,
                                                     const int* __restrict__ elist,
                                                     float* __restrict__ x_agg,
                                                     float* __restrict__ dvec) {
  int n = blockIdx.x * 2 + (threadIdx.x >> 7);
  int h = threadIdx.x & 127;
  if (n >= N_NODES) return;
  int beg = rowptr[n], end = rowptr[n + 1];
  float ax = 0.f;
  float av[L] = {};
  for (int p = beg; p < end; ++p) {
    int e = elist[p];
    int src = ei[e];
    ax += (float)vm[(size_t)e * H + h];
    float s1 = (float)s[(size_t)e * 256 + h];
    float s2 = (float)s[(size_t)e * 256 + 128 + h];
    const __bf16* vrow = vecw + (size_t)src * L * H + h;
    const float* dd = d_ij + (size_t)e * L;
#pragma unroll
    for (int l = 0; l < L; l++) av[l] += (float)vrow[l * H] * s1 + s2 * dd[l];
  }
  x_agg[(size_t)n * H + h] = ax;
  float* drow = dvec + (size_t)n * L * H + h;
#pragma unroll
  for (int l = 0; l < L; l++) drow[l * H] = av[l];
}

// ---------------- edge update (big [NL][384]: vec3 @0, vt @128, vs @256; dfw = fm @256) ----------------
__global__ __launch_bounds__(256) void edgeupd_kernel(const __bf16* __restrict__ big,
                                                      const float* __restrict__ d_ij,
                                                      const __bf16* __restrict__ fm,
                                                      const int* __restrict__ ei,
                                                      float* __restrict__ df) {
  int e = blockIdx.x * 2 + (threadIdx.x >> 7);
  int h = threadIdx.x & 127;
  int src = ei[e], dst = ei[N_EDGES + e];
  float d[L];
  float sd2 = 0.f;
#pragma unroll
  for (int l = 0; l < L; l++) {
    d[l] = d_ij[(size_t)e * L + l];
    sd2 += d[l] * d[l];
  }
  const __bf16* arow = big + (size_t)dst * 8 * 384 + 128 + h;
  const __bf16* brow = big + (size_t)src * 8 * 384 + 256 + h;
  float dot = 0.f, p1 = 0.f, p2 = 0.f;
#pragma unroll
  for (int l = 0; l < L; l++) {
    float a = (float)arow[l * 384], bb = (float)brow[l * 384];
    dot += a * bb;
    p1 += a * d[l];
    p2 += bb * d[l];
  }
  float wdot = dot - p1 * p2 * (2.f - sd2);
  df[(size_t)e * H + h] = (float)fm[(size_t)e * 384 + 256 + h] * wdot;
}

// ---------------- final node update (vec3 = big cols 0..127) ----------------
__global__ __launch_bounds__(256) void final_kernel(const float* __restrict__ o,
                                                    const float* __restrict__ vdot,
                                                    const __bf16* __restrict__ big,
                                                    float* __restrict__ dx,
                                                    float* __restrict__ dvec, int n_nodes) {
  int n = blockIdx.x * 2 + (threadIdx.x >> 7);
  int h = threadIdx.x & 127;
  if (n >= n_nodes) return;
  float o1 = o[(size_t)n * 384 + h];
  float o2 = o[(size_t)n * 384 + 128 + h];
  float o3 = o[(size_t)n * 384 + 256 + h];
  dx[(size_t)n * H + h] = vdot[(size_t)n * H + h] * o2 + o3;
  float* drow = dvec + (size_t)n * L * H + h;
  const __bf16* v3 = big + (size_t)n * 8 * 384 + h;
#pragma unroll
  for (int l = 0; l < L; l++) drow[l * H] += (float)v3[l * 384] * o1;
}

extern "C" void kernel_launch(void* const* d_in, const int* in_sizes, int n_in, void* d_out,
                              int out_size, void* d_ws, size_t ws_size, hipStream_t stream) {
  const float* x = (const float*)d_in[0];
  const float* vec = (const float*)d_in[1];
  const float* f_ij = (const float*)d_in[2];
  const float* d_ij = (const float*)d_in[3];
  const float* r_ij = (const float*)d_in[4];
  const int* ei = (const int*)d_in[5];
  const float* ln_g = (const float*)d_in[6];
  const float* ln_b = (const float*)d_in[7];
  const float* vln_w = (const float*)d_in[8];
  const float* W_vec = (const float*)d_in[9];
  const float* W_q = (const float*)d_in[10];
  const float* b_q = (const float*)d_in[11];
  const float* W_k = (const float*)d_in[12];
  const float* b_k = (const float*)d_in[13];
  const float* W_v = (const float*)d_in[14];
  const float* b_v = (const float*)d_in[15];
  const float* W_dk = (const float*)d_in[16];
  const float* b_dk = (const float*)d_in[17];
  const float* W_dv = (const float*)d_in[18];
  const float* b_dv = (const float*)d_in[19];
  const float* W_s = (const float*)d_in[20];
  const float* b_s = (const float*)d_in[21];
  const float* W_f = (const float*)d_in[22];
  const float* b_f = (const float*)d_in[23];
  const float* W_src = (const float*)d_in[24];
  const float* W_trg = (const float*)d_in[25];
  const float* W_o = (const float*)d_in[26];
  const float* b_o = (const float*)d_in[27];

  float* out = (float*)d_out;
  float* dx = out;
  float* dvec = out + (size_t)N_NODES * H;
  float* df = dvec + (size_t)N_NODES * L * H;

  // ---- workspace plan (~207 MB; offsets in f32 slots) ----
  float* ws = (float*)d_ws;
  __bf16* vecw = (__bf16*)ws;                 // NL*128 bf16
  __bf16* big = (__bf16*)(ws + 5120000);      // NL*384 bf16: [vec3 128 | vt 128 | vs 128]
  __bf16* fm = (__bf16*)(ws + 20480000);      // E*384 bf16: [dk | dv | dfw]
  __bf16* vm = (__bf16*)(ws + 32768000);      // E*128 bf16
  __bf16* s_buf = (__bf16*)(ws + 36864000);   // E*256 bf16
  __bf16* qkv = (__bf16*)(ws + 45056000);     // N*384 bf16 (region reused as o_buf f32)
  float* xln = ws + 48896000;                 // N*128 f32 (reused as x_agg)
  float* vdot = ws + 50176000;                // N*128 f32
  __bf16* Wt = (__bf16*)(ws + 51456000);      // [2048][128] bf16
  float* bqkv = ws + 51456000 + 131072;       // 384
  float* bfm = bqkv + 384;                    // 384
  int* rowptr = (int*)(bfm + 384);            // 10,001
  int* elist = rowptr + 10001;                // 64,000
  int* cnt = elist + 64000;                   // 10,000
  int* cursor = cnt + 10000;                  // 10,000

  float* o_buf = ws + 45056000;  // overwrites qkv after it's consumed (step 6)
  float* x_agg = xln;

  dim3 b256(256);

  // CSR build (depends only on ei)
  hipMemsetAsync(cnt, 0, N_NODES * sizeof(int), stream);
  hipMemsetAsync(cursor, 0, N_NODES * sizeof(int), stream);
  hist_kernel<<<dim3((N_EDGES + 255) / 256), b256, 0, stream>>>(ei, cnt);
  scan_kernel<<<dim3(1), dim3(1024), 0, stream>>>(cnt, rowptr);
  fill_kernel<<<dim3((N_EDGES + 255) / 256), b256, 0, stream>>>(ei, rowptr, cursor, elist);

  // 0. weight convert/transpose + bias concat
  wconv_kernel<<<dim3(258), b256, 0, stream>>>(W_vec, W_q, W_k, W_v, W_dk, W_dv, W_s, W_trg,
                                               W_src, W_f, W_o, b_q, b_k, b_v, b_dk, b_dv, b_f,
                                               Wt, bqkv, bfm);
  // 1. x_ln = layernorm(x)
  ln_kernel<<<dim3((N_NODES + 3) / 4), b256, 0, stream>>>(x, ln_g, ln_b, xln, N_NODES);
  // 2. vecw = vec * vln_w (bf16)
  vecw_kernel<<<dim3(2048), b256, 0, stream>>>(vec, vln_w, vecw, (size_t)NL * H / 8);
  // 3. big = vecw @ [Wvec|Wtrg|Wsrc], vec_dot fused; XCD-swizzled grid (625 x-tiles, 4 y)
  gemm_v6<__bf16, __bf16, true><<<dim3(swz_grid(625, 4)), b256, 0, stream>>>(
      vecw, Wt, nullptr, big, vdot, NL, 625, 4, 384, 0);
  // 4. qkv = xln @ [Wq|Wk|Wv] + b (bf16 out)
  gemm_v6<float, __bf16, false><<<dim3(swz_grid(79, 3)), b256, 0, stream>>>(
      xln, Wt + (size_t)640 * 128, bqkv, qkv, nullptr, N_NODES, 79, 3, 384, 0);
  // 5. fm = silu(f_ij @ [Wdk|Wdv|Wf] + b)
  gemm_v6<float, __bf16, false><<<dim3(swz_grid(500, 3)), b256, 0, stream>>>(
      f_ij, Wt + (size_t)1024 * 128, bfm, fm, nullptr, N_EDGES, 500, 3, 384, 1);
  // 6. message -> vm (bf16)
  msg_kernel<<<dim3(N_EDGES / 2), b256, 0, stream>>>(qkv, fm, r_ij, ei, vm);
  // 7. s = silu(vm @ W_s + b)
  gemm_v6<__bf16, __bf16, false><<<dim3(swz_grid(500, 2)), b256, 0, stream>>>(
      vm, Wt + (size_t)1408 * 128, b_s, s_buf, nullptr, N_EDGES, 500, 2, 256, 1);
  // 8. gather into x_agg and dvec (no atomics)
  gather_kernel<<<dim3(N_NODES / 2), b256, 0, stream>>>(vm, s_buf, vecw, d_ij, ei, rowptr,
                                                        elist, x_agg, dvec);
  // 9. edge update -> df (reads big vt/vs + fm dfw)
  edgeupd_kernel<<<dim3(N_EDGES / 2), b256, 0, stream>>>(big, d_ij, fm, ei, df);
  // 10. o = x_agg @ W_o + b (f32; overwrites qkv region: consumed in 6)
  gemm_v6<float, float, false><<<dim3(swz_grid(79, 3)), b256, 0, stream>>>(
      x_agg, Wt + (size_t)1664 * 128, b_o, o_buf, nullptr, N_NODES, 79, 3, 384, 0);
  // 11. final: dx, dvec += vec3*o1
  final_kernel<<<dim3(5000), b256, 0, stream>>>(o_buf, vdot, big, dx, dvec, N_NODES);
}

// Round 11
// 381.995 us; speedup vs baseline: 1.1174x; 1.1174x over previous
//
#include <hip/hip_runtime.h>
#include <hip/hip_bf16.h>
#include <math.h>

#define N_NODES 10000
#define N_EDGES 64000
#define H 128
#define L 8
#define NL (N_NODES * L)

typedef __attribute__((ext_vector_type(4))) float f32x4;
typedef __attribute__((ext_vector_type(8))) __bf16 bf16x8;

__device__ __forceinline__ float silu_f(float x) { return x / (1.f + __expf(-x)); }

// ---------------- LayerNorm: one wave per node ----------------
__global__ __launch_bounds__(256) void ln_kernel(const float* __restrict__ x,
                                                 const float* __restrict__ g,
                                                 const float* __restrict__ b,
                                                 float* __restrict__ out, int n_nodes) {
  int wave = threadIdx.x >> 6;
  int lane = threadIdx.x & 63;
  int n = blockIdx.x * 4 + wave;
  if (n >= n_nodes) return;
  const float* xr = x + (size_t)n * H;
  float a0 = xr[lane], a1 = xr[lane + 64];
  float s = a0 + a1;
#pragma unroll
  for (int off = 32; off >= 1; off >>= 1) s += __shfl_xor(s, off, 64);
  float mu = s * (1.f / H);
  float d0 = a0 - mu, d1 = a1 - mu;
  float v = d0 * d0 + d1 * d1;
#pragma unroll
  for (int off = 32; off >= 1; off >>= 1) v += __shfl_xor(v, off, 64);
  float rstd = rsqrtf(v * (1.f / H) + 1e-5f);
  float* orow = out + (size_t)n * H;
  orow[lane] = d0 * rstd * g[lane] + b[lane];
  orow[lane + 64] = d1 * rstd * g[lane + 64] + b[lane + 64];
}

// ---------------- vecw = vec * vln_w  -> bf16 ----------------
__global__ __launch_bounds__(256) void vecw_kernel(const float* __restrict__ vec,
                                                   const float* __restrict__ w,
                                                   __bf16* __restrict__ out, size_t total8) {
  size_t i = (size_t)blockIdx.x * blockDim.x + threadIdx.x;
  size_t stride = (size_t)gridDim.x * blockDim.x;
  for (; i < total8; i += stride) {
    size_t base = i * 8;
    f32x4 a = *(const f32x4*)(vec + base);
    f32x4 b = *(const f32x4*)(vec + base + 4);
    int c = (int)(base & 127);
    bf16x8 h;
    h[0] = (__bf16)(a[0] * w[c + 0]); h[1] = (__bf16)(a[1] * w[c + 1]);
    h[2] = (__bf16)(a[2] * w[c + 2]); h[3] = (__bf16)(a[3] * w[c + 3]);
    h[4] = (__bf16)(b[0] * w[c + 4]); h[5] = (__bf16)(b[1] * w[c + 5]);
    h[6] = (__bf16)(b[2] * w[c + 6]); h[7] = (__bf16)(b[3] * w[c + 7]);
    *(bf16x8*)(out + base) = h;
  }
}

// ---------------- weight convert into one [2048][128] bf16 table ----------------
// col map: [0,384) Wvec | [384,512) Wtrg | [512,640) Wsrc | [640,768) Wq | [768,896) Wk
//          | [896,1024) Wv | [1024,1152) Wdk | [1152,1280) Wdv | [1280,1408) Wf
//          | [1408,1664) Ws | [1664,2048) Wo
__global__ __launch_bounds__(256) void wconv_kernel(
    const float* __restrict__ Wvec, const float* __restrict__ Wq, const float* __restrict__ Wk,
    const float* __restrict__ Wv, const float* __restrict__ Wdk, const float* __restrict__ Wdv,
    const float* __restrict__ Ws, const float* __restrict__ Wtrg, const float* __restrict__ Wsrc,
    const float* __restrict__ Wf, const float* __restrict__ Wo,
    const float* __restrict__ bq, const float* __restrict__ bk, const float* __restrict__ bv,
    const float* __restrict__ bdk, const float* __restrict__ bdv, const float* __restrict__ bf,
    __bf16* __restrict__ Wt, float* __restrict__ bqkv, float* __restrict__ bfm) {
  int bid = blockIdx.x;
  int t = threadIdx.x;
  if (bid >= 256) {
    if (bid == 256) {
      if (t < 128) { bqkv[t] = bq[t]; bqkv[128 + t] = bk[t]; bqkv[256 + t] = bv[t]; }
    } else {
      if (t < 128) { bfm[t] = bdk[t]; bfm[128 + t] = bdv[t]; bfm[256 + t] = bf[t]; }
    }
    return;
  }
  int ct = bid >> 2, kt = bid & 3;
  int gc0 = ct * 32;
  const float* W; int ldw, sc0;
  if      (gc0 < 384)  { W = Wvec; ldw = 384; sc0 = gc0; }
  else if (gc0 < 512)  { W = Wtrg; ldw = 128; sc0 = gc0 - 384; }
  else if (gc0 < 640)  { W = Wsrc; ldw = 128; sc0 = gc0 - 512; }
  else if (gc0 < 768)  { W = Wq;   ldw = 128; sc0 = gc0 - 640; }
  else if (gc0 < 896)  { W = Wk;   ldw = 128; sc0 = gc0 - 768; }
  else if (gc0 < 1024) { W = Wv;   ldw = 128; sc0 = gc0 - 896; }
  else if (gc0 < 1152) { W = Wdk;  ldw = 128; sc0 = gc0 - 1024; }
  else if (gc0 < 1280) { W = Wdv;  ldw = 128; sc0 = gc0 - 1152; }
  else if (gc0 < 1408) { W = Wf;   ldw = 128; sc0 = gc0 - 1280; }
  else if (gc0 < 1664) { W = Ws;   ldw = 256; sc0 = gc0 - 1408; }
  else                 { W = Wo;   ldw = 384; sc0 = gc0 - 1664; }
  __shared__ float tile[32][33];
  int tx = t & 31, ty = t >> 5;
#pragma unroll
  for (int i = 0; i < 4; ++i)
    tile[ty + i * 8][tx] = W[(size_t)(kt * 32 + ty + i * 8) * ldw + sc0 + tx];
  __syncthreads();
#pragma unroll
  for (int i = 0; i < 4; ++i)
    Wt[(size_t)(gc0 + ty + i * 8) * 128 + kt * 32 + tx] = (__bf16)tile[tx][ty + i * 8];
}

// ---------------- MFMA GEMM v7: 1D XCD-swizzled grid; one 128x128 tile per block ----------
// bid = xg*(ny*8) + y*8 + xi, x = xg*8+xi: all ny y-siblings of an x share bid%8 (same XCD)
// so the A-tile is fetched to that XCD's L2 once. As-only LDS (32KB, swizzled); Cs staging
// aliased into As (dead after epilogue barrier). Plain cached 16B C-stores (NT regressed r10).
// launch_bounds(256,3): VGPR 84 keeps the B-hoist in registers (r10's (256,4) -> 64 VGPR spilled).
// FUSE: y==0 computes ct0,ct1 -> vdot only; y>=1 computes ct=y+1, stores col (y-1)*128.
template <typename AT, typename CT, bool FUSE>
__global__ __launch_bounds__(256, 3) void gemm_v7(const AT* __restrict__ A,
                                                  const __bf16* __restrict__ Bt,
                                                  const float* __restrict__ bias,
                                                  CT* __restrict__ C,
                                                  float* __restrict__ vdot, int M, int nx,
                                                  int ny, int ldc, int act) {
  __shared__ __bf16 As[128 * 128];
  __bf16* Cs = As;  // reused for C staging after MFMA (post-barrier; 32*136 <= 128*128)
  const int bid = blockIdx.x;
  const int xi = bid & 7;
  const int rem = bid >> 3;
  const int y = rem % ny;
  const int x = (rem / ny) * 8 + xi;
  if (x >= nx) return;
  const int tid = threadIdx.x;
  const int lane = tid & 63;
  const int wave = tid >> 6;
  const int wm = wave >> 1, wn = wave & 1;
  const int row0 = x * 128;

  if constexpr (sizeof(AT) == 2) {
#pragma unroll
    for (int i = 0; i < 8; ++i) {
      int c = tid + i * 256;  // 16B chunk; LDS dest linear
      int row = c >> 4, k8 = c & 15;
      int k8s = k8 ^ (row & 7);  // inverse-swizzled source == read-side XOR
      const AT* src = A + (size_t)(row0 + row) * 128 + k8s * 8;
      __builtin_amdgcn_global_load_lds((const __attribute__((address_space(1))) void*)src,
                                       (__attribute__((address_space(3))) void*)(As + c * 8),
                                       16, 0, 0);
    }
  } else {
#pragma unroll
    for (int i = 0; i < 8; ++i) {
      int c = tid + i * 256;
      int row = c >> 4, k8 = c & 15;
      int gm = row0 + row;
      bf16x8 h = {};
      if (gm < M) {
        f32x4 f0 = *(const f32x4*)(A + (size_t)gm * 128 + k8 * 8);
        f32x4 f1 = *(const f32x4*)(A + (size_t)gm * 128 + k8 * 8 + 4);
        h[0] = (__bf16)f0[0]; h[1] = (__bf16)f0[1]; h[2] = (__bf16)f0[2]; h[3] = (__bf16)f0[3];
        h[4] = (__bf16)f1[0]; h[5] = (__bf16)f1[1]; h[6] = (__bf16)f1[2]; h[7] = (__bf16)f1[3];
      }
      int byte = (c * 16) ^ ((row & 7) << 4);
      *(bf16x8*)((char*)As + byte) = h;
    }
  }
  __syncthreads();

  if constexpr (FUSE) {
    if (y == 0) {
      // ct=0 (vec1) and ct=1 (vec2) -> vdot; per-ks B loads (VGPR budget)
      f32x4 pacc[4][4], acc[4][4];
#pragma unroll
      for (int mi = 0; mi < 4; ++mi)
#pragma unroll
        for (int ni = 0; ni < 4; ++ni) {
          pacc[mi][ni] = f32x4{0.f, 0.f, 0.f, 0.f};
          acc[mi][ni] = f32x4{0.f, 0.f, 0.f, 0.f};
        }
#pragma unroll
      for (int ct = 0; ct < 2; ++ct) {
        const __bf16* Bbase =
            Bt + ((size_t)(ct * 128 + wn * 64 + (lane & 15)) << 7) + ((lane >> 4) << 3);
#pragma unroll
        for (int ks = 0; ks < 4; ++ks) {
          bf16x8 b[4];
#pragma unroll
          for (int ni = 0; ni < 4; ++ni) b[ni] = *(const bf16x8*)(Bbase + (ni << 11) + (ks << 5));
          bf16x8 a[4];
#pragma unroll
          for (int mi = 0; mi < 4; ++mi) {
            int row = wm * 64 + mi * 16 + (lane & 15);
            int byte = (row * 256 + ks * 64 + ((lane >> 4) << 4)) ^ ((row & 7) << 4);
            a[mi] = *(const bf16x8*)((const char*)As + byte);
          }
          if (ct == 0) {
#pragma unroll
            for (int mi = 0; mi < 4; ++mi)
#pragma unroll
              for (int ni = 0; ni < 4; ++ni)
                pacc[mi][ni] =
                    __builtin_amdgcn_mfma_f32_16x16x32_bf16(a[mi], b[ni], pacc[mi][ni], 0, 0, 0);
          } else {
#pragma unroll
            for (int mi = 0; mi < 4; ++mi)
#pragma unroll
              for (int ni = 0; ni < 4; ++ni)
                acc[mi][ni] =
                    __builtin_amdgcn_mfma_f32_16x16x32_bf16(a[mi], b[ni], acc[mi][ni], 0, 0, 0);
          }
        }
      }
      // vdot[node][c] = sum over 8 L-rows of vec1*vec2
#pragma unroll
      for (int mi = 0; mi < 4; ++mi) {
#pragma unroll
        for (int ni = 0; ni < 4; ++ni) {
          float sr = pacc[mi][ni][0] * acc[mi][ni][0] + pacc[mi][ni][1] * acc[mi][ni][1] +
                     pacc[mi][ni][2] * acc[mi][ni][2] + pacc[mi][ni][3] * acc[mi][ni][3];
          sr += __shfl_xor(sr, 16, 64);
          if ((lane & 16) == 0) {
            int node = (row0 >> 3) + wm * 8 + mi * 2 + (lane >> 5);
            int col = wn * 64 + ni * 16 + (lane & 15);
            vdot[(size_t)node * 128 + col] = sr;
          }
        }
      }
      return;
    }
  }

  const int ct = FUSE ? y + 1 : y;
  const int cstore = FUSE ? (y - 1) * 128 : y * 128;

  // hoist all 16 B fragments (one wait; weights L2-hot)
  const __bf16* Bbase =
      Bt + ((size_t)(ct * 128 + wn * 64 + (lane & 15)) << 7) + ((lane >> 4) << 3);
  bf16x8 b[4][4];
#pragma unroll
  for (int ks = 0; ks < 4; ++ks)
#pragma unroll
    for (int ni = 0; ni < 4; ++ni) b[ks][ni] = *(const bf16x8*)(Bbase + (ni << 11) + (ks << 5));

  f32x4 acc[4][4];
#pragma unroll
  for (int mi = 0; mi < 4; ++mi)
#pragma unroll
    for (int ni = 0; ni < 4; ++ni) acc[mi][ni] = f32x4{0.f, 0.f, 0.f, 0.f};

#pragma unroll
  for (int ks = 0; ks < 4; ++ks) {
    bf16x8 a[4];
#pragma unroll
    for (int mi = 0; mi < 4; ++mi) {
      int row = wm * 64 + mi * 16 + (lane & 15);
      int byte = (row * 256 + ks * 64 + ((lane >> 4) << 4)) ^ ((row & 7) << 4);
      a[mi] = *(const bf16x8*)((const char*)As + byte);
    }
#pragma unroll
    for (int mi = 0; mi < 4; ++mi)
#pragma unroll
      for (int ni = 0; ni < 4; ++ni)
        acc[mi][ni] =
            __builtin_amdgcn_mfma_f32_16x16x32_bf16(a[mi], b[ks][ni], acc[mi][ni], 0, 0, 0);
  }

  if constexpr (sizeof(CT) == 2) {
    // staged epilogue: acc -> LDS (padded, aliases As) -> 16B coalesced stores
#pragma unroll
    for (int mi = 0; mi < 4; ++mi) {
      __syncthreads();  // all MFMA-reads of As done / previous stage consumed
      int rl = (wm << 4) | ((lane >> 4) << 2);
#pragma unroll
      for (int ni = 0; ni < 4; ++ni) {
        int col = wn * 64 + ni * 16 + (lane & 15);
        float bv = bias ? bias[ct * 128 + col] : 0.f;
#pragma unroll
        for (int r = 0; r < 4; ++r) {
          float xv = acc[mi][ni][r] + bv;
          if (act) xv = silu_f(xv);
          Cs[(rl + r) * 136 + col] = (__bf16)xv;
        }
      }
      __syncthreads();
      // 32 rows x 16 chunks of 8 bf16 = 512 stores; 2 per thread
#pragma unroll
      for (int rr = 0; rr < 2; ++rr) {
        int row = (tid >> 4) + rr * 16;
        int chunk = tid & 15;
        bf16x8 v = *(const bf16x8*)(Cs + row * 136 + chunk * 8);
        int grow = row0 + (row >> 4) * 64 + mi * 16 + (row & 15);
        if (grow < M)
          *(bf16x8*)(C + (size_t)grow * ldc + cstore + chunk * 8) = v;
      }
    }
  } else {
#pragma unroll
    for (int mi = 0; mi < 4; ++mi) {
      int rbase = row0 + wm * 64 + mi * 16 + ((lane >> 4) << 2);
#pragma unroll
      for (int ni = 0; ni < 4; ++ni) {
        int gcol = cstore + wn * 64 + ni * 16 + (lane & 15);
        float bv = bias ? bias[ct * 128 + wn * 64 + ni * 16 + (lane & 15)] : 0.f;
#pragma unroll
        for (int r = 0; r < 4; ++r) {
          int grow = rbase + r;
          if (grow < M) {
            float xv = acc[mi][ni][r] + bv;
            if (act) xv = silu_f(xv);
            C[(size_t)grow * ldc + gcol] = (CT)xv;
          }
        }
      }
    }
  }
}

// helper: swizzled grid size
static inline int swz_grid(int nx, int ny) { return ((nx + 7) / 8) * ny * 8; }

// ---------------- message: attn + vm per edge (qkv bf16 [N][384]; dk/dv = fm cols 0..255) ----------
__global__ __launch_bounds__(256) void msg_kernel(const __bf16* __restrict__ qkv,
                                                  const __bf16* __restrict__ fm,
                                                  const float* __restrict__ r_ij,
                                                  const int* __restrict__ ei,
                                                  __bf16* __restrict__ vm) {
  int e = blockIdx.x * 2 + (threadIdx.x >> 7);
  int h = threadIdx.x & 127;
  int src = ei[e], dst = ei[N_EDGES + e];
  float qv = (float)qkv[(size_t)dst * 384 + h];
  float kv = (float)qkv[(size_t)src * 384 + 128 + h];
  float vv = (float)qkv[(size_t)src * 384 + 256 + h];
  float t = qv * kv * (float)fm[(size_t)e * 384 + h];
#pragma unroll
  for (int off = 8; off >= 1; off >>= 1) t += __shfl_xor(t, off, 16);
  float r = r_ij[e];
  float cut = 0.5f * (__cosf(0.6283185307f * r) + 1.f);
  cut = (r < 5.f) ? cut : 0.f;
  float attn = silu_f(t) * cut;
  vm[(size_t)e * H + h] = (__bf16)(vv * (float)fm[(size_t)e * 384 + 128 + h] * attn);
}

// ---------------- CSR build: histogram, scan, fill ----------------
__global__ __launch_bounds__(256) void hist_kernel(const int* __restrict__ ei,
                                                   int* __restrict__ cnt) {
  int e = blockIdx.x * 256 + threadIdx.x;
  if (e < N_EDGES) atomicAdd(&cnt[ei[N_EDGES + e]], 1);
}

__global__ __launch_bounds__(1024) void scan_kernel(const int* __restrict__ cnt,
                                                    int* __restrict__ rowptr) {
  __shared__ int wsum[16];
  int t = threadIdx.x;
  int base = t * 10;
  int local[10];
  int s = 0;
#pragma unroll
  for (int i = 0; i < 10; ++i) {
    int v = (base + i < N_NODES) ? cnt[base + i] : 0;
    local[i] = s;
    s += v;
  }
  int lane = t & 63, wave = t >> 6;
  int inc = s;
#pragma unroll
  for (int off = 1; off < 64; off <<= 1) {
    int u = __shfl_up(inc, off, 64);
    if (lane >= off) inc += u;
  }
  if (lane == 63) wsum[wave] = inc;
  __syncthreads();
  if (t == 0) {
    int acc = 0;
#pragma unroll
    for (int w = 0; w < 16; ++w) { int v = wsum[w]; wsum[w] = acc; acc += v; }
  }
  __syncthreads();
  int excl = inc - s + wsum[wave];
#pragma unroll
  for (int i = 0; i < 10; ++i)
    if (base + i <= N_NODES) rowptr[base + i] = excl + local[i];
}

__global__ __launch_bounds__(256) void fill_kernel(const int* __restrict__ ei,
                                                   const int* __restrict__ rowptr,
                                                   int* __restrict__ cursor,
                                                   int* __restrict__ elist) {
  int e = blockIdx.x * 256 + threadIdx.x;
  if (e < N_EDGES) {
    int d = ei[N_EDGES + e];
    int p = atomicAdd(&cursor[d], 1);
    elist[rowptr[d] + p] = e;
  }
}

// ---------------- gather: x_agg = Σ vm ; dvec = Σ vec_m (no atomics) ----------------
__global__ __launch_bounds__(256) void gather_kernel(const __bf16* __restrict__ vm,
                                                     const __bf16* __restrict__ s,
                                                     const __bf16* __restrict__ vecw,
                                                     const float* __restrict__ d_ij,
                                                     const int* __restrict__ ei,
                                                     const int* __restrict__ rowptr,
                                                     const int* __restrict__ elist,
                                                     float* __restrict__ x_agg,
                                                     float* __restrict__ dvec) {
  int n = blockIdx.x * 2 + (threadIdx.x >> 7);
  int h = threadIdx.x & 127;
  if (n >= N_NODES) return;
  int beg = rowptr[n], end = rowptr[n + 1];
  float ax = 0.f;
  float av[L] = {};
  for (int p = beg; p < end; ++p) {
    int e = elist[p];
    int src = ei[e];
    ax += (float)vm[(size_t)e * H + h];
    float s1 = (float)s[(size_t)e * 256 + h];
    float s2 = (float)s[(size_t)e * 256 + 128 + h];
    const __bf16* vrow = vecw + (size_t)src * L * H + h;
    const float* dd = d_ij + (size_t)e * L;
#pragma unroll
    for (int l = 0; l < L; l++) av[l] += (float)vrow[l * H] * s1 + s2 * dd[l];
  }
  x_agg[(size_t)n * H + h] = ax;
  float* drow = dvec + (size_t)n * L * H + h;
#pragma unroll
  for (int l = 0; l < L; l++) drow[l * H] = av[l];
}

// ---------------- edge update (big [NL][384]: vec3 @0, vt @128, vs @256; dfw = fm @256) ----------------
__global__ __launch_bounds__(256) void edgeupd_kernel(const __bf16* __restrict__ big,
                                                      const float* __restrict__ d_ij,
                                                      const __bf16* __restrict__ fm,
                                                      const int* __restrict__ ei,
                                                      float* __restrict__ df) {
  int e = blockIdx.x * 2 + (threadIdx.x >> 7);
  int h = threadIdx.x & 127;
  int src = ei[e], dst = ei[N_EDGES + e];
  float d[L];
  float sd2 = 0.f;
#pragma unroll
  for (int l = 0; l < L; l++) {
    d[l] = d_ij[(size_t)e * L + l];
    sd2 += d[l] * d[l];
  }
  const __bf16* arow = big + (size_t)dst * 8 * 384 + 128 + h;
  const __bf16* brow = big + (size_t)src * 8 * 384 + 256 + h;
  float dot = 0.f, p1 = 0.f, p2 = 0.f;
#pragma unroll
  for (int l = 0; l < L; l++) {
    float a = (float)arow[l * 384], bb = (float)brow[l * 384];
    dot += a * bb;
    p1 += a * d[l];
    p2 += bb * d[l];
  }
  float wdot = dot - p1 * p2 * (2.f - sd2);
  df[(size_t)e * H + h] = (float)fm[(size_t)e * 384 + 256 + h] * wdot;
}

// ---------------- final node update (vec3 = big cols 0..127) ----------------
__global__ __launch_bounds__(256) void final_kernel(const float* __restrict__ o,
                                                    const float* __restrict__ vdot,
                                                    const __bf16* __restrict__ big,
                                                    float* __restrict__ dx,
                                                    float* __restrict__ dvec, int n_nodes) {
  int n = blockIdx.x * 2 + (threadIdx.x >> 7);
  int h = threadIdx.x & 127;
  if (n >= n_nodes) return;
  float o1 = o[(size_t)n * 384 + h];
  float o2 = o[(size_t)n * 384 + 128 + h];
  float o3 = o[(size_t)n * 384 + 256 + h];
  dx[(size_t)n * H + h] = vdot[(size_t)n * H + h] * o2 + o3;
  float* drow = dvec + (size_t)n * L * H + h;
  const __bf16* v3 = big + (size_t)n * 8 * 384 + h;
#pragma unroll
  for (int l = 0; l < L; l++) drow[l * H] += (float)v3[l * 384] * o1;
}

extern "C" void kernel_launch(void* const* d_in, const int* in_sizes, int n_in, void* d_out,
                              int out_size, void* d_ws, size_t ws_size, hipStream_t stream) {
  const float* x = (const float*)d_in[0];
  const float* vec = (const float*)d_in[1];
  const float* f_ij = (const float*)d_in[2];
  const float* d_ij = (const float*)d_in[3];
  const float* r_ij = (const float*)d_in[4];
  const int* ei = (const int*)d_in[5];
  const float* ln_g = (const float*)d_in[6];
  const float* ln_b = (const float*)d_in[7];
  const float* vln_w = (const float*)d_in[8];
  const float* W_vec = (const float*)d_in[9];
  const float* W_q = (const float*)d_in[10];
  const float* b_q = (const float*)d_in[11];
  const float* W_k = (const float*)d_in[12];
  const float* b_k = (const float*)d_in[13];
  const float* W_v = (const float*)d_in[14];
  const float* b_v = (const float*)d_in[15];
  const float* W_dk = (const float*)d_in[16];
  const float* b_dk = (const float*)d_in[17];
  const float* W_dv = (const float*)d_in[18];
  const float* b_dv = (const float*)d_in[19];
  const float* W_s = (const float*)d_in[20];
  const float* b_s = (const float*)d_in[21];
  const float* W_f = (const float*)d_in[22];
  const float* b_f = (const float*)d_in[23];
  const float* W_src = (const float*)d_in[24];
  const float* W_trg = (const float*)d_in[25];
  const float* W_o = (const float*)d_in[26];
  const float* b_o = (const float*)d_in[27];

  float* out = (float*)d_out;
  float* dx = out;
  float* dvec = out + (size_t)N_NODES * H;
  float* df = dvec + (size_t)N_NODES * L * H;

  // ---- workspace plan (~207 MB; offsets in f32 slots) ----
  float* ws = (float*)d_ws;
  __bf16* vecw = (__bf16*)ws;                 // NL*128 bf16
  __bf16* big = (__bf16*)(ws + 5120000);      // NL*384 bf16: [vec3 128 | vt 128 | vs 128]
  __bf16* fm = (__bf16*)(ws + 20480000);      // E*384 bf16: [dk | dv | dfw]
  __bf16* vm = (__bf16*)(ws + 32768000);      // E*128 bf16
  __bf16* s_buf = (__bf16*)(ws + 36864000);   // E*256 bf16
  __bf16* qkv = (__bf16*)(ws + 45056000);     // N*384 bf16 (region reused as o_buf f32)
  float* xln = ws + 48896000;                 // N*128 f32 (reused as x_agg)
  float* vdot = ws + 50176000;                // N*128 f32
  __bf16* Wt = (__bf16*)(ws + 51456000);      // [2048][128] bf16
  float* bqkv = ws + 51456000 + 131072;       // 384
  float* bfm = bqkv + 384;                    // 384
  int* rowptr = (int*)(bfm + 384);            // 10,001
  int* elist = rowptr + 10001;                // 64,000
  int* cnt = elist + 64000;                   // 10,000
  int* cursor = cnt + 10000;                  // 10,000

  float* o_buf = ws + 45056000;  // overwrites qkv after it's consumed (step 6)
  float* x_agg = xln;

  dim3 b256(256);

  // CSR build (depends only on ei)
  hipMemsetAsync(cnt, 0, N_NODES * sizeof(int), stream);
  hipMemsetAsync(cursor, 0, N_NODES * sizeof(int), stream);
  hist_kernel<<<dim3((N_EDGES + 255) / 256), b256, 0, stream>>>(ei, cnt);
  scan_kernel<<<dim3(1), dim3(1024), 0, stream>>>(cnt, rowptr);
  fill_kernel<<<dim3((N_EDGES + 255) / 256), b256, 0, stream>>>(ei, rowptr, cursor, elist);

  // 0. weight convert/transpose + bias concat
  wconv_kernel<<<dim3(258), b256, 0, stream>>>(W_vec, W_q, W_k, W_v, W_dk, W_dv, W_s, W_trg,
                                               W_src, W_f, W_o, b_q, b_k, b_v, b_dk, b_dv, b_f,
                                               Wt, bqkv, bfm);
  // 1. x_ln = layernorm(x)
  ln_kernel<<<dim3((N_NODES + 3) / 4), b256, 0, stream>>>(x, ln_g, ln_b, xln, N_NODES);
  // 2. vecw = vec * vln_w (bf16)
  vecw_kernel<<<dim3(2048), b256, 0, stream>>>(vec, vln_w, vecw, (size_t)NL * H / 8);
  // 3. big = vecw @ [Wvec|Wtrg|Wsrc], vec_dot fused; XCD-swizzled grid (625 x-tiles, 4 y)
  gemm_v7<__bf16, __bf16, true><<<dim3(swz_grid(625, 4)), b256, 0, stream>>>(
      vecw, Wt, nullptr, big, vdot, NL, 625, 4, 384, 0);
  // 4. qkv = xln @ [Wq|Wk|Wv] + b (bf16 out)
  gemm_v7<float, __bf16, false><<<dim3(swz_grid(79, 3)), b256, 0, stream>>>(
      xln, Wt + (size_t)640 * 128, bqkv, qkv, nullptr, N_NODES, 79, 3, 384, 0);
  // 5. fm = silu(f_ij @ [Wdk|Wdv|Wf] + b)
  gemm_v7<float, __bf16, false><<<dim3(swz_grid(500, 3)), b256, 0, stream>>>(
      f_ij, Wt + (size_t)1024 * 128, bfm, fm, nullptr, N_EDGES, 500, 3, 384, 1);
  // 6. message -> vm (bf16)
  msg_kernel<<<dim3(N_EDGES / 2), b256, 0, stream>>>(qkv, fm, r_ij, ei, vm);
  // 7. s = silu(vm @ W_s + b)
  gemm_v7<__bf16, __bf16, false><<<dim3(swz_grid(500, 2)), b256, 0, stream>>>(
      vm, Wt + (size_t)1408 * 128, b_s, s_buf, nullptr, N_EDGES, 500, 2, 256, 1);
  // 8. gather into x_agg and dvec (no atomics)
  gather_kernel<<<dim3(N_NODES / 2), b256, 0, stream>>>(vm, s_buf, vecw, d_ij, ei, rowptr,
                                                        elist, x_agg, dvec);
  // 9. edge update -> df (reads big vt/vs + fm dfw)
  edgeupd_kernel<<<dim3(N_EDGES / 2), b256, 0, stream>>>(big, d_ij, fm, ei, df);
  // 10. o = x_agg @ W_o + b (f32; overwrites qkv region: consumed in 6)
  gemm_v7<float, float, false><<<dim3(swz_grid(79, 3)), b256, 0, stream>>>(
      x_agg, Wt + (size_t)1664 * 128, b_o, o_buf, nullptr, N_NODES, 79, 3, 384, 0);
  // 11. final: dx, dvec += vec3*o1
  final_kernel<<<dim3(5000), b256, 0, stream>>>(o_buf, vdot, big, dx, dvec, N_NODES);
}

// Round 12
// 328.692 us; speedup vs baseline: 1.2986x; 1.1622x over previous
//
#include <hip/hip_runtime.h>
#include <hip/hip_bf16.h>
#include <math.h>

#define N_NODES 10000
#define N_EDGES 64000
#define H 128
#define L 8
#define NL (N_NODES * L)

typedef __attribute__((ext_vector_type(4))) float f32x4;
typedef __attribute__((ext_vector_type(8))) __bf16 bf16x8;

__device__ __forceinline__ float silu_f(float x) { return x / (1.f + __expf(-x)); }

// ---------------- LayerNorm: one wave per node ----------------
__global__ __launch_bounds__(256) void ln_kernel(const float* __restrict__ x,
                                                 const float* __restrict__ g,
                                                 const float* __restrict__ b,
                                                 float* __restrict__ out, int n_nodes) {
  int wave = threadIdx.x >> 6;
  int lane = threadIdx.x & 63;
  int n = blockIdx.x * 4 + wave;
  if (n >= n_nodes) return;
  const float* xr = x + (size_t)n * H;
  float a0 = xr[lane], a1 = xr[lane + 64];
  float s = a0 + a1;
#pragma unroll
  for (int off = 32; off >= 1; off >>= 1) s += __shfl_xor(s, off, 64);
  float mu = s * (1.f / H);
  float d0 = a0 - mu, d1 = a1 - mu;
  float v = d0 * d0 + d1 * d1;
#pragma unroll
  for (int off = 32; off >= 1; off >>= 1) v += __shfl_xor(v, off, 64);
  float rstd = rsqrtf(v * (1.f / H) + 1e-5f);
  float* orow = out + (size_t)n * H;
  orow[lane] = d0 * rstd * g[lane] + b[lane];
  orow[lane + 64] = d1 * rstd * g[lane + 64] + b[lane + 64];
}

// ---------------- vecw = vec * vln_w  -> bf16 ----------------
__global__ __launch_bounds__(256) void vecw_kernel(const float* __restrict__ vec,
                                                   const float* __restrict__ w,
                                                   __bf16* __restrict__ out, size_t total8) {
  size_t i = (size_t)blockIdx.x * blockDim.x + threadIdx.x;
  size_t stride = (size_t)gridDim.x * blockDim.x;
  for (; i < total8; i += stride) {
    size_t base = i * 8;
    f32x4 a = *(const f32x4*)(vec + base);
    f32x4 b = *(const f32x4*)(vec + base + 4);
    int c = (int)(base & 127);
    bf16x8 h;
    h[0] = (__bf16)(a[0] * w[c + 0]); h[1] = (__bf16)(a[1] * w[c + 1]);
    h[2] = (__bf16)(a[2] * w[c + 2]); h[3] = (__bf16)(a[3] * w[c + 3]);
    h[4] = (__bf16)(b[0] * w[c + 4]); h[5] = (__bf16)(b[1] * w[c + 5]);
    h[6] = (__bf16)(b[2] * w[c + 6]); h[7] = (__bf16)(b[3] * w[c + 7]);
    *(bf16x8*)(out + base) = h;
  }
}

// ---------------- weight convert into one [2048][128] bf16 table ----------------
// col map: [0,384) Wvec | [384,512) Wtrg | [512,640) Wsrc | [640,768) Wq | [768,896) Wk
//          | [896,1024) Wv | [1024,1152) Wdk | [1152,1280) Wdv | [1280,1408) Wf
//          | [1408,1664) Ws | [1664,2048) Wo
__global__ __launch_bounds__(256) void wconv_kernel(
    const float* __restrict__ Wvec, const float* __restrict__ Wq, const float* __restrict__ Wk,
    const float* __restrict__ Wv, const float* __restrict__ Wdk, const float* __restrict__ Wdv,
    const float* __restrict__ Ws, const float* __restrict__ Wtrg, const float* __restrict__ Wsrc,
    const float* __restrict__ Wf, const float* __restrict__ Wo,
    const float* __restrict__ bq, const float* __restrict__ bk, const float* __restrict__ bv,
    const float* __restrict__ bdk, const float* __restrict__ bdv, const float* __restrict__ bf,
    __bf16* __restrict__ Wt, float* __restrict__ bqkv, float* __restrict__ bfm) {
  int bid = blockIdx.x;
  int t = threadIdx.x;
  if (bid >= 256) {
    if (bid == 256) {
      if (t < 128) { bqkv[t] = bq[t]; bqkv[128 + t] = bk[t]; bqkv[256 + t] = bv[t]; }
    } else {
      if (t < 128) { bfm[t] = bdk[t]; bfm[128 + t] = bdv[t]; bfm[256 + t] = bf[t]; }
    }
    return;
  }
  int ct = bid >> 2, kt = bid & 3;
  int gc0 = ct * 32;
  const float* W; int ldw, sc0;
  if      (gc0 < 384)  { W = Wvec; ldw = 384; sc0 = gc0; }
  else if (gc0 < 512)  { W = Wtrg; ldw = 128; sc0 = gc0 - 384; }
  else if (gc0 < 640)  { W = Wsrc; ldw = 128; sc0 = gc0 - 512; }
  else if (gc0 < 768)  { W = Wq;   ldw = 128; sc0 = gc0 - 640; }
  else if (gc0 < 896)  { W = Wk;   ldw = 128; sc0 = gc0 - 768; }
  else if (gc0 < 1024) { W = Wv;   ldw = 128; sc0 = gc0 - 896; }
  else if (gc0 < 1152) { W = Wdk;  ldw = 128; sc0 = gc0 - 1024; }
  else if (gc0 < 1280) { W = Wdv;  ldw = 128; sc0 = gc0 - 1152; }
  else if (gc0 < 1408) { W = Wf;   ldw = 128; sc0 = gc0 - 1280; }
  else if (gc0 < 1664) { W = Ws;   ldw = 256; sc0 = gc0 - 1408; }
  else                 { W = Wo;   ldw = 384; sc0 = gc0 - 1664; }
  __shared__ float tile[32][33];
  int tx = t & 31, ty = t >> 5;
#pragma unroll
  for (int i = 0; i < 4; ++i)
    tile[ty + i * 8][tx] = W[(size_t)(kt * 32 + ty + i * 8) * ldw + sc0 + tx];
  __syncthreads();
#pragma unroll
  for (int i = 0; i < 4; ++i)
    Wt[(size_t)(gc0 + ty + i * 8) * 128 + kt * 32 + tx] = (__bf16)tile[tx][ty + i * 8];
}

// ---------------- vdot GEMM: dedicated kernel, no spill ----------------
// vdot[node][c] = sum_l (A@W1)[row][c] * (A@W2)[row][c], rows = node*8+l.
// launch_bounds(256,2): VGPR budget 256 holds pacc(64)+acc(64)+frags(~32) without scratch.
__global__ __launch_bounds__(256, 2) void vdot_gemm(const __bf16* __restrict__ A,
                                                    const __bf16* __restrict__ Bt,
                                                    float* __restrict__ vdot) {
  __shared__ __bf16 As[128 * 128];
  const int tid = threadIdx.x;
  const int lane = tid & 63;
  const int wave = tid >> 6;
  const int wm = wave >> 1, wn = wave & 1;
  const int row0 = blockIdx.x * 128;

#pragma unroll
  for (int i = 0; i < 8; ++i) {
    int c = tid + i * 256;
    int row = c >> 4, k8 = c & 15;
    int k8s = k8 ^ (row & 7);
    const __bf16* src = A + (size_t)(row0 + row) * 128 + k8s * 8;
    __builtin_amdgcn_global_load_lds((const __attribute__((address_space(1))) void*)src,
                                     (__attribute__((address_space(3))) void*)(As + c * 8),
                                     16, 0, 0);
  }
  __syncthreads();

  f32x4 pacc[4][4], acc[4][4];
#pragma unroll
  for (int mi = 0; mi < 4; ++mi)
#pragma unroll
    for (int ni = 0; ni < 4; ++ni) {
      pacc[mi][ni] = f32x4{0.f, 0.f, 0.f, 0.f};
      acc[mi][ni] = f32x4{0.f, 0.f, 0.f, 0.f};
    }
#pragma unroll
  for (int ct = 0; ct < 2; ++ct) {
    const __bf16* Bbase =
        Bt + ((size_t)(ct * 128 + wn * 64 + (lane & 15)) << 7) + ((lane >> 4) << 3);
#pragma unroll
    for (int ks = 0; ks < 4; ++ks) {
      bf16x8 b[4];
#pragma unroll
      for (int ni = 0; ni < 4; ++ni) b[ni] = *(const bf16x8*)(Bbase + (ni << 11) + (ks << 5));
      bf16x8 a[4];
#pragma unroll
      for (int mi = 0; mi < 4; ++mi) {
        int row = wm * 64 + mi * 16 + (lane & 15);
        int byte = (row * 256 + ks * 64 + ((lane >> 4) << 4)) ^ ((row & 7) << 4);
        a[mi] = *(const bf16x8*)((const char*)As + byte);
      }
      if (ct == 0) {
#pragma unroll
        for (int mi = 0; mi < 4; ++mi)
#pragma unroll
          for (int ni = 0; ni < 4; ++ni)
            pacc[mi][ni] =
                __builtin_amdgcn_mfma_f32_16x16x32_bf16(a[mi], b[ni], pacc[mi][ni], 0, 0, 0);
      } else {
#pragma unroll
        for (int mi = 0; mi < 4; ++mi)
#pragma unroll
          for (int ni = 0; ni < 4; ++ni)
            acc[mi][ni] =
                __builtin_amdgcn_mfma_f32_16x16x32_bf16(a[mi], b[ni], acc[mi][ni], 0, 0, 0);
      }
    }
  }
  // vdot[node][c] = sum over 8 L-rows of vec1*vec2
#pragma unroll
  for (int mi = 0; mi < 4; ++mi) {
#pragma unroll
    for (int ni = 0; ni < 4; ++ni) {
      float sr = pacc[mi][ni][0] * acc[mi][ni][0] + pacc[mi][ni][1] * acc[mi][ni][1] +
                 pacc[mi][ni][2] * acc[mi][ni][2] + pacc[mi][ni][3] * acc[mi][ni][3];
      sr += __shfl_xor(sr, 16, 64);
      if ((lane & 16) == 0) {
        int node = (row0 >> 3) + wm * 8 + mi * 2 + (lane >> 5);
        int col = wn * 64 + ni * 16 + (lane & 15);
        vdot[(size_t)node * 128 + col] = sr;
      }
    }
  }
}

// ---------------- MFMA GEMM v8: uniform (no FUSE); 1D XCD-swizzled grid ----------
// bid = xg*(ny*8) + y*8 + xi, x = xg*8+xi: all ny y-siblings of an x share bid%8 (same XCD)
// so the A-tile is fetched to that XCD's L2 once. As-only LDS (32KB, swizzled); Cs staging
// aliased into As (dead after epilogue barrier). Plain cached 16B C-stores.
template <typename AT, typename CT>
__global__ __launch_bounds__(256, 3) void gemm_v8(const AT* __restrict__ A,
                                                  const __bf16* __restrict__ Bt,
                                                  const float* __restrict__ bias,
                                                  CT* __restrict__ C, int M, int nx, int ny,
                                                  int ldc, int act) {
  __shared__ __bf16 As[128 * 128];
  __bf16* Cs = As;  // reused for C staging after MFMA (post-barrier; 32*136 <= 128*128)
  const int bid = blockIdx.x;
  const int xi = bid & 7;
  const int rem = bid >> 3;
  const int y = rem % ny;
  const int x = (rem / ny) * 8 + xi;
  if (x >= nx) return;
  const int tid = threadIdx.x;
  const int lane = tid & 63;
  const int wave = tid >> 6;
  const int wm = wave >> 1, wn = wave & 1;
  const int row0 = x * 128;

  if constexpr (sizeof(AT) == 2) {
#pragma unroll
    for (int i = 0; i < 8; ++i) {
      int c = tid + i * 256;  // 16B chunk; LDS dest linear
      int row = c >> 4, k8 = c & 15;
      int k8s = k8 ^ (row & 7);  // inverse-swizzled source == read-side XOR
      const AT* src = A + (size_t)(row0 + row) * 128 + k8s * 8;
      __builtin_amdgcn_global_load_lds((const __attribute__((address_space(1))) void*)src,
                                       (__attribute__((address_space(3))) void*)(As + c * 8),
                                       16, 0, 0);
    }
  } else {
#pragma unroll
    for (int i = 0; i < 8; ++i) {
      int c = tid + i * 256;
      int row = c >> 4, k8 = c & 15;
      int gm = row0 + row;
      bf16x8 h = {};
      if (gm < M) {
        f32x4 f0 = *(const f32x4*)(A + (size_t)gm * 128 + k8 * 8);
        f32x4 f1 = *(const f32x4*)(A + (size_t)gm * 128 + k8 * 8 + 4);
        h[0] = (__bf16)f0[0]; h[1] = (__bf16)f0[1]; h[2] = (__bf16)f0[2]; h[3] = (__bf16)f0[3];
        h[4] = (__bf16)f1[0]; h[5] = (__bf16)f1[1]; h[6] = (__bf16)f1[2]; h[7] = (__bf16)f1[3];
      }
      int byte = (c * 16) ^ ((row & 7) << 4);
      *(bf16x8*)((char*)As + byte) = h;
    }
  }
  __syncthreads();

  // hoist all 16 B fragments (one wait; weights L2-hot)
  const __bf16* Bbase =
      Bt + ((size_t)(y * 128 + wn * 64 + (lane & 15)) << 7) + ((lane >> 4) << 3);
  bf16x8 b[4][4];
#pragma unroll
  for (int ks = 0; ks < 4; ++ks)
#pragma unroll
    for (int ni = 0; ni < 4; ++ni) b[ks][ni] = *(const bf16x8*)(Bbase + (ni << 11) + (ks << 5));

  f32x4 acc[4][4];
#pragma unroll
  for (int mi = 0; mi < 4; ++mi)
#pragma unroll
    for (int ni = 0; ni < 4; ++ni) acc[mi][ni] = f32x4{0.f, 0.f, 0.f, 0.f};

#pragma unroll
  for (int ks = 0; ks < 4; ++ks) {
    bf16x8 a[4];
#pragma unroll
    for (int mi = 0; mi < 4; ++mi) {
      int row = wm * 64 + mi * 16 + (lane & 15);
      int byte = (row * 256 + ks * 64 + ((lane >> 4) << 4)) ^ ((row & 7) << 4);
      a[mi] = *(const bf16x8*)((const char*)As + byte);
    }
#pragma unroll
    for (int mi = 0; mi < 4; ++mi)
#pragma unroll
      for (int ni = 0; ni < 4; ++ni)
        acc[mi][ni] =
            __builtin_amdgcn_mfma_f32_16x16x32_bf16(a[mi], b[ks][ni], acc[mi][ni], 0, 0, 0);
  }

  const int cstore = y * 128;
  if constexpr (sizeof(CT) == 2) {
    // staged epilogue: acc -> LDS (padded, aliases As) -> 16B coalesced stores
#pragma unroll
    for (int mi = 0; mi < 4; ++mi) {
      __syncthreads();  // all MFMA-reads of As done / previous stage consumed
      int rl = (wm << 4) | ((lane >> 4) << 2);
#pragma unroll
      for (int ni = 0; ni < 4; ++ni) {
        int col = wn * 64 + ni * 16 + (lane & 15);
        float bv = bias ? bias[y * 128 + col] : 0.f;
#pragma unroll
        for (int r = 0; r < 4; ++r) {
          float xv = acc[mi][ni][r] + bv;
          if (act) xv = silu_f(xv);
          Cs[(rl + r) * 136 + col] = (__bf16)xv;
        }
      }
      __syncthreads();
      // 32 rows x 16 chunks of 8 bf16 = 512 stores; 2 per thread
#pragma unroll
      for (int rr = 0; rr < 2; ++rr) {
        int row = (tid >> 4) + rr * 16;
        int chunk = tid & 15;
        bf16x8 v = *(const bf16x8*)(Cs + row * 136 + chunk * 8);
        int grow = row0 + (row >> 4) * 64 + mi * 16 + (row & 15);
        if (grow < M)
          *(bf16x8*)(C + (size_t)grow * ldc + cstore + chunk * 8) = v;
      }
    }
  } else {
#pragma unroll
    for (int mi = 0; mi < 4; ++mi) {
      int rbase = row0 + wm * 64 + mi * 16 + ((lane >> 4) << 2);
#pragma unroll
      for (int ni = 0; ni < 4; ++ni) {
        int gcol = cstore + wn * 64 + ni * 16 + (lane & 15);
        float bv = bias ? bias[y * 128 + wn * 64 + ni * 16 + (lane & 15)] : 0.f;
#pragma unroll
        for (int r = 0; r < 4; ++r) {
          int grow = rbase + r;
          if (grow < M) {
            float xv = acc[mi][ni][r] + bv;
            if (act) xv = silu_f(xv);
            C[(size_t)grow * ldc + gcol] = (CT)xv;
          }
        }
      }
    }
  }
}

// helper: swizzled grid size
static inline int swz_grid(int nx, int ny) { return ((nx + 7) / 8) * ny * 8; }

// ---------------- message: attn + vm per edge (qkv bf16 [N][384]; dk/dv = fm cols 0..255) ----------
__global__ __launch_bounds__(256) void msg_kernel(const __bf16* __restrict__ qkv,
                                                  const __bf16* __restrict__ fm,
                                                  const float* __restrict__ r_ij,
                                                  const int* __restrict__ ei,
                                                  __bf16* __restrict__ vm) {
  int e = blockIdx.x * 2 + (threadIdx.x >> 7);
  int h = threadIdx.x & 127;
  int src = ei[e], dst = ei[N_EDGES + e];
  float qv = (float)qkv[(size_t)dst * 384 + h];
  float kv = (float)qkv[(size_t)src * 384 + 128 + h];
  float vv = (float)qkv[(size_t)src * 384 + 256 + h];
  float t = qv * kv * (float)fm[(size_t)e * 384 + h];
#pragma unroll
  for (int off = 8; off >= 1; off >>= 1) t += __shfl_xor(t, off, 16);
  float r = r_ij[e];
  float cut = 0.5f * (__cosf(0.6283185307f * r) + 1.f);
  cut = (r < 5.f) ? cut : 0.f;
  float attn = silu_f(t) * cut;
  vm[(size_t)e * H + h] = (__bf16)(vv * (float)fm[(size_t)e * 384 + 128 + h] * attn);
}

// ---------------- CSR build: histogram, scan, fill ----------------
__global__ __launch_bounds__(256) void hist_kernel(const int* __restrict__ ei,
                                                   int* __restrict__ cnt) {
  int e = blockIdx.x * 256 + threadIdx.x;
  if (e < N_EDGES) atomicAdd(&cnt[ei[N_EDGES + e]], 1);
}

__global__ __launch_bounds__(1024) void scan_kernel(const int* __restrict__ cnt,
                                                    int* __restrict__ rowptr) {
  __shared__ int wsum[16];
  int t = threadIdx.x;
  int base = t * 10;
  int local[10];
  int s = 0;
#pragma unroll
  for (int i = 0; i < 10; ++i) {
    int v = (base + i < N_NODES) ? cnt[base + i] : 0;
    local[i] = s;
    s += v;
  }
  int lane = t & 63, wave = t >> 6;
  int inc = s;
#pragma unroll
  for (int off = 1; off < 64; off <<= 1) {
    int u = __shfl_up(inc, off, 64);
    if (lane >= off) inc += u;
  }
  if (lane == 63) wsum[wave] = inc;
  __syncthreads();
  if (t == 0) {
    int acc = 0;
#pragma unroll
    for (int w = 0; w < 16; ++w) { int v = wsum[w]; wsum[w] = acc; acc += v; }
  }
  __syncthreads();
  int excl = inc - s + wsum[wave];
#pragma unroll
  for (int i = 0; i < 10; ++i)
    if (base + i <= N_NODES) rowptr[base + i] = excl + local[i];
}

__global__ __launch_bounds__(256) void fill_kernel(const int* __restrict__ ei,
                                                   const int* __restrict__ rowptr,
                                                   int* __restrict__ cursor,
                                                   int* __restrict__ elist) {
  int e = blockIdx.x * 256 + threadIdx.x;
  if (e < N_EDGES) {
    int d = ei[N_EDGES + e];
    int p = atomicAdd(&cursor[d], 1);
    elist[rowptr[d] + p] = e;
  }
}

// ---------------- gather: x_agg = Σ vm ; dvec = Σ vec_m (no atomics) ----------------
__global__ __launch_bounds__(256) void gather_kernel(const __bf16* __restrict__ vm,
                                                     const __bf16* __restrict__ s,
                                                     const __bf16* __restrict__ vecw,
                                                     const float* __restrict__ d_ij,
                                                     const int* __restrict__ ei,
                                                     const int* __restrict__ rowptr,
                                                     const int* __restrict__ elist,
                                                     float* __restrict__ x_agg,
                                                     float* __restrict__ dvec) {
  int n = blockIdx.x * 2 + (threadIdx.x >> 7);
  int h = threadIdx.x & 127;
  if (n >= N_NODES) return;
  int beg = rowptr[n], end = rowptr[n + 1];
  float ax = 0.f;
  float av[L] = {};
  for (int p = beg; p < end; ++p) {
    int e = elist[p];
    int src = ei[e];
    ax += (float)vm[(size_t)e * H + h];
    float s1 = (float)s[(size_t)e * 256 + h];
    float s2 = (float)s[(size_t)e * 256 + 128 + h];
    const __bf16* vrow = vecw + (size_t)src * L * H + h;
    const float* dd = d_ij + (size_t)e * L;
#pragma unroll
    for (int l = 0; l < L; l++) av[l] += (float)vrow[l * H] * s1 + s2 * dd[l];
  }
  x_agg[(size_t)n * H + h] = ax;
  float* drow = dvec + (size_t)n * L * H + h;
#pragma unroll
  for (int l = 0; l < L; l++) drow[l * H] = av[l];
}

// ---------------- edge update (big [NL][384]: vec3 @0, vt @128, vs @256; dfw = fm @256) ----------------
__global__ __launch_bounds__(256) void edgeupd_kernel(const __bf16* __restrict__ big,
                                                      const float* __restrict__ d_ij,
                                                      const __bf16* __restrict__ fm,
                                                      const int* __restrict__ ei,
                                                      float* __restrict__ df) {
  int e = blockIdx.x * 2 + (threadIdx.x >> 7);
  int h = threadIdx.x & 127;
  int src = ei[e], dst = ei[N_EDGES + e];
  float d[L];
  float sd2 = 0.f;
#pragma unroll
  for (int l = 0; l < L; l++) {
    d[l] = d_ij[(size_t)e * L + l];
    sd2 += d[l] * d[l];
  }
  const __bf16* arow = big + (size_t)dst * 8 * 384 + 128 + h;
  const __bf16* brow = big + (size_t)src * 8 * 384 + 256 + h;
  float dot = 0.f, p1 = 0.f, p2 = 0.f;
#pragma unroll
  for (int l = 0; l < L; l++) {
    float a = (float)arow[l * 384], bb = (float)brow[l * 384];
    dot += a * bb;
    p1 += a * d[l];
    p2 += bb * d[l];
  }
  float wdot = dot - p1 * p2 * (2.f - sd2);
  df[(size_t)e * H + h] = (float)fm[(size_t)e * 384 + 256 + h] * wdot;
}

// ---------------- final node update (vec3 = big cols 0..127) ----------------
__global__ __launch_bounds__(256) void final_kernel(const float* __restrict__ o,
                                                    const float* __restrict__ vdot,
                                                    const __bf16* __restrict__ big,
                                                    float* __restrict__ dx,
                                                    float* __restrict__ dvec, int n_nodes) {
  int n = blockIdx.x * 2 + (threadIdx.x >> 7);
  int h = threadIdx.x & 127;
  if (n >= n_nodes) return;
  float o1 = o[(size_t)n * 384 + h];
  float o2 = o[(size_t)n * 384 + 128 + h];
  float o3 = o[(size_t)n * 384 + 256 + h];
  dx[(size_t)n * H + h] = vdot[(size_t)n * H + h] * o2 + o3;
  float* drow = dvec + (size_t)n * L * H + h;
  const __bf16* v3 = big + (size_t)n * 8 * 384 + h;
#pragma unroll
  for (int l = 0; l < L; l++) drow[l * H] += (float)v3[l * 384] * o1;
}

extern "C" void kernel_launch(void* const* d_in, const int* in_sizes, int n_in, void* d_out,
                              int out_size, void* d_ws, size_t ws_size, hipStream_t stream) {
  const float* x = (const float*)d_in[0];
  const float* vec = (const float*)d_in[1];
  const float* f_ij = (const float*)d_in[2];
  const float* d_ij = (const float*)d_in[3];
  const float* r_ij = (const float*)d_in[4];
  const int* ei = (const int*)d_in[5];
  const float* ln_g = (const float*)d_in[6];
  const float* ln_b = (const float*)d_in[7];
  const float* vln_w = (const float*)d_in[8];
  const float* W_vec = (const float*)d_in[9];
  const float* W_q = (const float*)d_in[10];
  const float* b_q = (const float*)d_in[11];
  const float* W_k = (const float*)d_in[12];
  const float* b_k = (const float*)d_in[13];
  const float* W_v = (const float*)d_in[14];
  const float* b_v = (const float*)d_in[15];
  const float* W_dk = (const float*)d_in[16];
  const float* b_dk = (const float*)d_in[17];
  const float* W_dv = (const float*)d_in[18];
  const float* b_dv = (const float*)d_in[19];
  const float* W_s = (const float*)d_in[20];
  const float* b_s = (const float*)d_in[21];
  const float* W_f = (const float*)d_in[22];
  const float* b_f = (const float*)d_in[23];
  const float* W_src = (const float*)d_in[24];
  const float* W_trg = (const float*)d_in[25];
  const float* W_o = (const float*)d_in[26];
  const float* b_o = (const float*)d_in[27];

  float* out = (float*)d_out;
  float* dx = out;
  float* dvec = out + (size_t)N_NODES * H;
  float* df = dvec + (size_t)N_NODES * L * H;

  // ---- workspace plan (~207 MB; offsets in f32 slots) ----
  float* ws = (float*)d_ws;
  __bf16* vecw = (__bf16*)ws;                 // NL*128 bf16
  __bf16* big = (__bf16*)(ws + 5120000);      // NL*384 bf16: [vec3 128 | vt 128 | vs 128]
  __bf16* fm = (__bf16*)(ws + 20480000);      // E*384 bf16: [dk | dv | dfw]
  __bf16* vm = (__bf16*)(ws + 32768000);      // E*128 bf16
  __bf16* s_buf = (__bf16*)(ws + 36864000);   // E*256 bf16
  __bf16* qkv = (__bf16*)(ws + 45056000);     // N*384 bf16 (region reused as o_buf f32)
  float* xln = ws + 48896000;                 // N*128 f32 (reused as x_agg)
  float* vdot = ws + 50176000;                // N*128 f32
  __bf16* Wt = (__bf16*)(ws + 51456000);      // [2048][128] bf16
  float* bqkv = ws + 51456000 + 131072;       // 384
  float* bfm = bqkv + 384;                    // 384
  int* rowptr = (int*)(bfm + 384);            // 10,001
  int* elist = rowptr + 10001;                // 64,000
  int* cnt = elist + 64000;                   // 10,000
  int* cursor = cnt + 10000;                  // 10,000

  float* o_buf = ws + 45056000;  // overwrites qkv after it's consumed (step 6)
  float* x_agg = xln;

  dim3 b256(256);

  // CSR build (depends only on ei)
  hipMemsetAsync(cnt, 0, N_NODES * sizeof(int), stream);
  hipMemsetAsync(cursor, 0, N_NODES * sizeof(int), stream);
  hist_kernel<<<dim3((N_EDGES + 255) / 256), b256, 0, stream>>>(ei, cnt);
  scan_kernel<<<dim3(1), dim3(1024), 0, stream>>>(cnt, rowptr);
  fill_kernel<<<dim3((N_EDGES + 255) / 256), b256, 0, stream>>>(ei, rowptr, cursor, elist);

  // 0. weight convert/transpose + bias concat
  wconv_kernel<<<dim3(258), b256, 0, stream>>>(W_vec, W_q, W_k, W_v, W_dk, W_dv, W_s, W_trg,
                                               W_src, W_f, W_o, b_q, b_k, b_v, b_dk, b_dv, b_f,
                                               Wt, bqkv, bfm);
  // 1. x_ln = layernorm(x)
  ln_kernel<<<dim3((N_NODES + 3) / 4), b256, 0, stream>>>(x, ln_g, ln_b, xln, N_NODES);
  // 2. vecw = vec * vln_w (bf16)
  vecw_kernel<<<dim3(2048), b256, 0, stream>>>(vec, vln_w, vecw, (size_t)NL * H / 8);
  // 3a. vdot (dedicated, no-spill kernel; Wt rows 0..255 = vec1|vec2)
  vdot_gemm<<<dim3(625), b256, 0, stream>>>(vecw, Wt, vdot);
  // 3b. big = vecw @ [vec3|Wtrg|Wsrc] (Wt rows 256..639); XCD-swizzled, ny=3
  gemm_v8<__bf16, __bf16><<<dim3(swz_grid(625, 3)), b256, 0, stream>>>(
      vecw, Wt + (size_t)256 * 128, nullptr, big, NL, 625, 3, 384, 0);
  // 4. qkv = xln @ [Wq|Wk|Wv] + b (bf16 out)
  gemm_v8<float, __bf16><<<dim3(swz_grid(79, 3)), b256, 0, stream>>>(
      xln, Wt + (size_t)640 * 128, bqkv, qkv, N_NODES, 79, 3, 384, 0);
  // 5. fm = silu(f_ij @ [Wdk|Wdv|Wf] + b)
  gemm_v8<float, __bf16><<<dim3(swz_grid(500, 3)), b256, 0, stream>>>(
      f_ij, Wt + (size_t)1024 * 128, bfm, fm, N_EDGES, 500, 3, 384, 1);
  // 6. message -> vm (bf16)
  msg_kernel<<<dim3(N_EDGES / 2), b256, 0, stream>>>(qkv, fm, r_ij, ei, vm);
  // 7. s = silu(vm @ W_s + b)
  gemm_v8<__bf16, __bf16><<<dim3(swz_grid(500, 2)), b256, 0, stream>>>(
      vm, Wt + (size_t)1408 * 128, b_s, s_buf, N_EDGES, 500, 2, 256, 1);
  // 8. gather into x_agg and dvec (no atomics)
  gather_kernel<<<dim3(N_NODES / 2), b256, 0, stream>>>(vm, s_buf, vecw, d_ij, ei, rowptr,
                                                        elist, x_agg, dvec);
  // 9. edge update -> df (reads big vt/vs + fm dfw)
  edgeupd_kernel<<<dim3(N_EDGES / 2), b256, 0, stream>>>(big, d_ij, fm, ei, df);
  // 10. o = x_agg @ W_o + b (f32; overwrites qkv region: consumed in 6)
  gemm_v8<float, float><<<dim3(swz_grid(79, 3)), b256, 0, stream>>>(
      x_agg, Wt + (size_t)1664 * 128, b_o, o_buf, N_NODES, 79, 3, 384, 0);
  // 11. final: dx, dvec += vec3*o1
  final_kernel<<<dim3(5000), b256, 0, stream>>>(o_buf, vdot, big, dx, dvec, N_NODES);
}

// Round 13
// 326.553 us; speedup vs baseline: 1.3071x; 1.0065x over previous
//
#include <hip/hip_runtime.h>
#include <hip/hip_bf16.h>
#include <math.h>

#define N_NODES 10000
#define N_EDGES 64000
#define H 128
#define L 8
#define NL (N_NODES * L)

typedef __attribute__((ext_vector_type(4))) float f32x4;
typedef __attribute__((ext_vector_type(8))) __bf16 bf16x8;

__device__ __forceinline__ float silu_f(float x) { return x / (1.f + __expf(-x)); }

// ---------------- LayerNorm: one wave per node -> bf16 out ----------------
__global__ __launch_bounds__(256) void ln_kernel(const float* __restrict__ x,
                                                 const float* __restrict__ g,
                                                 const float* __restrict__ b,
                                                 __bf16* __restrict__ out, int n_nodes) {
  int wave = threadIdx.x >> 6;
  int lane = threadIdx.x & 63;
  int n = blockIdx.x * 4 + wave;
  if (n >= n_nodes) return;
  const float* xr = x + (size_t)n * H;
  float a0 = xr[lane], a1 = xr[lane + 64];
  float s = a0 + a1;
#pragma unroll
  for (int off = 32; off >= 1; off >>= 1) s += __shfl_xor(s, off, 64);
  float mu = s * (1.f / H);
  float d0 = a0 - mu, d1 = a1 - mu;
  float v = d0 * d0 + d1 * d1;
#pragma unroll
  for (int off = 32; off >= 1; off >>= 1) v += __shfl_xor(v, off, 64);
  float rstd = rsqrtf(v * (1.f / H) + 1e-5f);
  __bf16* orow = out + (size_t)n * H;
  orow[lane] = (__bf16)(d0 * rstd * g[lane] + b[lane]);
  orow[lane + 64] = (__bf16)(d1 * rstd * g[lane + 64] + b[lane + 64]);
}

// ---------------- vecw = vec * vln_w  -> bf16 ----------------
__global__ __launch_bounds__(256) void vecw_kernel(const float* __restrict__ vec,
                                                   const float* __restrict__ w,
                                                   __bf16* __restrict__ out, size_t total8) {
  size_t i = (size_t)blockIdx.x * blockDim.x + threadIdx.x;
  size_t stride = (size_t)gridDim.x * blockDim.x;
  for (; i < total8; i += stride) {
    size_t base = i * 8;
    f32x4 a = *(const f32x4*)(vec + base);
    f32x4 b = *(const f32x4*)(vec + base + 4);
    int c = (int)(base & 127);
    bf16x8 h;
    h[0] = (__bf16)(a[0] * w[c + 0]); h[1] = (__bf16)(a[1] * w[c + 1]);
    h[2] = (__bf16)(a[2] * w[c + 2]); h[3] = (__bf16)(a[3] * w[c + 3]);
    h[4] = (__bf16)(b[0] * w[c + 4]); h[5] = (__bf16)(b[1] * w[c + 5]);
    h[6] = (__bf16)(b[2] * w[c + 6]); h[7] = (__bf16)(b[3] * w[c + 7]);
    *(bf16x8*)(out + base) = h;
  }
}

// ---------------- f32 -> bf16 bulk convert ----------------
__global__ __launch_bounds__(256) void f2b_kernel(const float* __restrict__ in,
                                                  __bf16* __restrict__ out, size_t total8) {
  size_t i = (size_t)blockIdx.x * blockDim.x + threadIdx.x;
  size_t stride = (size_t)gridDim.x * blockDim.x;
  for (; i < total8; i += stride) {
    size_t base = i * 8;
    f32x4 a = *(const f32x4*)(in + base);
    f32x4 b = *(const f32x4*)(in + base + 4);
    bf16x8 h;
    h[0] = (__bf16)a[0]; h[1] = (__bf16)a[1]; h[2] = (__bf16)a[2]; h[3] = (__bf16)a[3];
    h[4] = (__bf16)b[0]; h[5] = (__bf16)b[1]; h[6] = (__bf16)b[2]; h[7] = (__bf16)b[3];
    *(bf16x8*)(out + base) = h;
  }
}

// ---------------- weight convert into one [2048][128] bf16 table ----------------
// col map: [0,384) Wvec | [384,512) Wtrg | [512,640) Wsrc | [640,768) Wq | [768,896) Wk
//          | [896,1024) Wv | [1024,1152) Wdk | [1152,1280) Wdv | [1280,1408) Wf
//          | [1408,1664) Ws | [1664,2048) Wo
__global__ __launch_bounds__(256) void wconv_kernel(
    const float* __restrict__ Wvec, const float* __restrict__ Wq, const float* __restrict__ Wk,
    const float* __restrict__ Wv, const float* __restrict__ Wdk, const float* __restrict__ Wdv,
    const float* __restrict__ Ws, const float* __restrict__ Wtrg, const float* __restrict__ Wsrc,
    const float* __restrict__ Wf, const float* __restrict__ Wo,
    const float* __restrict__ bq, const float* __restrict__ bk, const float* __restrict__ bv,
    const float* __restrict__ bdk, const float* __restrict__ bdv, const float* __restrict__ bf,
    __bf16* __restrict__ Wt, float* __restrict__ bqkv, float* __restrict__ bfm) {
  int bid = blockIdx.x;
  int t = threadIdx.x;
  if (bid >= 256) {
    if (bid == 256) {
      if (t < 128) { bqkv[t] = bq[t]; bqkv[128 + t] = bk[t]; bqkv[256 + t] = bv[t]; }
    } else {
      if (t < 128) { bfm[t] = bdk[t]; bfm[128 + t] = bdv[t]; bfm[256 + t] = bf[t]; }
    }
    return;
  }
  int ct = bid >> 2, kt = bid & 3;
  int gc0 = ct * 32;
  const float* W; int ldw, sc0;
  if      (gc0 < 384)  { W = Wvec; ldw = 384; sc0 = gc0; }
  else if (gc0 < 512)  { W = Wtrg; ldw = 128; sc0 = gc0 - 384; }
  else if (gc0 < 640)  { W = Wsrc; ldw = 128; sc0 = gc0 - 512; }
  else if (gc0 < 768)  { W = Wq;   ldw = 128; sc0 = gc0 - 640; }
  else if (gc0 < 896)  { W = Wk;   ldw = 128; sc0 = gc0 - 768; }
  else if (gc0 < 1024) { W = Wv;   ldw = 128; sc0 = gc0 - 896; }
  else if (gc0 < 1152) { W = Wdk;  ldw = 128; sc0 = gc0 - 1024; }
  else if (gc0 < 1280) { W = Wdv;  ldw = 128; sc0 = gc0 - 1152; }
  else if (gc0 < 1408) { W = Wf;   ldw = 128; sc0 = gc0 - 1280; }
  else if (gc0 < 1664) { W = Ws;   ldw = 256; sc0 = gc0 - 1408; }
  else                 { W = Wo;   ldw = 384; sc0 = gc0 - 1664; }
  __shared__ float tile[32][33];
  int tx = t & 31, ty = t >> 5;
#pragma unroll
  for (int i = 0; i < 4; ++i)
    tile[ty + i * 8][tx] = W[(size_t)(kt * 32 + ty + i * 8) * ldw + sc0 + tx];
  __syncthreads();
#pragma unroll
  for (int i = 0; i < 4; ++i)
    Wt[(size_t)(gc0 + ty + i * 8) * 128 + kt * 32 + tx] = (__bf16)tile[tx][ty + i * 8];
}

// ---------------- vdot GEMM: dedicated kernel, no spill ----------------
__global__ __launch_bounds__(256, 2) void vdot_gemm(const __bf16* __restrict__ A,
                                                    const __bf16* __restrict__ Bt,
                                                    float* __restrict__ vdot) {
  __shared__ __bf16 As[128 * 128];
  const int tid = threadIdx.x;
  const int lane = tid & 63;
  const int wave = tid >> 6;
  const int wm = wave >> 1, wn = wave & 1;
  const int row0 = blockIdx.x * 128;

#pragma unroll
  for (int i = 0; i < 8; ++i) {
    int c = tid + i * 256;
    int row = c >> 4, k8 = c & 15;
    int k8s = k8 ^ (row & 7);
    const __bf16* src = A + (size_t)(row0 + row) * 128 + k8s * 8;
    __builtin_amdgcn_global_load_lds((const __attribute__((address_space(1))) void*)src,
                                     (__attribute__((address_space(3))) void*)(As + c * 8),
                                     16, 0, 0);
  }
  __syncthreads();

  f32x4 pacc[4][4], acc[4][4];
#pragma unroll
  for (int mi = 0; mi < 4; ++mi)
#pragma unroll
    for (int ni = 0; ni < 4; ++ni) {
      pacc[mi][ni] = f32x4{0.f, 0.f, 0.f, 0.f};
      acc[mi][ni] = f32x4{0.f, 0.f, 0.f, 0.f};
    }
#pragma unroll
  for (int ct = 0; ct < 2; ++ct) {
    const __bf16* Bbase =
        Bt + ((size_t)(ct * 128 + wn * 64 + (lane & 15)) << 7) + ((lane >> 4) << 3);
#pragma unroll
    for (int ks = 0; ks < 4; ++ks) {
      bf16x8 b[4];
#pragma unroll
      for (int ni = 0; ni < 4; ++ni) b[ni] = *(const bf16x8*)(Bbase + (ni << 11) + (ks << 5));
      bf16x8 a[4];
#pragma unroll
      for (int mi = 0; mi < 4; ++mi) {
        int row = wm * 64 + mi * 16 + (lane & 15);
        int byte = (row * 256 + ks * 64 + ((lane >> 4) << 4)) ^ ((row & 7) << 4);
        a[mi] = *(const bf16x8*)((const char*)As + byte);
      }
      if (ct == 0) {
#pragma unroll
        for (int mi = 0; mi < 4; ++mi)
#pragma unroll
          for (int ni = 0; ni < 4; ++ni)
            pacc[mi][ni] =
                __builtin_amdgcn_mfma_f32_16x16x32_bf16(a[mi], b[ni], pacc[mi][ni], 0, 0, 0);
      } else {
#pragma unroll
        for (int mi = 0; mi < 4; ++mi)
#pragma unroll
          for (int ni = 0; ni < 4; ++ni)
            acc[mi][ni] =
                __builtin_amdgcn_mfma_f32_16x16x32_bf16(a[mi], b[ni], acc[mi][ni], 0, 0, 0);
      }
    }
  }
#pragma unroll
  for (int mi = 0; mi < 4; ++mi) {
#pragma unroll
    for (int ni = 0; ni < 4; ++ni) {
      float sr = pacc[mi][ni][0] * acc[mi][ni][0] + pacc[mi][ni][1] * acc[mi][ni][1] +
                 pacc[mi][ni][2] * acc[mi][ni][2] + pacc[mi][ni][3] * acc[mi][ni][3];
      sr += __shfl_xor(sr, 16, 64);
      if ((lane & 16) == 0) {
        int node = (row0 >> 3) + wm * 8 + mi * 2 + (lane >> 5);
        int col = wn * 64 + ni * 16 + (lane & 15);
        vdot[(size_t)node * 128 + col] = sr;
      }
    }
  }
}

// ---------------- MFMA GEMM v9: bf16-A only (global_load_lds); XCD-swizzled 1D grid ----------
// All ny y-siblings of an x-tile share bid%8 (same XCD) -> A-tile HBM-fetched once.
// Cs staging aliased into As. bf16-C epilogue stages mi in PAIRS (64x136 = 17.4KB) -> 4 barriers.
template <typename CT>
__global__ __launch_bounds__(256, 3) void gemm_v9(const __bf16* __restrict__ A,
                                                  const __bf16* __restrict__ Bt,
                                                  const float* __restrict__ bias,
                                                  CT* __restrict__ C, int M, int nx, int ny,
                                                  int ldc, int act) {
  __shared__ __bf16 As[128 * 128];
  __bf16* Cs = As;  // post-barrier reuse; 64*136*2B = 17.4KB <= 32KB
  const int bid = blockIdx.x;
  const int xi = bid & 7;
  const int rem = bid >> 3;
  const int y = rem % ny;
  const int x = (rem / ny) * 8 + xi;
  if (x >= nx) return;
  const int tid = threadIdx.x;
  const int lane = tid & 63;
  const int wave = tid >> 6;
  const int wm = wave >> 1, wn = wave & 1;
  const int row0 = x * 128;

#pragma unroll
  for (int i = 0; i < 8; ++i) {
    int c = tid + i * 256;  // 16B chunk; LDS dest linear
    int row = c >> 4, k8 = c & 15;
    int k8s = k8 ^ (row & 7);  // inverse-swizzled source == read-side XOR
    const __bf16* src = A + (size_t)(row0 + row) * 128 + k8s * 8;
    __builtin_amdgcn_global_load_lds((const __attribute__((address_space(1))) void*)src,
                                     (__attribute__((address_space(3))) void*)(As + c * 8),
                                     16, 0, 0);
  }
  __syncthreads();

  // hoist all 16 B fragments (one wait; weights L2-hot)
  const __bf16* Bbase =
      Bt + ((size_t)(y * 128 + wn * 64 + (lane & 15)) << 7) + ((lane >> 4) << 3);
  bf16x8 b[4][4];
#pragma unroll
  for (int ks = 0; ks < 4; ++ks)
#pragma unroll
    for (int ni = 0; ni < 4; ++ni) b[ks][ni] = *(const bf16x8*)(Bbase + (ni << 11) + (ks << 5));

  f32x4 acc[4][4];
#pragma unroll
  for (int mi = 0; mi < 4; ++mi)
#pragma unroll
    for (int ni = 0; ni < 4; ++ni) acc[mi][ni] = f32x4{0.f, 0.f, 0.f, 0.f};

#pragma unroll
  for (int ks = 0; ks < 4; ++ks) {
    bf16x8 a[4];
#pragma unroll
    for (int mi = 0; mi < 4; ++mi) {
      int row = wm * 64 + mi * 16 + (lane & 15);
      int byte = (row * 256 + ks * 64 + ((lane >> 4) << 4)) ^ ((row & 7) << 4);
      a[mi] = *(const bf16x8*)((const char*)As + byte);
    }
#pragma unroll
    for (int mi = 0; mi < 4; ++mi)
#pragma unroll
      for (int ni = 0; ni < 4; ++ni)
        acc[mi][ni] =
            __builtin_amdgcn_mfma_f32_16x16x32_bf16(a[mi], b[ks][ni], acc[mi][ni], 0, 0, 0);
  }

  const int cstore = y * 128;
  if constexpr (sizeof(CT) == 2) {
    // epilogue: mi-pairs through 64x136 LDS -> 16B coalesced stores (4 barriers total)
#pragma unroll
    for (int p = 0; p < 2; ++p) {
      __syncthreads();  // As reads done (p=0) / previous pair consumed (p=1)
      int rl = (wm << 5) | ((lane >> 4) << 2);
#pragma unroll
      for (int q = 0; q < 2; ++q) {
        int mi = 2 * p + q;
#pragma unroll
        for (int ni = 0; ni < 4; ++ni) {
          int col = wn * 64 + ni * 16 + (lane & 15);
          float bv = bias ? bias[cstore + col] : 0.f;
#pragma unroll
          for (int r = 0; r < 4; ++r) {
            float xv = acc[mi][ni][r] + bv;
            if (act) xv = silu_f(xv);
            Cs[(rl + q * 16 + r) * 136 + col] = (__bf16)xv;
          }
        }
      }
      __syncthreads();
      // 64 rows x 16 chunks of 8 bf16 = 1024 stores; 4 per thread
#pragma unroll
      for (int rr = 0; rr < 4; ++rr) {
        int row = (tid >> 4) + rr * 16;  // 0..63
        int chunk = tid & 15;
        bf16x8 v = *(const bf16x8*)(Cs + row * 136 + chunk * 8);
        int grow = row0 + (row >> 5) * 64 + (2 * p + ((row >> 4) & 1)) * 16 + (row & 15);
        if (grow < M)
          *(bf16x8*)(C + (size_t)grow * ldc + cstore + chunk * 8) = v;
      }
    }
  } else {
#pragma unroll
    for (int mi = 0; mi < 4; ++mi) {
      int rbase = row0 + wm * 64 + mi * 16 + ((lane >> 4) << 2);
#pragma unroll
      for (int ni = 0; ni < 4; ++ni) {
        int gcol = cstore + wn * 64 + ni * 16 + (lane & 15);
        float bv = bias ? bias[cstore + wn * 64 + ni * 16 + (lane & 15)] : 0.f;
#pragma unroll
        for (int r = 0; r < 4; ++r) {
          int grow = rbase + r;
          if (grow < M) {
            float xv = acc[mi][ni][r] + bv;
            if (act) xv = silu_f(xv);
            C[(size_t)grow * ldc + gcol] = (CT)xv;
          }
        }
      }
    }
  }
}

// helper: swizzled grid size
static inline int swz_grid(int nx, int ny) { return ((nx + 7) / 8) * ny * 8; }

// ---------------- message: attn + vm per edge (qkv bf16 [N][384]; dk/dv = fm cols 0..255) ----------
__global__ __launch_bounds__(256) void msg_kernel(const __bf16* __restrict__ qkv,
                                                  const __bf16* __restrict__ fm,
                                                  const float* __restrict__ r_ij,
                                                  const int* __restrict__ ei,
                                                  __bf16* __restrict__ vm) {
  int e = blockIdx.x * 2 + (threadIdx.x >> 7);
  int h = threadIdx.x & 127;
  int src = ei[e], dst = ei[N_EDGES + e];
  float qv = (float)qkv[(size_t)dst * 384 + h];
  float kv = (float)qkv[(size_t)src * 384 + 128 + h];
  float vv = (float)qkv[(size_t)src * 384 + 256 + h];
  float t = qv * kv * (float)fm[(size_t)e * 384 + h];
#pragma unroll
  for (int off = 8; off >= 1; off >>= 1) t += __shfl_xor(t, off, 16);
  float r = r_ij[e];
  float cut = 0.5f * (__cosf(0.6283185307f * r) + 1.f);
  cut = (r < 5.f) ? cut : 0.f;
  float attn = silu_f(t) * cut;
  vm[(size_t)e * H + h] = (__bf16)(vv * (float)fm[(size_t)e * 384 + 128 + h] * attn);
}

// ---------------- CSR build: histogram, scan, fill ----------------
__global__ __launch_bounds__(256) void hist_kernel(const int* __restrict__ ei,
                                                   int* __restrict__ cnt) {
  int e = blockIdx.x * 256 + threadIdx.x;
  if (e < N_EDGES) atomicAdd(&cnt[ei[N_EDGES + e]], 1);
}

__global__ __launch_bounds__(1024) void scan_kernel(const int* __restrict__ cnt,
                                                    int* __restrict__ rowptr) {
  __shared__ int wsum[16];
  int t = threadIdx.x;
  int base = t * 10;
  int local[10];
  int s = 0;
#pragma unroll
  for (int i = 0; i < 10; ++i) {
    int v = (base + i < N_NODES) ? cnt[base + i] : 0;
    local[i] = s;
    s += v;
  }
  int lane = t & 63, wave = t >> 6;
  int inc = s;
#pragma unroll
  for (int off = 1; off < 64; off <<= 1) {
    int u = __shfl_up(inc, off, 64);
    if (lane >= off) inc += u;
  }
  if (lane == 63) wsum[wave] = inc;
  __syncthreads();
  if (t == 0) {
    int acc = 0;
#pragma unroll
    for (int w = 0; w < 16; ++w) { int v = wsum[w]; wsum[w] = acc; acc += v; }
  }
  __syncthreads();
  int excl = inc - s + wsum[wave];
#pragma unroll
  for (int i = 0; i < 10; ++i)
    if (base + i <= N_NODES) rowptr[base + i] = excl + local[i];
}

__global__ __launch_bounds__(256) void fill_kernel(const int* __restrict__ ei,
                                                   const int* __restrict__ rowptr,
                                                   int* __restrict__ cursor,
                                                   int* __restrict__ elist) {
  int e = blockIdx.x * 256 + threadIdx.x;
  if (e < N_EDGES) {
    int d = ei[N_EDGES + e];
    int p = atomicAdd(&cursor[d], 1);
    elist[rowptr[d] + p] = e;
  }
}

// ---------------- gather: x_agg(bf16) = Σ vm ; dvec = Σ vec_m (no atomics) ----------------
__global__ __launch_bounds__(256) void gather_kernel(const __bf16* __restrict__ vm,
                                                     const __bf16* __restrict__ s,
                                                     const __bf16* __restrict__ vecw,
                                                     const float* __restrict__ d_ij,
                                                     const int* __restrict__ ei,
                                                     const int* __restrict__ rowptr,
                                                     const int* __restrict__ elist,
                                                     __bf16* __restrict__ x_agg,
                                                     float* __restrict__ dvec) {
  int n = blockIdx.x * 2 + (threadIdx.x >> 7);
  int h = threadIdx.x & 127;
  if (n >= N_NODES) return;
  int beg = rowptr[n], end = rowptr[n + 1];
  float ax = 0.f;
  float av[L] = {};
  for (int p = beg; p < end; ++p) {
    int e = elist[p];
    int src = ei[e];
    ax += (float)vm[(size_t)e * H + h];
    float s1 = (float)s[(size_t)e * 256 + h];
    float s2 = (float)s[(size_t)e * 256 + 128 + h];
    const __bf16* vrow = vecw + (size_t)src * L * H + h;
    const float* dd = d_ij + (size_t)e * L;
#pragma unroll
    for (int l = 0; l < L; l++) av[l] += (float)vrow[l * H] * s1 + s2 * dd[l];
  }
  x_agg[(size_t)n * H + h] = (__bf16)ax;
  float* drow = dvec + (size_t)n * L * H + h;
#pragma unroll
  for (int l = 0; l < L; l++) drow[l * H] = av[l];
}

// ---------------- edge update (big [NL][384]: vec3 @0, vt @128, vs @256; dfw = fm @256) ----------------
__global__ __launch_bounds__(256) void edgeupd_kernel(const __bf16* __restrict__ big,
                                                      const float* __restrict__ d_ij,
                                                      const __bf16* __restrict__ fm,
                                                      const int* __restrict__ ei,
                                                      float* __restrict__ df) {
  int e = blockIdx.x * 2 + (threadIdx.x >> 7);
  int h = threadIdx.x & 127;
  int src = ei[e], dst = ei[N_EDGES + e];
  float d[L];
  float sd2 = 0.f;
#pragma unroll
  for (int l = 0; l < L; l++) {
    d[l] = d_ij[(size_t)e * L + l];
    sd2 += d[l] * d[l];
  }
  const __bf16* arow = big + (size_t)dst * 8 * 384 + 128 + h;
  const __bf16* brow = big + (size_t)src * 8 * 384 + 256 + h;
  float dot = 0.f, p1 = 0.f, p2 = 0.f;
#pragma unroll
  for (int l = 0; l < L; l++) {
    float a = (float)arow[l * 384], bb = (float)brow[l * 384];
    dot += a * bb;
    p1 += a * d[l];
    p2 += bb * d[l];
  }
  float wdot = dot - p1 * p2 * (2.f - sd2);
  df[(size_t)e * H + h] = (float)fm[(size_t)e * 384 + 256 + h] * wdot;
}

// ---------------- final node update (vec3 = big cols 0..127) ----------------
__global__ __launch_bounds__(256) void final_kernel(const float* __restrict__ o,
                                                    const float* __restrict__ vdot,
                                                    const __bf16* __restrict__ big,
                                                    float* __restrict__ dx,
                                                    float* __restrict__ dvec, int n_nodes) {
  int n = blockIdx.x * 2 + (threadIdx.x >> 7);
  int h = threadIdx.x & 127;
  if (n >= n_nodes) return;
  float o1 = o[(size_t)n * 384 + h];
  float o2 = o[(size_t)n * 384 + 128 + h];
  float o3 = o[(size_t)n * 384 + 256 + h];
  dx[(size_t)n * H + h] = vdot[(size_t)n * H + h] * o2 + o3;
  float* drow = dvec + (size_t)n * L * H + h;
  const __bf16* v3 = big + (size_t)n * 8 * 384 + h;
#pragma unroll
  for (int l = 0; l < L; l++) drow[l * H] += (float)v3[l * 384] * o1;
}

extern "C" void kernel_launch(void* const* d_in, const int* in_sizes, int n_in, void* d_out,
                              int out_size, void* d_ws, size_t ws_size, hipStream_t stream) {
  const float* x = (const float*)d_in[0];
  const float* vec = (const float*)d_in[1];
  const float* f_ij = (const float*)d_in[2];
  const float* d_ij = (const float*)d_in[3];
  const float* r_ij = (const float*)d_in[4];
  const int* ei = (const int*)d_in[5];
  const float* ln_g = (const float*)d_in[6];
  const float* ln_b = (const float*)d_in[7];
  const float* vln_w = (const float*)d_in[8];
  const float* W_vec = (const float*)d_in[9];
  const float* W_q = (const float*)d_in[10];
  const float* b_q = (const float*)d_in[11];
  const float* W_k = (const float*)d_in[12];
  const float* b_k = (const float*)d_in[13];
  const float* W_v = (const float*)d_in[14];
  const float* b_v = (const float*)d_in[15];
  const float* W_dk = (const float*)d_in[16];
  const float* b_dk = (const float*)d_in[17];
  const float* W_dv = (const float*)d_in[18];
  const float* b_dv = (const float*)d_in[19];
  const float* W_s = (const float*)d_in[20];
  const float* b_s = (const float*)d_in[21];
  const float* W_f = (const float*)d_in[22];
  const float* b_f = (const float*)d_in[23];
  const float* W_src = (const float*)d_in[24];
  const float* W_trg = (const float*)d_in[25];
  const float* W_o = (const float*)d_in[26];
  const float* b_o = (const float*)d_in[27];

  float* out = (float*)d_out;
  float* dx = out;
  float* dvec = out + (size_t)N_NODES * H;
  float* df = dvec + (size_t)N_NODES * L * H;

  // ---- workspace plan (~224 MB; offsets in f32 slots) ----
  float* ws = (float*)d_ws;
  __bf16* vecw = (__bf16*)ws;                 // NL*128 bf16
  __bf16* big = (__bf16*)(ws + 5120000);      // NL*384 bf16: [vec3 128 | vt 128 | vs 128]
  __bf16* fm = (__bf16*)(ws + 20480000);      // E*384 bf16: [dk | dv | dfw]
  __bf16* vm = (__bf16*)(ws + 32768000);      // E*128 bf16
  __bf16* s_buf = (__bf16*)(ws + 36864000);   // E*256 bf16
  __bf16* qkv = (__bf16*)(ws + 45056000);     // N*384 bf16 (region reused as o_buf f32)
  __bf16* xln = (__bf16*)(ws + 48896000);     // N*128 bf16 (region holds 2x; OOB-tail safe)
  __bf16* xagg = (__bf16*)(ws + 49536000);    // N*128 bf16 (+tail slack)
  float* vdot = ws + 50176000;                // N*128 f32
  __bf16* Wt = (__bf16*)(ws + 51456000);      // [2048][128] bf16
  float* bqkv = ws + 51456000 + 131072;       // 384
  float* bfm = bqkv + 384;                    // 384
  int* rowptr = (int*)(bfm + 384);            // 10,001
  int* elist = rowptr + 10001;                // 64,000
  int* cnt = elist + 64000;                   // 10,000
  int* cursor = cnt + 10000;                  // 10,000
  __bf16* fijb = (__bf16*)(ws + 51800000);    // E*128 bf16 = 4,096,000 f32 slots

  float* o_buf = ws + 45056000;  // overwrites qkv after it's consumed (step 6)

  dim3 b256(256);

  // CSR build (depends only on ei)
  hipMemsetAsync(cnt, 0, N_NODES * sizeof(int), stream);
  hipMemsetAsync(cursor, 0, N_NODES * sizeof(int), stream);
  hist_kernel<<<dim3((N_EDGES + 255) / 256), b256, 0, stream>>>(ei, cnt);
  scan_kernel<<<dim3(1), dim3(1024), 0, stream>>>(cnt, rowptr);
  fill_kernel<<<dim3((N_EDGES + 255) / 256), b256, 0, stream>>>(ei, rowptr, cursor, elist);

  // 0. weight convert/transpose + bias concat; f_ij -> bf16
  wconv_kernel<<<dim3(258), b256, 0, stream>>>(W_vec, W_q, W_k, W_v, W_dk, W_dv, W_s, W_trg,
                                               W_src, W_f, W_o, b_q, b_k, b_v, b_dk, b_dv, b_f,
                                               Wt, bqkv, bfm);
  f2b_kernel<<<dim3(2048), b256, 0, stream>>>(f_ij, fijb, (size_t)N_EDGES * H / 8);
  // 1. x_ln = layernorm(x) -> bf16
  ln_kernel<<<dim3((N_NODES + 3) / 4), b256, 0, stream>>>(x, ln_g, ln_b, xln, N_NODES);
  // 2. vecw = vec * vln_w (bf16)
  vecw_kernel<<<dim3(2048), b256, 0, stream>>>(vec, vln_w, vecw, (size_t)NL * H / 8);
  // 3a. vdot (dedicated, no-spill kernel; Wt rows 0..255 = vec1|vec2)
  vdot_gemm<<<dim3(625), b256, 0, stream>>>(vecw, Wt, vdot);
  // 3b. big = vecw @ [vec3|Wtrg|Wsrc] (Wt rows 256..639); XCD-swizzled, ny=3
  gemm_v9<__bf16><<<dim3(swz_grid(625, 3)), b256, 0, stream>>>(
      vecw, Wt + (size_t)256 * 128, nullptr, big, NL, 625, 3, 384, 0);
  // 4. qkv = xln @ [Wq|Wk|Wv] + b (bf16 out)
  gemm_v9<__bf16><<<dim3(swz_grid(79, 3)), b256, 0, stream>>>(
      xln, Wt + (size_t)640 * 128, bqkv, qkv, N_NODES, 79, 3, 384, 0);
  // 5. fm = silu(fijb @ [Wdk|Wdv|Wf] + b)
  gemm_v9<__bf16><<<dim3(swz_grid(500, 3)), b256, 0, stream>>>(
      fijb, Wt + (size_t)1024 * 128, bfm, fm, N_EDGES, 500, 3, 384, 1);
  // 6. message -> vm (bf16)
  msg_kernel<<<dim3(N_EDGES / 2), b256, 0, stream>>>(qkv, fm, r_ij, ei, vm);
  // 7. s = silu(vm @ W_s + b)
  gemm_v9<__bf16><<<dim3(swz_grid(500, 2)), b256, 0, stream>>>(
      vm, Wt + (size_t)1408 * 128, b_s, s_buf, N_EDGES, 500, 2, 256, 1);
  // 8. gather into x_agg (bf16) and dvec (no atomics)
  gather_kernel<<<dim3(N_NODES / 2), b256, 0, stream>>>(vm, s_buf, vecw, d_ij, ei, rowptr,
                                                        elist, xagg, dvec);
  // 9. edge update -> df (reads big vt/vs + fm dfw)
  edgeupd_kernel<<<dim3(N_EDGES / 2), b256, 0, stream>>>(big, d_ij, fm, ei, df);
  // 10. o = xagg @ W_o + b (f32 out; overwrites qkv region: consumed in 6)
  gemm_v9<float><<<dim3(swz_grid(79, 3)), b256, 0, stream>>>(
      xagg, Wt + (size_t)1664 * 128, b_o, o_buf, N_NODES, 79, 3, 384, 0);
  // 11. final: dx, dvec += vec3*o1
  final_kernel<<<dim3(5000), b256, 0, stream>>>(o_buf, vdot, big, dx, dvec, N_NODES);
}

// Round 14
// 325.732 us; speedup vs baseline: 1.3104x; 1.0025x over previous
//
#include <hip/hip_runtime.h>
#include <hip/hip_bf16.h>
#include <math.h>

#define N_NODES 10000
#define N_EDGES 64000
#define H 128
#define L 8
#define NL (N_NODES * L)

typedef __attribute__((ext_vector_type(4))) float f32x4;
typedef __attribute__((ext_vector_type(8))) __bf16 bf16x8;

__device__ __forceinline__ float silu_f(float x) { return x / (1.f + __expf(-x)); }

// ---------------- LayerNorm: one wave per node -> bf16 out ----------------
__global__ __launch_bounds__(256) void ln_kernel(const float* __restrict__ x,
                                                 const float* __restrict__ g,
                                                 const float* __restrict__ b,
                                                 __bf16* __restrict__ out, int n_nodes) {
  int wave = threadIdx.x >> 6;
  int lane = threadIdx.x & 63;
  int n = blockIdx.x * 4 + wave;
  if (n >= n_nodes) return;
  const float* xr = x + (size_t)n * H;
  float a0 = xr[lane], a1 = xr[lane + 64];
  float s = a0 + a1;
#pragma unroll
  for (int off = 32; off >= 1; off >>= 1) s += __shfl_xor(s, off, 64);
  float mu = s * (1.f / H);
  float d0 = a0 - mu, d1 = a1 - mu;
  float v = d0 * d0 + d1 * d1;
#pragma unroll
  for (int off = 32; off >= 1; off >>= 1) v += __shfl_xor(v, off, 64);
  float rstd = rsqrtf(v * (1.f / H) + 1e-5f);
  __bf16* orow = out + (size_t)n * H;
  orow[lane] = (__bf16)(d0 * rstd * g[lane] + b[lane]);
  orow[lane + 64] = (__bf16)(d1 * rstd * g[lane + 64] + b[lane + 64]);
}

// ---------------- vecw = vec * vln_w  -> bf16 ----------------
__global__ __launch_bounds__(256) void vecw_kernel(const float* __restrict__ vec,
                                                   const float* __restrict__ w,
                                                   __bf16* __restrict__ out, size_t total8) {
  size_t i = (size_t)blockIdx.x * blockDim.x + threadIdx.x;
  size_t stride = (size_t)gridDim.x * blockDim.x;
  for (; i < total8; i += stride) {
    size_t base = i * 8;
    f32x4 a = *(const f32x4*)(vec + base);
    f32x4 b = *(const f32x4*)(vec + base + 4);
    int c = (int)(base & 127);
    bf16x8 h;
    h[0] = (__bf16)(a[0] * w[c + 0]); h[1] = (__bf16)(a[1] * w[c + 1]);
    h[2] = (__bf16)(a[2] * w[c + 2]); h[3] = (__bf16)(a[3] * w[c + 3]);
    h[4] = (__bf16)(b[0] * w[c + 4]); h[5] = (__bf16)(b[1] * w[c + 5]);
    h[6] = (__bf16)(b[2] * w[c + 6]); h[7] = (__bf16)(b[3] * w[c + 7]);
    *(bf16x8*)(out + base) = h;
  }
}

// ---------------- f32 -> bf16 bulk convert ----------------
__global__ __launch_bounds__(256) void f2b_kernel(const float* __restrict__ in,
                                                  __bf16* __restrict__ out, size_t total8) {
  size_t i = (size_t)blockIdx.x * blockDim.x + threadIdx.x;
  size_t stride = (size_t)gridDim.x * blockDim.x;
  for (; i < total8; i += stride) {
    size_t base = i * 8;
    f32x4 a = *(const f32x4*)(in + base);
    f32x4 b = *(const f32x4*)(in + base + 4);
    bf16x8 h;
    h[0] = (__bf16)a[0]; h[1] = (__bf16)a[1]; h[2] = (__bf16)a[2]; h[3] = (__bf16)a[3];
    h[4] = (__bf16)b[0]; h[5] = (__bf16)b[1]; h[6] = (__bf16)b[2]; h[7] = (__bf16)b[3];
    *(bf16x8*)(out + base) = h;
  }
}

// ---------------- weight convert into one [2048][128] bf16 table ----------------
__global__ __launch_bounds__(256) void wconv_kernel(
    const float* __restrict__ Wvec, const float* __restrict__ Wq, const float* __restrict__ Wk,
    const float* __restrict__ Wv, const float* __restrict__ Wdk, const float* __restrict__ Wdv,
    const float* __restrict__ Ws, const float* __restrict__ Wtrg, const float* __restrict__ Wsrc,
    const float* __restrict__ Wf, const float* __restrict__ Wo,
    const float* __restrict__ bq, const float* __restrict__ bk, const float* __restrict__ bv,
    const float* __restrict__ bdk, const float* __restrict__ bdv, const float* __restrict__ bf,
    __bf16* __restrict__ Wt, float* __restrict__ bqkv, float* __restrict__ bfm) {
  int bid = blockIdx.x;
  int t = threadIdx.x;
  if (bid >= 256) {
    if (bid == 256) {
      if (t < 128) { bqkv[t] = bq[t]; bqkv[128 + t] = bk[t]; bqkv[256 + t] = bv[t]; }
    } else {
      if (t < 128) { bfm[t] = bdk[t]; bfm[128 + t] = bdv[t]; bfm[256 + t] = bf[t]; }
    }
    return;
  }
  int ct = bid >> 2, kt = bid & 3;
  int gc0 = ct * 32;
  const float* W; int ldw, sc0;
  if      (gc0 < 384)  { W = Wvec; ldw = 384; sc0 = gc0; }
  else if (gc0 < 512)  { W = Wtrg; ldw = 128; sc0 = gc0 - 384; }
  else if (gc0 < 640)  { W = Wsrc; ldw = 128; sc0 = gc0 - 512; }
  else if (gc0 < 768)  { W = Wq;   ldw = 128; sc0 = gc0 - 640; }
  else if (gc0 < 896)  { W = Wk;   ldw = 128; sc0 = gc0 - 768; }
  else if (gc0 < 1024) { W = Wv;   ldw = 128; sc0 = gc0 - 896; }
  else if (gc0 < 1152) { W = Wdk;  ldw = 128; sc0 = gc0 - 1024; }
  else if (gc0 < 1280) { W = Wdv;  ldw = 128; sc0 = gc0 - 1152; }
  else if (gc0 < 1408) { W = Wf;   ldw = 128; sc0 = gc0 - 1280; }
  else if (gc0 < 1664) { W = Ws;   ldw = 256; sc0 = gc0 - 1408; }
  else                 { W = Wo;   ldw = 384; sc0 = gc0 - 1664; }
  __shared__ float tile[32][33];
  int tx = t & 31, ty = t >> 5;
#pragma unroll
  for (int i = 0; i < 4; ++i)
    tile[ty + i * 8][tx] = W[(size_t)(kt * 32 + ty + i * 8) * ldw + sc0 + tx];
  __syncthreads();
#pragma unroll
  for (int i = 0; i < 4; ++i)
    Wt[(size_t)(gc0 + ty + i * 8) * 128 + kt * 32 + tx] = (__bf16)tile[tx][ty + i * 8];
}

// ---------------- vdot GEMM: dedicated kernel, no spill ----------------
__global__ __launch_bounds__(256, 2) void vdot_gemm(const __bf16* __restrict__ A,
                                                    const __bf16* __restrict__ Bt,
                                                    float* __restrict__ vdot) {
  __shared__ __bf16 As[128 * 128];
  const int tid = threadIdx.x;
  const int lane = tid & 63;
  const int wave = tid >> 6;
  const int wm = wave >> 1, wn = wave & 1;
  const int row0 = blockIdx.x * 128;

#pragma unroll
  for (int i = 0; i < 8; ++i) {
    int c = tid + i * 256;
    int row = c >> 4, k8 = c & 15;
    int k8s = k8 ^ (row & 7);
    const __bf16* src = A + (size_t)(row0 + row) * 128 + k8s * 8;
    __builtin_amdgcn_global_load_lds((const __attribute__((address_space(1))) void*)src,
                                     (__attribute__((address_space(3))) void*)(As + c * 8),
                                     16, 0, 0);
  }
  __syncthreads();

  f32x4 pacc[4][4], acc[4][4];
#pragma unroll
  for (int mi = 0; mi < 4; ++mi)
#pragma unroll
    for (int ni = 0; ni < 4; ++ni) {
      pacc[mi][ni] = f32x4{0.f, 0.f, 0.f, 0.f};
      acc[mi][ni] = f32x4{0.f, 0.f, 0.f, 0.f};
    }
#pragma unroll
  for (int ct = 0; ct < 2; ++ct) {
    const __bf16* Bbase =
        Bt + ((size_t)(ct * 128 + wn * 64 + (lane & 15)) << 7) + ((lane >> 4) << 3);
#pragma unroll
    for (int ks = 0; ks < 4; ++ks) {
      bf16x8 b[4];
#pragma unroll
      for (int ni = 0; ni < 4; ++ni) b[ni] = *(const bf16x8*)(Bbase + (ni << 11) + (ks << 5));
      bf16x8 a[4];
#pragma unroll
      for (int mi = 0; mi < 4; ++mi) {
        int row = wm * 64 + mi * 16 + (lane & 15);
        int byte = (row * 256 + ks * 64 + ((lane >> 4) << 4)) ^ ((row & 7) << 4);
        a[mi] = *(const bf16x8*)((const char*)As + byte);
      }
      if (ct == 0) {
#pragma unroll
        for (int mi = 0; mi < 4; ++mi)
#pragma unroll
          for (int ni = 0; ni < 4; ++ni)
            pacc[mi][ni] =
                __builtin_amdgcn_mfma_f32_16x16x32_bf16(a[mi], b[ni], pacc[mi][ni], 0, 0, 0);
      } else {
#pragma unroll
        for (int mi = 0; mi < 4; ++mi)
#pragma unroll
          for (int ni = 0; ni < 4; ++ni)
            acc[mi][ni] =
                __builtin_amdgcn_mfma_f32_16x16x32_bf16(a[mi], b[ni], acc[mi][ni], 0, 0, 0);
      }
    }
  }
#pragma unroll
  for (int mi = 0; mi < 4; ++mi) {
#pragma unroll
    for (int ni = 0; ni < 4; ++ni) {
      float sr = pacc[mi][ni][0] * acc[mi][ni][0] + pacc[mi][ni][1] * acc[mi][ni][1] +
                 pacc[mi][ni][2] * acc[mi][ni][2] + pacc[mi][ni][3] * acc[mi][ni][3];
      sr += __shfl_xor(sr, 16, 64);
      if ((lane & 16) == 0) {
        int node = (row0 >> 3) + wm * 8 + mi * 2 + (lane >> 5);
        int col = wn * 64 + ni * 16 + (lane & 15);
        vdot[(size_t)node * 128 + col] = sr;
      }
    }
  }
}

// ---------------- MFMA GEMM v9: bf16-A only (global_load_lds); XCD-swizzled 1D grid ----------
template <typename CT>
__global__ __launch_bounds__(256, 3) void gemm_v9(const __bf16* __restrict__ A,
                                                  const __bf16* __restrict__ Bt,
                                                  const float* __restrict__ bias,
                                                  CT* __restrict__ C, int M, int nx, int ny,
                                                  int ldc, int act) {
  __shared__ __bf16 As[128 * 128];
  __bf16* Cs = As;  // post-barrier reuse; 64*136*2B = 17.4KB <= 32KB
  const int bid = blockIdx.x;
  const int xi = bid & 7;
  const int rem = bid >> 3;
  const int y = rem % ny;
  const int x = (rem / ny) * 8 + xi;
  if (x >= nx) return;
  const int tid = threadIdx.x;
  const int lane = tid & 63;
  const int wave = tid >> 6;
  const int wm = wave >> 1, wn = wave & 1;
  const int row0 = x * 128;

#pragma unroll
  for (int i = 0; i < 8; ++i) {
    int c = tid + i * 256;  // 16B chunk; LDS dest linear
    int row = c >> 4, k8 = c & 15;
    int k8s = k8 ^ (row & 7);  // inverse-swizzled source == read-side XOR
    const __bf16* src = A + (size_t)(row0 + row) * 128 + k8s * 8;
    __builtin_amdgcn_global_load_lds((const __attribute__((address_space(1))) void*)src,
                                     (__attribute__((address_space(3))) void*)(As + c * 8),
                                     16, 0, 0);
  }
  __syncthreads();

  // hoist all 16 B fragments (one wait; weights L2-hot)
  const __bf16* Bbase =
      Bt + ((size_t)(y * 128 + wn * 64 + (lane & 15)) << 7) + ((lane >> 4) << 3);
  bf16x8 b[4][4];
#pragma unroll
  for (int ks = 0; ks < 4; ++ks)
#pragma unroll
    for (int ni = 0; ni < 4; ++ni) b[ks][ni] = *(const bf16x8*)(Bbase + (ni << 11) + (ks << 5));

  f32x4 acc[4][4];
#pragma unroll
  for (int mi = 0; mi < 4; ++mi)
#pragma unroll
    for (int ni = 0; ni < 4; ++ni) acc[mi][ni] = f32x4{0.f, 0.f, 0.f, 0.f};

#pragma unroll
  for (int ks = 0; ks < 4; ++ks) {
    bf16x8 a[4];
#pragma unroll
    for (int mi = 0; mi < 4; ++mi) {
      int row = wm * 64 + mi * 16 + (lane & 15);
      int byte = (row * 256 + ks * 64 + ((lane >> 4) << 4)) ^ ((row & 7) << 4);
      a[mi] = *(const bf16x8*)((const char*)As + byte);
    }
#pragma unroll
    for (int mi = 0; mi < 4; ++mi)
#pragma unroll
      for (int ni = 0; ni < 4; ++ni)
        acc[mi][ni] =
            __builtin_amdgcn_mfma_f32_16x16x32_bf16(a[mi], b[ks][ni], acc[mi][ni], 0, 0, 0);
  }

  const int cstore = y * 128;
  if constexpr (sizeof(CT) == 2) {
#pragma unroll
    for (int p = 0; p < 2; ++p) {
      __syncthreads();
      int rl = (wm << 5) | ((lane >> 4) << 2);
#pragma unroll
      for (int q = 0; q < 2; ++q) {
        int mi = 2 * p + q;
#pragma unroll
        for (int ni = 0; ni < 4; ++ni) {
          int col = wn * 64 + ni * 16 + (lane & 15);
          float bv = bias ? bias[cstore + col] : 0.f;
#pragma unroll
          for (int r = 0; r < 4; ++r) {
            float xv = acc[mi][ni][r] + bv;
            if (act) xv = silu_f(xv);
            Cs[(rl + q * 16 + r) * 136 + col] = (__bf16)xv;
          }
        }
      }
      __syncthreads();
#pragma unroll
      for (int rr = 0; rr < 4; ++rr) {
        int row = (tid >> 4) + rr * 16;  // 0..63
        int chunk = tid & 15;
        bf16x8 v = *(const bf16x8*)(Cs + row * 136 + chunk * 8);
        int grow = row0 + (row >> 5) * 64 + (2 * p + ((row >> 4) & 1)) * 16 + (row & 15);
        if (grow < M)
          *(bf16x8*)(C + (size_t)grow * ldc + cstore + chunk * 8) = v;
      }
    }
  } else {
#pragma unroll
    for (int mi = 0; mi < 4; ++mi) {
      int rbase = row0 + wm * 64 + mi * 16 + ((lane >> 4) << 2);
#pragma unroll
      for (int ni = 0; ni < 4; ++ni) {
        int gcol = cstore + wn * 64 + ni * 16 + (lane & 15);
        float bv = bias ? bias[cstore + wn * 64 + ni * 16 + (lane & 15)] : 0.f;
#pragma unroll
        for (int r = 0; r < 4; ++r) {
          int grow = rbase + r;
          if (grow < M) {
            float xv = acc[mi][ni][r] + bv;
            if (act) xv = silu_f(xv);
            C[(size_t)grow * ldc + gcol] = (CT)xv;
          }
        }
      }
    }
  }
}

// helper: swizzled grid size
static inline int swz_grid(int nx, int ny) { return ((nx + 7) / 8) * ny * 8; }

// ---------------- message (CSR dst-ordered): attn + vm per edge ----------------
__global__ __launch_bounds__(256) void msg_kernel(const __bf16* __restrict__ qkv,
                                                  const __bf16* __restrict__ fm,
                                                  const float* __restrict__ r_ij,
                                                  const int* __restrict__ ei,
                                                  const int* __restrict__ elist,
                                                  __bf16* __restrict__ vm) {
  int p = blockIdx.x * 2 + (threadIdx.x >> 7);
  int h = threadIdx.x & 127;
  int e = elist[p];
  int src = ei[e], dst = ei[N_EDGES + e];
  float qv = (float)qkv[(size_t)dst * 384 + h];
  float kv = (float)qkv[(size_t)src * 384 + 128 + h];
  float vv = (float)qkv[(size_t)src * 384 + 256 + h];
  float t = qv * kv * (float)fm[(size_t)e * 384 + h];
#pragma unroll
  for (int off = 8; off >= 1; off >>= 1) t += __shfl_xor(t, off, 16);
  float r = r_ij[e];
  float cut = 0.5f * (__cosf(0.6283185307f * r) + 1.f);
  cut = (r < 5.f) ? cut : 0.f;
  float attn = silu_f(t) * cut;
  vm[(size_t)e * H + h] = (__bf16)(vv * (float)fm[(size_t)e * 384 + 128 + h] * attn);
}

// ---------------- CSR build: histogram, scan, fill ----------------
__global__ __launch_bounds__(256) void hist_kernel(const int* __restrict__ ei,
                                                   int* __restrict__ cnt) {
  int e = blockIdx.x * 256 + threadIdx.x;
  if (e < N_EDGES) atomicAdd(&cnt[ei[N_EDGES + e]], 1);
}

__global__ __launch_bounds__(1024) void scan_kernel(const int* __restrict__ cnt,
                                                    int* __restrict__ rowptr) {
  __shared__ int wsum[16];
  int t = threadIdx.x;
  int base = t * 10;
  int local[10];
  int s = 0;
#pragma unroll
  for (int i = 0; i < 10; ++i) {
    int v = (base + i < N_NODES) ? cnt[base + i] : 0;
    local[i] = s;
    s += v;
  }
  int lane = t & 63, wave = t >> 6;
  int inc = s;
#pragma unroll
  for (int off = 1; off < 64; off <<= 1) {
    int u = __shfl_up(inc, off, 64);
    if (lane >= off) inc += u;
  }
  if (lane == 63) wsum[wave] = inc;
  __syncthreads();
  if (t == 0) {
    int acc = 0;
#pragma unroll
    for (int w = 0; w < 16; ++w) { int v = wsum[w]; wsum[w] = acc; acc += v; }
  }
  __syncthreads();
  int excl = inc - s + wsum[wave];
#pragma unroll
  for (int i = 0; i < 10; ++i)
    if (base + i <= N_NODES) rowptr[base + i] = excl + local[i];
}

__global__ __launch_bounds__(256) void fill_kernel(const int* __restrict__ ei,
                                                   const int* __restrict__ rowptr,
                                                   int* __restrict__ cursor,
                                                   int* __restrict__ elist) {
  int e = blockIdx.x * 256 + threadIdx.x;
  if (e < N_EDGES) {
    int d = ei[N_EDGES + e];
    int p = atomicAdd(&cursor[d], 1);
    elist[rowptr[d] + p] = e;
  }
}

// ---------------- gather: x_agg(bf16) = Σ vm ; dvec = Σ vec_m (no atomics) ----------------
__global__ __launch_bounds__(256) void gather_kernel(const __bf16* __restrict__ vm,
                                                     const __bf16* __restrict__ s,
                                                     const __bf16* __restrict__ vecw,
                                                     const float* __restrict__ d_ij,
                                                     const int* __restrict__ ei,
                                                     const int* __restrict__ rowptr,
                                                     const int* __restrict__ elist,
                                                     __bf16* __restrict__ x_agg,
                                                     float* __restrict__ dvec) {
  int n = blockIdx.x * 2 + (threadIdx.x >> 7);
  int h = threadIdx.x & 127;
  if (n >= N_NODES) return;
  int beg = rowptr[n], end = rowptr[n + 1];
  float ax = 0.f;
  float av[L] = {};
  for (int p = beg; p < end; ++p) {
    int e = elist[p];
    int src = ei[e];
    ax += (float)vm[(size_t)e * H + h];
    float s1 = (float)s[(size_t)e * 256 + h];
    float s2 = (float)s[(size_t)e * 256 + 128 + h];
    const __bf16* vrow = vecw + (size_t)src * L * H + h;
    const float* dd = d_ij + (size_t)e * L;
#pragma unroll
    for (int l = 0; l < L; l++) av[l] += (float)vrow[l * H] * s1 + s2 * dd[l];
  }
  x_agg[(size_t)n * H + h] = (__bf16)ax;
  float* drow = dvec + (size_t)n * L * H + h;
#pragma unroll
  for (int l = 0; l < L; l++) drow[l * H] = av[l];
}

// ---------------- edge update (CSR dst-ordered) ----------------
// big [NL][384]: vec3 @0, vt @128, vs @256; dfw = fm @256
__global__ __launch_bounds__(256) void edgeupd_kernel(const __bf16* __restrict__ big,
                                                      const float* __restrict__ d_ij,
                                                      const __bf16* __restrict__ fm,
                                                      const int* __restrict__ ei,
                                                      const int* __restrict__ elist,
                                                      float* __restrict__ df) {
  int p = blockIdx.x * 2 + (threadIdx.x >> 7);
  int h = threadIdx.x & 127;
  int e = elist[p];
  int src = ei[e], dst = ei[N_EDGES + e];
  float d[L];
  float sd2 = 0.f;
#pragma unroll
  for (int l = 0; l < L; l++) {
    d[l] = d_ij[(size_t)e * L + l];
    sd2 += d[l] * d[l];
  }
  const __bf16* arow = big + (size_t)dst * 8 * 384 + 128 + h;
  const __bf16* brow = big + (size_t)src * 8 * 384 + 256 + h;
  float dot = 0.f, p1 = 0.f, p2 = 0.f;
#pragma unroll
  for (int l = 0; l < L; l++) {
    float a = (float)arow[l * 384], bb = (float)brow[l * 384];
    dot += a * bb;
    p1 += a * d[l];
    p2 += bb * d[l];
  }
  float wdot = dot - p1 * p2 * (2.f - sd2);
  df[(size_t)e * H + h] = (float)fm[(size_t)e * 384 + 256 + h] * wdot;
}

// ---------------- final node update (vec3 = big cols 0..127) ----------------
__global__ __launch_bounds__(256) void final_kernel(const float* __restrict__ o,
                                                    const float* __restrict__ vdot,
                                                    const __bf16* __restrict__ big,
                                                    float* __restrict__ dx,
                                                    float* __restrict__ dvec, int n_nodes) {
  int n = blockIdx.x * 2 + (threadIdx.x >> 7);
  int h = threadIdx.x & 127;
  if (n >= n_nodes) return;
  float o1 = o[(size_t)n * 384 + h];
  float o2 = o[(size_t)n * 384 + 128 + h];
  float o3 = o[(size_t)n * 384 + 256 + h];
  dx[(size_t)n * H + h] = vdot[(size_t)n * H + h] * o2 + o3;
  float* drow = dvec + (size_t)n * L * H + h;
  const __bf16* v3 = big + (size_t)n * 8 * 384 + h;
#pragma unroll
  for (int l = 0; l < L; l++) drow[l * H] += (float)v3[l * 384] * o1;
}

extern "C" void kernel_launch(void* const* d_in, const int* in_sizes, int n_in, void* d_out,
                              int out_size, void* d_ws, size_t ws_size, hipStream_t stream) {
  const float* x = (const float*)d_in[0];
  const float* vec = (const float*)d_in[1];
  const float* f_ij = (const float*)d_in[2];
  const float* d_ij = (const float*)d_in[3];
  const float* r_ij = (const float*)d_in[4];
  const int* ei = (const int*)d_in[5];
  const float* ln_g = (const float*)d_in[6];
  const float* ln_b = (const float*)d_in[7];
  const float* vln_w = (const float*)d_in[8];
  const float* W_vec = (const float*)d_in[9];
  const float* W_q = (const float*)d_in[10];
  const float* b_q = (const float*)d_in[11];
  const float* W_k = (const float*)d_in[12];
  const float* b_k = (const float*)d_in[13];
  const float* W_v = (const float*)d_in[14];
  const float* b_v = (const float*)d_in[15];
  const float* W_dk = (const float*)d_in[16];
  const float* b_dk = (const float*)d_in[17];
  const float* W_dv = (const float*)d_in[18];
  const float* b_dv = (const float*)d_in[19];
  const float* W_s = (const float*)d_in[20];
  const float* b_s = (const float*)d_in[21];
  const float* W_f = (const float*)d_in[22];
  const float* b_f = (const float*)d_in[23];
  const float* W_src = (const float*)d_in[24];
  const float* W_trg = (const float*)d_in[25];
  const float* W_o = (const float*)d_in[26];
  const float* b_o = (const float*)d_in[27];

  float* out = (float*)d_out;
  float* dx = out;
  float* dvec = out + (size_t)N_NODES * H;
  float* df = dvec + (size_t)N_NODES * L * H;

  // ---- workspace plan (~224 MB; offsets in f32 slots) ----
  float* ws = (float*)d_ws;
  __bf16* vecw = (__bf16*)ws;                 // NL*128 bf16
  __bf16* big = (__bf16*)(ws + 5120000);      // NL*384 bf16: [vec3 128 | vt 128 | vs 128]
  __bf16* fm = (__bf16*)(ws + 20480000);      // E*384 bf16: [dk | dv | dfw]
  __bf16* vm = (__bf16*)(ws + 32768000);      // E*128 bf16
  __bf16* s_buf = (__bf16*)(ws + 36864000);   // E*256 bf16
  __bf16* qkv = (__bf16*)(ws + 45056000);     // N*384 bf16 (region reused as o_buf f32)
  __bf16* xln = (__bf16*)(ws + 48896000);     // N*128 bf16 (+tail slack)
  __bf16* xagg = (__bf16*)(ws + 49536000);    // N*128 bf16 (+tail slack)
  float* vdot = ws + 50176000;                // N*128 f32
  __bf16* Wt = (__bf16*)(ws + 51456000);      // [2048][128] bf16
  float* bqkv = ws + 51456000 + 131072;       // 384
  float* bfm = bqkv + 384;                    // 384
  int* rowptr = (int*)(bfm + 384);            // 10,001
  int* elist = rowptr + 10001;                // 64,000
  int* cnt = elist + 64000;                   // 10,000
  int* cursor = cnt + 10000;                  // 10,000
  __bf16* fijb = (__bf16*)(ws + 51800000);    // E*128 bf16

  float* o_buf = ws + 45056000;  // overwrites qkv after it's consumed (step 6)

  dim3 b256(256);

  // CSR build (depends only on ei)
  hipMemsetAsync(cnt, 0, N_NODES * sizeof(int), stream);
  hipMemsetAsync(cursor, 0, N_NODES * sizeof(int), stream);
  hist_kernel<<<dim3((N_EDGES + 255) / 256), b256, 0, stream>>>(ei, cnt);
  scan_kernel<<<dim3(1), dim3(1024), 0, stream>>>(cnt, rowptr);
  fill_kernel<<<dim3((N_EDGES + 255) / 256), b256, 0, stream>>>(ei, rowptr, cursor, elist);

  // 0. weight convert/transpose + bias concat; f_ij -> bf16
  wconv_kernel<<<dim3(258), b256, 0, stream>>>(W_vec, W_q, W_k, W_v, W_dk, W_dv, W_s, W_trg,
                                               W_src, W_f, W_o, b_q, b_k, b_v, b_dk, b_dv, b_f,
                                               Wt, bqkv, bfm);
  f2b_kernel<<<dim3(2048), b256, 0, stream>>>(f_ij, fijb, (size_t)N_EDGES * H / 8);
  // 1. x_ln = layernorm(x) -> bf16
  ln_kernel<<<dim3((N_NODES + 3) / 4), b256, 0, stream>>>(x, ln_g, ln_b, xln, N_NODES);
  // 2. vecw = vec * vln_w (bf16)
  vecw_kernel<<<dim3(2048), b256, 0, stream>>>(vec, vln_w, vecw, (size_t)NL * H / 8);
  // 3a. vdot (dedicated, no-spill kernel; Wt rows 0..255 = vec1|vec2)
  vdot_gemm<<<dim3(625), b256, 0, stream>>>(vecw, Wt, vdot);
  // 3b. big = vecw @ [vec3|Wtrg|Wsrc] (Wt rows 256..639); XCD-swizzled, ny=3
  gemm_v9<__bf16><<<dim3(swz_grid(625, 3)), b256, 0, stream>>>(
      vecw, Wt + (size_t)256 * 128, nullptr, big, NL, 625, 3, 384, 0);
  // 4. qkv = xln @ [Wq|Wk|Wv] + b (bf16 out)
  gemm_v9<__bf16><<<dim3(swz_grid(79, 3)), b256, 0, stream>>>(
      xln, Wt + (size_t)640 * 128, bqkv, qkv, N_NODES, 79, 3, 384, 0);
  // 5. fm = silu(fijb @ [Wdk|Wdv|Wf] + b)
  gemm_v9<__bf16><<<dim3(swz_grid(500, 3)), b256, 0, stream>>>(
      fijb, Wt + (size_t)1024 * 128, bfm, fm, N_EDGES, 500, 3, 384, 1);
  // 6. message -> vm (bf16); CSR dst-ordered for qkv[dst] L2 locality
  msg_kernel<<<dim3(N_EDGES / 2), b256, 0, stream>>>(qkv, fm, r_ij, ei, elist, vm);
  // 7. s = silu(vm @ W_s + b)
  gemm_v9<__bf16><<<dim3(swz_grid(500, 2)), b256, 0, stream>>>(
      vm, Wt + (size_t)1408 * 128, b_s, s_buf, N_EDGES, 500, 2, 256, 1);
  // 8. gather into x_agg (bf16) and dvec (no atomics)
  gather_kernel<<<dim3(N_NODES / 2), b256, 0, stream>>>(vm, s_buf, vecw, d_ij, ei, rowptr,
                                                        elist, xagg, dvec);
  // 9. edge update -> df; CSR dst-ordered for big[dst] L2 locality
  edgeupd_kernel<<<dim3(N_EDGES / 2), b256, 0, stream>>>(big, d_ij, fm, ei, elist, df);
  // 10. o = xagg @ W_o + b (f32 out; overwrites qkv region: consumed in 6)
  gemm_v9<float><<<dim3(swz_grid(79, 3)), b256, 0, stream>>>(
      xagg, Wt + (size_t)1664 * 128, b_o, o_buf, N_NODES, 79, 3, 384, 0);
  // 11. final: dx, dvec += vec3*o1
  final_kernel<<<dim3(5000), b256, 0, stream>>>(o_buf, vdot, big, dx, dvec, N_NODES);
}

// Round 15
// 321.544 us; speedup vs baseline: 1.3274x; 1.0130x over previous
//
#include <hip/hip_runtime.h>
#include <hip/hip_bf16.h>
#include <math.h>

#define N_NODES 10000
#define N_EDGES 64000
#define H 128
#define L 8
#define NL (N_NODES * L)

typedef __attribute__((ext_vector_type(4))) float f32x4;
typedef __attribute__((ext_vector_type(8))) __bf16 bf16x8;

__device__ __forceinline__ float silu_f(float x) { return x / (1.f + __expf(-x)); }

// ---------------- LayerNorm: one wave per node -> bf16 out ----------------
__global__ __launch_bounds__(256) void ln_kernel(const float* __restrict__ x,
                                                 const float* __restrict__ g,
                                                 const float* __restrict__ b,
                                                 __bf16* __restrict__ out, int n_nodes) {
  int wave = threadIdx.x >> 6;
  int lane = threadIdx.x & 63;
  int n = blockIdx.x * 4 + wave;
  if (n >= n_nodes) return;
  const float* xr = x + (size_t)n * H;
  float a0 = xr[lane], a1 = xr[lane + 64];
  float s = a0 + a1;
#pragma unroll
  for (int off = 32; off >= 1; off >>= 1) s += __shfl_xor(s, off, 64);
  float mu = s * (1.f / H);
  float d0 = a0 - mu, d1 = a1 - mu;
  float v = d0 * d0 + d1 * d1;
#pragma unroll
  for (int off = 32; off >= 1; off >>= 1) v += __shfl_xor(v, off, 64);
  float rstd = rsqrtf(v * (1.f / H) + 1e-5f);
  __bf16* orow = out + (size_t)n * H;
  orow[lane] = (__bf16)(d0 * rstd * g[lane] + b[lane]);
  orow[lane + 64] = (__bf16)(d1 * rstd * g[lane + 64] + b[lane + 64]);
}

// ---------------- vecw = vec * vln_w  -> bf16 ----------------
__global__ __launch_bounds__(256) void vecw_kernel(const float* __restrict__ vec,
                                                   const float* __restrict__ w,
                                                   __bf16* __restrict__ out, size_t total8) {
  size_t i = (size_t)blockIdx.x * blockDim.x + threadIdx.x;
  size_t stride = (size_t)gridDim.x * blockDim.x;
  for (; i < total8; i += stride) {
    size_t base = i * 8;
    f32x4 a = *(const f32x4*)(vec + base);
    f32x4 b = *(const f32x4*)(vec + base + 4);
    int c = (int)(base & 127);
    bf16x8 h;
    h[0] = (__bf16)(a[0] * w[c + 0]); h[1] = (__bf16)(a[1] * w[c + 1]);
    h[2] = (__bf16)(a[2] * w[c + 2]); h[3] = (__bf16)(a[3] * w[c + 3]);
    h[4] = (__bf16)(b[0] * w[c + 4]); h[5] = (__bf16)(b[1] * w[c + 5]);
    h[6] = (__bf16)(b[2] * w[c + 6]); h[7] = (__bf16)(b[3] * w[c + 7]);
    *(bf16x8*)(out + base) = h;
  }
}

// ---------------- f32 -> bf16 bulk convert ----------------
__global__ __launch_bounds__(256) void f2b_kernel(const float* __restrict__ in,
                                                  __bf16* __restrict__ out, size_t total8) {
  size_t i = (size_t)blockIdx.x * blockDim.x + threadIdx.x;
  size_t stride = (size_t)gridDim.x * blockDim.x;
  for (; i < total8; i += stride) {
    size_t base = i * 8;
    f32x4 a = *(const f32x4*)(in + base);
    f32x4 b = *(const f32x4*)(in + base + 4);
    bf16x8 h;
    h[0] = (__bf16)a[0]; h[1] = (__bf16)a[1]; h[2] = (__bf16)a[2]; h[3] = (__bf16)a[3];
    h[4] = (__bf16)b[0]; h[5] = (__bf16)b[1]; h[6] = (__bf16)b[2]; h[7] = (__bf16)b[3];
    *(bf16x8*)(out + base) = h;
  }
}

// ---------------- weight convert into one [2048][128] bf16 table ----------------
__global__ __launch_bounds__(256) void wconv_kernel(
    const float* __restrict__ Wvec, const float* __restrict__ Wq, const float* __restrict__ Wk,
    const float* __restrict__ Wv, const float* __restrict__ Wdk, const float* __restrict__ Wdv,
    const float* __restrict__ Ws, const float* __restrict__ Wtrg, const float* __restrict__ Wsrc,
    const float* __restrict__ Wf, const float* __restrict__ Wo,
    const float* __restrict__ bq, const float* __restrict__ bk, const float* __restrict__ bv,
    const float* __restrict__ bdk, const float* __restrict__ bdv, const float* __restrict__ bf,
    __bf16* __restrict__ Wt, float* __restrict__ bqkv, float* __restrict__ bfm) {
  int bid = blockIdx.x;
  int t = threadIdx.x;
  if (bid >= 256) {
    if (bid == 256) {
      if (t < 128) { bqkv[t] = bq[t]; bqkv[128 + t] = bk[t]; bqkv[256 + t] = bv[t]; }
    } else {
      if (t < 128) { bfm[t] = bdk[t]; bfm[128 + t] = bdv[t]; bfm[256 + t] = bf[t]; }
    }
    return;
  }
  int ct = bid >> 2, kt = bid & 3;
  int gc0 = ct * 32;
  const float* W; int ldw, sc0;
  if      (gc0 < 384)  { W = Wvec; ldw = 384; sc0 = gc0; }
  else if (gc0 < 512)  { W = Wtrg; ldw = 128; sc0 = gc0 - 384; }
  else if (gc0 < 640)  { W = Wsrc; ldw = 128; sc0 = gc0 - 512; }
  else if (gc0 < 768)  { W = Wq;   ldw = 128; sc0 = gc0 - 640; }
  else if (gc0 < 896)  { W = Wk;   ldw = 128; sc0 = gc0 - 768; }
  else if (gc0 < 1024) { W = Wv;   ldw = 128; sc0 = gc0 - 896; }
  else if (gc0 < 1152) { W = Wdk;  ldw = 128; sc0 = gc0 - 1024; }
  else if (gc0 < 1280) { W = Wdv;  ldw = 128; sc0 = gc0 - 1152; }
  else if (gc0 < 1408) { W = Wf;   ldw = 128; sc0 = gc0 - 1280; }
  else if (gc0 < 1664) { W = Ws;   ldw = 256; sc0 = gc0 - 1408; }
  else                 { W = Wo;   ldw = 384; sc0 = gc0 - 1664; }
  __shared__ float tile[32][33];
  int tx = t & 31, ty = t >> 5;
#pragma unroll
  for (int i = 0; i < 4; ++i)
    tile[ty + i * 8][tx] = W[(size_t)(kt * 32 + ty + i * 8) * ldw + sc0 + tx];
  __syncthreads();
#pragma unroll
  for (int i = 0; i < 4; ++i)
    Wt[(size_t)(gc0 + ty + i * 8) * 128 + kt * 32 + tx] = (__bf16)tile[tx][ty + i * 8];
}

// ---------------- vdot GEMM: dedicated kernel, no spill ----------------
__global__ __launch_bounds__(256, 2) void vdot_gemm(const __bf16* __restrict__ A,
                                                    const __bf16* __restrict__ Bt,
                                                    float* __restrict__ vdot) {
  __shared__ __bf16 As[128 * 128];
  const int tid = threadIdx.x;
  const int lane = tid & 63;
  const int wave = tid >> 6;
  const int wm = wave >> 1, wn = wave & 1;
  const int row0 = blockIdx.x * 128;

#pragma unroll
  for (int i = 0; i < 8; ++i) {
    int c = tid + i * 256;
    int row = c >> 4, k8 = c & 15;
    int k8s = k8 ^ (row & 7);
    const __bf16* src = A + (size_t)(row0 + row) * 128 + k8s * 8;
    __builtin_amdgcn_global_load_lds((const __attribute__((address_space(1))) void*)src,
                                     (__attribute__((address_space(3))) void*)(As + c * 8),
                                     16, 0, 0);
  }
  __syncthreads();

  f32x4 pacc[4][4], acc[4][4];
#pragma unroll
  for (int mi = 0; mi < 4; ++mi)
#pragma unroll
    for (int ni = 0; ni < 4; ++ni) {
      pacc[mi][ni] = f32x4{0.f, 0.f, 0.f, 0.f};
      acc[mi][ni] = f32x4{0.f, 0.f, 0.f, 0.f};
    }
#pragma unroll
  for (int ct = 0; ct < 2; ++ct) {
    const __bf16* Bbase =
        Bt + ((size_t)(ct * 128 + wn * 64 + (lane & 15)) << 7) + ((lane >> 4) << 3);
#pragma unroll
    for (int ks = 0; ks < 4; ++ks) {
      bf16x8 b[4];
#pragma unroll
      for (int ni = 0; ni < 4; ++ni) b[ni] = *(const bf16x8*)(Bbase + (ni << 11) + (ks << 5));
      bf16x8 a[4];
#pragma unroll
      for (int mi = 0; mi < 4; ++mi) {
        int row = wm * 64 + mi * 16 + (lane & 15);
        int byte = (row * 256 + ks * 64 + ((lane >> 4) << 4)) ^ ((row & 7) << 4);
        a[mi] = *(const bf16x8*)((const char*)As + byte);
      }
      if (ct == 0) {
#pragma unroll
        for (int mi = 0; mi < 4; ++mi)
#pragma unroll
          for (int ni = 0; ni < 4; ++ni)
            pacc[mi][ni] =
                __builtin_amdgcn_mfma_f32_16x16x32_bf16(a[mi], b[ni], pacc[mi][ni], 0, 0, 0);
      } else {
#pragma unroll
        for (int mi = 0; mi < 4; ++mi)
#pragma unroll
          for (int ni = 0; ni < 4; ++ni)
            acc[mi][ni] =
                __builtin_amdgcn_mfma_f32_16x16x32_bf16(a[mi], b[ni], acc[mi][ni], 0, 0, 0);
      }
    }
  }
#pragma unroll
  for (int mi = 0; mi < 4; ++mi) {
#pragma unroll
    for (int ni = 0; ni < 4; ++ni) {
      float sr = pacc[mi][ni][0] * acc[mi][ni][0] + pacc[mi][ni][1] * acc[mi][ni][1] +
                 pacc[mi][ni][2] * acc[mi][ni][2] + pacc[mi][ni][3] * acc[mi][ni][3];
      sr += __shfl_xor(sr, 16, 64);
      if ((lane & 16) == 0) {
        int node = (row0 >> 3) + wm * 8 + mi * 2 + (lane >> 5);
        int col = wn * 64 + ni * 16 + (lane & 15);
        vdot[(size_t)node * 128 + col] = sr;
      }
    }
  }
}

// ---------------- MFMA GEMM v9: bf16-A only (global_load_lds); XCD-swizzled 1D grid ----------
template <typename CT>
__global__ __launch_bounds__(256, 3) void gemm_v9(const __bf16* __restrict__ A,
                                                  const __bf16* __restrict__ Bt,
                                                  const float* __restrict__ bias,
                                                  CT* __restrict__ C, int M, int nx, int ny,
                                                  int ldc, int act) {
  __shared__ __bf16 As[128 * 128];
  __bf16* Cs = As;  // post-barrier reuse; 64*136*2B = 17.4KB <= 32KB
  const int bid = blockIdx.x;
  const int xi = bid & 7;
  const int rem = bid >> 3;
  const int y = rem % ny;
  const int x = (rem / ny) * 8 + xi;
  if (x >= nx) return;
  const int tid = threadIdx.x;
  const int lane = tid & 63;
  const int wave = tid >> 6;
  const int wm = wave >> 1, wn = wave & 1;
  const int row0 = x * 128;

#pragma unroll
  for (int i = 0; i < 8; ++i) {
    int c = tid + i * 256;  // 16B chunk; LDS dest linear
    int row = c >> 4, k8 = c & 15;
    int k8s = k8 ^ (row & 7);  // inverse-swizzled source == read-side XOR
    const __bf16* src = A + (size_t)(row0 + row) * 128 + k8s * 8;
    __builtin_amdgcn_global_load_lds((const __attribute__((address_space(1))) void*)src,
                                     (__attribute__((address_space(3))) void*)(As + c * 8),
                                     16, 0, 0);
  }
  __syncthreads();

  // hoist all 16 B fragments (one wait; weights L2-hot)
  const __bf16* Bbase =
      Bt + ((size_t)(y * 128 + wn * 64 + (lane & 15)) << 7) + ((lane >> 4) << 3);
  bf16x8 b[4][4];
#pragma unroll
  for (int ks = 0; ks < 4; ++ks)
#pragma unroll
    for (int ni = 0; ni < 4; ++ni) b[ks][ni] = *(const bf16x8*)(Bbase + (ni << 11) + (ks << 5));

  f32x4 acc[4][4];
#pragma unroll
  for (int mi = 0; mi < 4; ++mi)
#pragma unroll
    for (int ni = 0; ni < 4; ++ni) acc[mi][ni] = f32x4{0.f, 0.f, 0.f, 0.f};

#pragma unroll
  for (int ks = 0; ks < 4; ++ks) {
    bf16x8 a[4];
#pragma unroll
    for (int mi = 0; mi < 4; ++mi) {
      int row = wm * 64 + mi * 16 + (lane & 15);
      int byte = (row * 256 + ks * 64 + ((lane >> 4) << 4)) ^ ((row & 7) << 4);
      a[mi] = *(const bf16x8*)((const char*)As + byte);
    }
#pragma unroll
    for (int mi = 0; mi < 4; ++mi)
#pragma unroll
      for (int ni = 0; ni < 4; ++ni)
        acc[mi][ni] =
            __builtin_amdgcn_mfma_f32_16x16x32_bf16(a[mi], b[ks][ni], acc[mi][ni], 0, 0, 0);
  }

  const int cstore = y * 128;
  if constexpr (sizeof(CT) == 2) {
#pragma unroll
    for (int p = 0; p < 2; ++p) {
      __syncthreads();
      int rl = (wm << 5) | ((lane >> 4) << 2);
#pragma unroll
      for (int q = 0; q < 2; ++q) {
        int mi = 2 * p + q;
#pragma unroll
        for (int ni = 0; ni < 4; ++ni) {
          int col = wn * 64 + ni * 16 + (lane & 15);
          float bv = bias ? bias[cstore + col] : 0.f;
#pragma unroll
          for (int r = 0; r < 4; ++r) {
            float xv = acc[mi][ni][r] + bv;
            if (act) xv = silu_f(xv);
            Cs[(rl + q * 16 + r) * 136 + col] = (__bf16)xv;
          }
        }
      }
      __syncthreads();
#pragma unroll
      for (int rr = 0; rr < 4; ++rr) {
        int row = (tid >> 4) + rr * 16;  // 0..63
        int chunk = tid & 15;
        bf16x8 v = *(const bf16x8*)(Cs + row * 136 + chunk * 8);
        int grow = row0 + (row >> 5) * 64 + (2 * p + ((row >> 4) & 1)) * 16 + (row & 15);
        if (grow < M)
          *(bf16x8*)(C + (size_t)grow * ldc + cstore + chunk * 8) = v;
      }
    }
  } else {
#pragma unroll
    for (int mi = 0; mi < 4; ++mi) {
      int rbase = row0 + wm * 64 + mi * 16 + ((lane >> 4) << 2);
#pragma unroll
      for (int ni = 0; ni < 4; ++ni) {
        int gcol = cstore + wn * 64 + ni * 16 + (lane & 15);
        float bv = bias ? bias[cstore + wn * 64 + ni * 16 + (lane & 15)] : 0.f;
#pragma unroll
        for (int r = 0; r < 4; ++r) {
          int grow = rbase + r;
          if (grow < M) {
            float xv = acc[mi][ni][r] + bv;
            if (act) xv = silu_f(xv);
            C[(size_t)grow * ldc + gcol] = (CT)xv;
          }
        }
      }
    }
  }
}

// helper: swizzled grid size
static inline int swz_grid(int nx, int ny) { return ((nx + 7) / 8) * ny * 8; }

// ---------------- message (CSR dst-ordered): attn + vm per edge ----------------
__global__ __launch_bounds__(256) void msg_kernel(const __bf16* __restrict__ qkv,
                                                  const __bf16* __restrict__ fm,
                                                  const float* __restrict__ r_ij,
                                                  const int* __restrict__ ei,
                                                  const int* __restrict__ elist,
                                                  __bf16* __restrict__ vm) {
  int p = blockIdx.x * 2 + (threadIdx.x >> 7);
  int h = threadIdx.x & 127;
  int e = elist[p];
  int src = ei[e], dst = ei[N_EDGES + e];
  float qv = (float)qkv[(size_t)dst * 384 + h];
  float kv = (float)qkv[(size_t)src * 384 + 128 + h];
  float vv = (float)qkv[(size_t)src * 384 + 256 + h];
  float t = qv * kv * (float)fm[(size_t)e * 384 + h];
#pragma unroll
  for (int off = 8; off >= 1; off >>= 1) t += __shfl_xor(t, off, 16);
  float r = r_ij[e];
  float cut = 0.5f * (__cosf(0.6283185307f * r) + 1.f);
  cut = (r < 5.f) ? cut : 0.f;
  float attn = silu_f(t) * cut;
  vm[(size_t)e * H + h] = (__bf16)(vv * (float)fm[(size_t)e * 384 + 128 + h] * attn);
}

// ---------------- CSR build: histogram, scan, fill ----------------
__global__ __launch_bounds__(256) void hist_kernel(const int* __restrict__ ei,
                                                   int* __restrict__ cnt) {
  int e = blockIdx.x * 256 + threadIdx.x;
  if (e < N_EDGES) atomicAdd(&cnt[ei[N_EDGES + e]], 1);
}

__global__ __launch_bounds__(1024) void scan_kernel(const int* __restrict__ cnt,
                                                    int* __restrict__ rowptr) {
  __shared__ int wsum[16];
  int t = threadIdx.x;
  int base = t * 10;
  int local[10];
  int s = 0;
#pragma unroll
  for (int i = 0; i < 10; ++i) {
    int v = (base + i < N_NODES) ? cnt[base + i] : 0;
    local[i] = s;
    s += v;
  }
  int lane = t & 63, wave = t >> 6;
  int inc = s;
#pragma unroll
  for (int off = 1; off < 64; off <<= 1) {
    int u = __shfl_up(inc, off, 64);
    if (lane >= off) inc += u;
  }
  if (lane == 63) wsum[wave] = inc;
  __syncthreads();
  if (t == 0) {
    int acc = 0;
#pragma unroll
    for (int w = 0; w < 16; ++w) { int v = wsum[w]; wsum[w] = acc; acc += v; }
  }
  __syncthreads();
  int excl = inc - s + wsum[wave];
#pragma unroll
  for (int i = 0; i < 10; ++i)
    if (base + i <= N_NODES) rowptr[base + i] = excl + local[i];
}

__global__ __launch_bounds__(256) void fill_kernel(const int* __restrict__ ei,
                                                   const int* __restrict__ rowptr,
                                                   int* __restrict__ cursor,
                                                   int* __restrict__ elist) {
  int e = blockIdx.x * 256 + threadIdx.x;
  if (e < N_EDGES) {
    int d = ei[N_EDGES + e];
    int p = atomicAdd(&cursor[d], 1);
    elist[rowptr[d] + p] = e;
  }
}

// ---------------- node kernel: gather (x_agg, dvec) + edge update (df), node-major ----------
// vt[dst] loaded ONCE per node into registers; per edge: vm/s/vecw[src] (gather stream)
// and vs[src]/fm-dfw (edge-update stream) overlap for latency hiding.
__global__ __launch_bounds__(256) void node_kernel(const __bf16* __restrict__ vm,
                                                   const __bf16* __restrict__ s,
                                                   const __bf16* __restrict__ vecw,
                                                   const __bf16* __restrict__ big,
                                                   const __bf16* __restrict__ fm,
                                                   const float* __restrict__ d_ij,
                                                   const int* __restrict__ ei,
                                                   const int* __restrict__ rowptr,
                                                   const int* __restrict__ elist,
                                                   __bf16* __restrict__ x_agg,
                                                   float* __restrict__ dvec,
                                                   float* __restrict__ df) {
  int n = blockIdx.x * 2 + (threadIdx.x >> 7);
  int h = threadIdx.x & 127;
  if (n >= N_NODES) return;
  int beg = rowptr[n], end = rowptr[n + 1];

  // vt[n] once (big cols 128..255, row stride 384)
  float vt[L];
  const __bf16* trow = big + (size_t)n * 8 * 384 + 128 + h;
#pragma unroll
  for (int l = 0; l < L; l++) vt[l] = (float)trow[l * 384];

  float ax = 0.f;
  float av[L] = {};
  for (int p = beg; p < end; ++p) {
    int e = elist[p];
    int src = ei[e];
    const float* dd = d_ij + (size_t)e * L;
    float d[L], sd2 = 0.f;
#pragma unroll
    for (int l = 0; l < L; l++) {
      d[l] = dd[l];
      sd2 += d[l] * d[l];
    }
    ax += (float)vm[(size_t)e * H + h];
    float s1 = (float)s[(size_t)e * 256 + h];
    float s2 = (float)s[(size_t)e * 256 + 128 + h];
    const __bf16* vrow = vecw + (size_t)src * L * H + h;
    const __bf16* brow = big + (size_t)src * 8 * 384 + 256 + h;  // vs[src]
    float dot = 0.f, p1 = 0.f, p2 = 0.f;
#pragma unroll
    for (int l = 0; l < L; l++) {
      float vw = (float)vrow[l * H];
      av[l] += vw * s1 + s2 * d[l];
      float bb = (float)brow[l * 384];
      dot += vt[l] * bb;
      p1 += vt[l] * d[l];
      p2 += bb * d[l];
    }
    float wdot = dot - p1 * p2 * (2.f - sd2);
    df[(size_t)e * H + h] = (float)fm[(size_t)e * 384 + 256 + h] * wdot;
  }
  x_agg[(size_t)n * H + h] = (__bf16)ax;
  float* drow = dvec + (size_t)n * L * H + h;
#pragma unroll
  for (int l = 0; l < L; l++) drow[l * H] = av[l];
}

// ---------------- final node update (vec3 = big cols 0..127) ----------------
__global__ __launch_bounds__(256) void final_kernel(const float* __restrict__ o,
                                                    const float* __restrict__ vdot,
                                                    const __bf16* __restrict__ big,
                                                    float* __restrict__ dx,
                                                    float* __restrict__ dvec, int n_nodes) {
  int n = blockIdx.x * 2 + (threadIdx.x >> 7);
  int h = threadIdx.x & 127;
  if (n >= n_nodes) return;
  float o1 = o[(size_t)n * 384 + h];
  float o2 = o[(size_t)n * 384 + 128 + h];
  float o3 = o[(size_t)n * 384 + 256 + h];
  dx[(size_t)n * H + h] = vdot[(size_t)n * H + h] * o2 + o3;
  float* drow = dvec + (size_t)n * L * H + h;
  const __bf16* v3 = big + (size_t)n * 8 * 384 + h;
#pragma unroll
  for (int l = 0; l < L; l++) drow[l * H] += (float)v3[l * 384] * o1;
}

extern "C" void kernel_launch(void* const* d_in, const int* in_sizes, int n_in, void* d_out,
                              int out_size, void* d_ws, size_t ws_size, hipStream_t stream) {
  const float* x = (const float*)d_in[0];
  const float* vec = (const float*)d_in[1];
  const float* f_ij = (const float*)d_in[2];
  const float* d_ij = (const float*)d_in[3];
  const float* r_ij = (const float*)d_in[4];
  const int* ei = (const int*)d_in[5];
  const float* ln_g = (const float*)d_in[6];
  const float* ln_b = (const float*)d_in[7];
  const float* vln_w = (const float*)d_in[8];
  const float* W_vec = (const float*)d_in[9];
  const float* W_q = (const float*)d_in[10];
  const float* b_q = (const float*)d_in[11];
  const float* W_k = (const float*)d_in[12];
  const float* b_k = (const float*)d_in[13];
  const float* W_v = (const float*)d_in[14];
  const float* b_v = (const float*)d_in[15];
  const float* W_dk = (const float*)d_in[16];
  const float* b_dk = (const float*)d_in[17];
  const float* W_dv = (const float*)d_in[18];
  const float* b_dv = (const float*)d_in[19];
  const float* W_s = (const float*)d_in[20];
  const float* b_s = (const float*)d_in[21];
  const float* W_f = (const float*)d_in[22];
  const float* b_f = (const float*)d_in[23];
  const float* W_src = (const float*)d_in[24];
  const float* W_trg = (const float*)d_in[25];
  const float* W_o = (const float*)d_in[26];
  const float* b_o = (const float*)d_in[27];

  float* out = (float*)d_out;
  float* dx = out;
  float* dvec = out + (size_t)N_NODES * H;
  float* df = dvec + (size_t)N_NODES * L * H;

  // ---- workspace plan (~224 MB; offsets in f32 slots) ----
  float* ws = (float*)d_ws;
  __bf16* vecw = (__bf16*)ws;                 // NL*128 bf16
  __bf16* big = (__bf16*)(ws + 5120000);      // NL*384 bf16: [vec3 128 | vt 128 | vs 128]
  __bf16* fm = (__bf16*)(ws + 20480000);      // E*384 bf16: [dk | dv | dfw]
  __bf16* vm = (__bf16*)(ws + 32768000);      // E*128 bf16
  __bf16* s_buf = (__bf16*)(ws + 36864000);   // E*256 bf16
  __bf16* qkv = (__bf16*)(ws + 45056000);     // N*384 bf16 (region reused as o_buf f32)
  __bf16* xln = (__bf16*)(ws + 48896000);     // N*128 bf16 (+tail slack)
  __bf16* xagg = (__bf16*)(ws + 49536000);    // N*128 bf16 (+tail slack)
  float* vdot = ws + 50176000;                // N*128 f32
  __bf16* Wt = (__bf16*)(ws + 51456000);      // [2048][128] bf16
  float* bqkv = ws + 51456000 + 131072;       // 384
  float* bfm = bqkv + 384;                    // 384
  int* rowptr = (int*)(bfm + 384);            // 10,001
  int* elist = rowptr + 10001;                // 64,000
  int* cnt = elist + 64000;                   // 10,000
  int* cursor = cnt + 10000;                  // 10,000
  __bf16* fijb = (__bf16*)(ws + 51800000);    // E*128 bf16

  float* o_buf = ws + 45056000;  // overwrites qkv after it's consumed (step 6)

  dim3 b256(256);

  // CSR build (depends only on ei)
  hipMemsetAsync(cnt, 0, N_NODES * sizeof(int), stream);
  hipMemsetAsync(cursor, 0, N_NODES * sizeof(int), stream);
  hist_kernel<<<dim3((N_EDGES + 255) / 256), b256, 0, stream>>>(ei, cnt);
  scan_kernel<<<dim3(1), dim3(1024), 0, stream>>>(cnt, rowptr);
  fill_kernel<<<dim3((N_EDGES + 255) / 256), b256, 0, stream>>>(ei, rowptr, cursor, elist);

  // 0. weight convert/transpose + bias concat; f_ij -> bf16
  wconv_kernel<<<dim3(258), b256, 0, stream>>>(W_vec, W_q, W_k, W_v, W_dk, W_dv, W_s, W_trg,
                                               W_src, W_f, W_o, b_q, b_k, b_v, b_dk, b_dv, b_f,
                                               Wt, bqkv, bfm);
  f2b_kernel<<<dim3(2048), b256, 0, stream>>>(f_ij, fijb, (size_t)N_EDGES * H / 8);
  // 1. x_ln = layernorm(x) -> bf16
  ln_kernel<<<dim3((N_NODES + 3) / 4), b256, 0, stream>>>(x, ln_g, ln_b, xln, N_NODES);
  // 2. vecw = vec * vln_w (bf16)
  vecw_kernel<<<dim3(2048), b256, 0, stream>>>(vec, vln_w, vecw, (size_t)NL * H / 8);
  // 3a. vdot (dedicated, no-spill kernel; Wt rows 0..255 = vec1|vec2)
  vdot_gemm<<<dim3(625), b256, 0, stream>>>(vecw, Wt, vdot);
  // 3b. big = vecw @ [vec3|Wtrg|Wsrc] (Wt rows 256..639); XCD-swizzled, ny=3
  gemm_v9<__bf16><<<dim3(swz_grid(625, 3)), b256, 0, stream>>>(
      vecw, Wt + (size_t)256 * 128, nullptr, big, NL, 625, 3, 384, 0);
  // 4. qkv = xln @ [Wq|Wk|Wv] + b (bf16 out)
  gemm_v9<__bf16><<<dim3(swz_grid(79, 3)), b256, 0, stream>>>(
      xln, Wt + (size_t)640 * 128, bqkv, qkv, N_NODES, 79, 3, 384, 0);
  // 5. fm = silu(fijb @ [Wdk|Wdv|Wf] + b)
  gemm_v9<__bf16><<<dim3(swz_grid(500, 3)), b256, 0, stream>>>(
      fijb, Wt + (size_t)1024 * 128, bfm, fm, N_EDGES, 500, 3, 384, 1);
  // 6. message -> vm (bf16); CSR dst-ordered for qkv[dst] L2 locality
  msg_kernel<<<dim3(N_EDGES / 2), b256, 0, stream>>>(qkv, fm, r_ij, ei, elist, vm);
  // 7. s = silu(vm @ W_s + b)
  gemm_v9<__bf16><<<dim3(swz_grid(500, 2)), b256, 0, stream>>>(
      vm, Wt + (size_t)1408 * 128, b_s, s_buf, N_EDGES, 500, 2, 256, 1);
  // 8. node-major: gather (x_agg, dvec) + edge update (df) in one pass
  node_kernel<<<dim3(N_NODES / 2), b256, 0, stream>>>(vm, s_buf, vecw, big, fm, d_ij, ei,
                                                      rowptr, elist, xagg, dvec, df);
  // 9. o = xagg @ W_o + b (f32 out; overwrites qkv region: consumed in 6)
  gemm_v9<float><<<dim3(swz_grid(79, 3)), b256, 0, stream>>>(
      xagg, Wt + (size_t)1664 * 128, b_o, o_buf, N_NODES, 79, 3, 384, 0);
  // 10. final: dx, dvec += vec3*o1
  final_kernel<<<dim3(5000), b256, 0, stream>>>(o_buf, vdot, big, dx, dvec, N_NODES);
}

// Round 16
// 309.028 us; speedup vs baseline: 1.3812x; 1.0405x over previous
//
#include <hip/hip_runtime.h>
#include <hip/hip_bf16.h>
#include <math.h>

#define N_NODES 10000
#define N_EDGES 64000
#define H 128
#define L 8
#define NL (N_NODES * L)

typedef __attribute__((ext_vector_type(4))) float f32x4;
typedef __attribute__((ext_vector_type(8))) __bf16 bf16x8;
typedef __attribute__((ext_vector_type(4))) __bf16 bf16x4;

__device__ __forceinline__ float silu_f(float x) { return x / (1.f + __expf(-x)); }

// ---------------- LayerNorm: one wave per node -> bf16 out ----------------
__global__ __launch_bounds__(256) void ln_kernel(const float* __restrict__ x,
                                                 const float* __restrict__ g,
                                                 const float* __restrict__ b,
                                                 __bf16* __restrict__ out, int n_nodes) {
  int wave = threadIdx.x >> 6;
  int lane = threadIdx.x & 63;
  int n = blockIdx.x * 4 + wave;
  if (n >= n_nodes) return;
  const float* xr = x + (size_t)n * H;
  float a0 = xr[lane], a1 = xr[lane + 64];
  float s = a0 + a1;
#pragma unroll
  for (int off = 32; off >= 1; off >>= 1) s += __shfl_xor(s, off, 64);
  float mu = s * (1.f / H);
  float d0 = a0 - mu, d1 = a1 - mu;
  float v = d0 * d0 + d1 * d1;
#pragma unroll
  for (int off = 32; off >= 1; off >>= 1) v += __shfl_xor(v, off, 64);
  float rstd = rsqrtf(v * (1.f / H) + 1e-5f);
  __bf16* orow = out + (size_t)n * H;
  orow[lane] = (__bf16)(d0 * rstd * g[lane] + b[lane]);
  orow[lane + 64] = (__bf16)(d1 * rstd * g[lane + 64] + b[lane + 64]);
}

// ---------------- vecw = vec * vln_w  -> bf16 ----------------
__global__ __launch_bounds__(256) void vecw_kernel(const float* __restrict__ vec,
                                                   const float* __restrict__ w,
                                                   __bf16* __restrict__ out, size_t total8) {
  size_t i = (size_t)blockIdx.x * blockDim.x + threadIdx.x;
  size_t stride = (size_t)gridDim.x * blockDim.x;
  for (; i < total8; i += stride) {
    size_t base = i * 8;
    f32x4 a = *(const f32x4*)(vec + base);
    f32x4 b = *(const f32x4*)(vec + base + 4);
    int c = (int)(base & 127);
    bf16x8 h;
    h[0] = (__bf16)(a[0] * w[c + 0]); h[1] = (__bf16)(a[1] * w[c + 1]);
    h[2] = (__bf16)(a[2] * w[c + 2]); h[3] = (__bf16)(a[3] * w[c + 3]);
    h[4] = (__bf16)(b[0] * w[c + 4]); h[5] = (__bf16)(b[1] * w[c + 5]);
    h[6] = (__bf16)(b[2] * w[c + 6]); h[7] = (__bf16)(b[3] * w[c + 7]);
    *(bf16x8*)(out + base) = h;
  }
}

// ---------------- gather f_ij rows into CSR (p) order -> bf16 ----------------
__global__ __launch_bounds__(256) void gatherf2b_kernel(const float* __restrict__ in,
                                                        const int* __restrict__ elist,
                                                        __bf16* __restrict__ out) {
  int p = blockIdx.x * 8 + (threadIdx.x >> 5);
  int c = (threadIdx.x & 31) * 4;
  int e = elist[p];
  f32x4 a = *(const f32x4*)(in + (size_t)e * 128 + c);
  bf16x4 h;
  h[0] = (__bf16)a[0]; h[1] = (__bf16)a[1]; h[2] = (__bf16)a[2]; h[3] = (__bf16)a[3];
  *(bf16x4*)(out + (size_t)p * 128 + c) = h;
}

// ---------------- weight convert into one [2048][128] bf16 table ----------------
__global__ __launch_bounds__(256) void wconv_kernel(
    const float* __restrict__ Wvec, const float* __restrict__ Wq, const float* __restrict__ Wk,
    const float* __restrict__ Wv, const float* __restrict__ Wdk, const float* __restrict__ Wdv,
    const float* __restrict__ Ws, const float* __restrict__ Wtrg, const float* __restrict__ Wsrc,
    const float* __restrict__ Wf, const float* __restrict__ Wo,
    const float* __restrict__ bq, const float* __restrict__ bk, const float* __restrict__ bv,
    const float* __restrict__ bdk, const float* __restrict__ bdv, const float* __restrict__ bf,
    __bf16* __restrict__ Wt, float* __restrict__ bqkv, float* __restrict__ bfm) {
  int bid = blockIdx.x;
  int t = threadIdx.x;
  if (bid >= 256) {
    if (bid == 256) {
      if (t < 128) { bqkv[t] = bq[t]; bqkv[128 + t] = bk[t]; bqkv[256 + t] = bv[t]; }
    } else {
      if (t < 128) { bfm[t] = bdk[t]; bfm[128 + t] = bdv[t]; bfm[256 + t] = bf[t]; }
    }
    return;
  }
  int ct = bid >> 2, kt = bid & 3;
  int gc0 = ct * 32;
  const float* W; int ldw, sc0;
  if      (gc0 < 384)  { W = Wvec; ldw = 384; sc0 = gc0; }
  else if (gc0 < 512)  { W = Wtrg; ldw = 128; sc0 = gc0 - 384; }
  else if (gc0 < 640)  { W = Wsrc; ldw = 128; sc0 = gc0 - 512; }
  else if (gc0 < 768)  { W = Wq;   ldw = 128; sc0 = gc0 - 640; }
  else if (gc0 < 896)  { W = Wk;   ldw = 128; sc0 = gc0 - 768; }
  else if (gc0 < 1024) { W = Wv;   ldw = 128; sc0 = gc0 - 896; }
  else if (gc0 < 1152) { W = Wdk;  ldw = 128; sc0 = gc0 - 1024; }
  else if (gc0 < 1280) { W = Wdv;  ldw = 128; sc0 = gc0 - 1152; }
  else if (gc0 < 1408) { W = Wf;   ldw = 128; sc0 = gc0 - 1280; }
  else if (gc0 < 1664) { W = Ws;   ldw = 256; sc0 = gc0 - 1408; }
  else                 { W = Wo;   ldw = 384; sc0 = gc0 - 1664; }
  __shared__ float tile[32][33];
  int tx = t & 31, ty = t >> 5;
#pragma unroll
  for (int i = 0; i < 4; ++i)
    tile[ty + i * 8][tx] = W[(size_t)(kt * 32 + ty + i * 8) * ldw + sc0 + tx];
  __syncthreads();
#pragma unroll
  for (int i = 0; i < 4; ++i)
    Wt[(size_t)(gc0 + ty + i * 8) * 128 + kt * 32 + tx] = (__bf16)tile[tx][ty + i * 8];
}

// ---------------- vdot GEMM: dedicated kernel, no spill ----------------
__global__ __launch_bounds__(256, 2) void vdot_gemm(const __bf16* __restrict__ A,
                                                    const __bf16* __restrict__ Bt,
                                                    float* __restrict__ vdot) {
  __shared__ __bf16 As[128 * 128];
  const int tid = threadIdx.x;
  const int lane = tid & 63;
  const int wave = tid >> 6;
  const int wm = wave >> 1, wn = wave & 1;
  const int row0 = blockIdx.x * 128;

#pragma unroll
  for (int i = 0; i < 8; ++i) {
    int c = tid + i * 256;
    int row = c >> 4, k8 = c & 15;
    int k8s = k8 ^ (row & 7);
    const __bf16* src = A + (size_t)(row0 + row) * 128 + k8s * 8;
    __builtin_amdgcn_global_load_lds((const __attribute__((address_space(1))) void*)src,
                                     (__attribute__((address_space(3))) void*)(As + c * 8),
                                     16, 0, 0);
  }
  __syncthreads();

  f32x4 pacc[4][4], acc[4][4];
#pragma unroll
  for (int mi = 0; mi < 4; ++mi)
#pragma unroll
    for (int ni = 0; ni < 4; ++ni) {
      pacc[mi][ni] = f32x4{0.f, 0.f, 0.f, 0.f};
      acc[mi][ni] = f32x4{0.f, 0.f, 0.f, 0.f};
    }
#pragma unroll
  for (int ct = 0; ct < 2; ++ct) {
    const __bf16* Bbase =
        Bt + ((size_t)(ct * 128 + wn * 64 + (lane & 15)) << 7) + ((lane >> 4) << 3);
#pragma unroll
    for (int ks = 0; ks < 4; ++ks) {
      bf16x8 b[4];
#pragma unroll
      for (int ni = 0; ni < 4; ++ni) b[ni] = *(const bf16x8*)(Bbase + (ni << 11) + (ks << 5));
      bf16x8 a[4];
#pragma unroll
      for (int mi = 0; mi < 4; ++mi) {
        int row = wm * 64 + mi * 16 + (lane & 15);
        int byte = (row * 256 + ks * 64 + ((lane >> 4) << 4)) ^ ((row & 7) << 4);
        a[mi] = *(const bf16x8*)((const char*)As + byte);
      }
      if (ct == 0) {
#pragma unroll
        for (int mi = 0; mi < 4; ++mi)
#pragma unroll
          for (int ni = 0; ni < 4; ++ni)
            pacc[mi][ni] =
                __builtin_amdgcn_mfma_f32_16x16x32_bf16(a[mi], b[ni], pacc[mi][ni], 0, 0, 0);
      } else {
#pragma unroll
        for (int mi = 0; mi < 4; ++mi)
#pragma unroll
          for (int ni = 0; ni < 4; ++ni)
            acc[mi][ni] =
                __builtin_amdgcn_mfma_f32_16x16x32_bf16(a[mi], b[ni], acc[mi][ni], 0, 0, 0);
      }
    }
  }
#pragma unroll
  for (int mi = 0; mi < 4; ++mi) {
#pragma unroll
    for (int ni = 0; ni < 4; ++ni) {
      float sr = pacc[mi][ni][0] * acc[mi][ni][0] + pacc[mi][ni][1] * acc[mi][ni][1] +
                 pacc[mi][ni][2] * acc[mi][ni][2] + pacc[mi][ni][3] * acc[mi][ni][3];
      sr += __shfl_xor(sr, 16, 64);
      if ((lane & 16) == 0) {
        int node = (row0 >> 3) + wm * 8 + mi * 2 + (lane >> 5);
        int col = wn * 64 + ni * 16 + (lane & 15);
        vdot[(size_t)node * 128 + col] = sr;
      }
    }
  }
}

// ---------------- MFMA GEMM v9: bf16-A only (global_load_lds); XCD-swizzled 1D grid ----------
template <typename CT>
__global__ __launch_bounds__(256, 3) void gemm_v9(const __bf16* __restrict__ A,
                                                  const __bf16* __restrict__ Bt,
                                                  const float* __restrict__ bias,
                                                  CT* __restrict__ C, int M, int nx, int ny,
                                                  int ldc, int act) {
  __shared__ __bf16 As[128 * 128];
  __bf16* Cs = As;
  const int bid = blockIdx.x;
  const int xi = bid & 7;
  const int rem = bid >> 3;
  const int y = rem % ny;
  const int x = (rem / ny) * 8 + xi;
  if (x >= nx) return;
  const int tid = threadIdx.x;
  const int lane = tid & 63;
  const int wave = tid >> 6;
  const int wm = wave >> 1, wn = wave & 1;
  const int row0 = x * 128;

#pragma unroll
  for (int i = 0; i < 8; ++i) {
    int c = tid + i * 256;
    int row = c >> 4, k8 = c & 15;
    int k8s = k8 ^ (row & 7);
    const __bf16* src = A + (size_t)(row0 + row) * 128 + k8s * 8;
    __builtin_amdgcn_global_load_lds((const __attribute__((address_space(1))) void*)src,
                                     (__attribute__((address_space(3))) void*)(As + c * 8),
                                     16, 0, 0);
  }
  __syncthreads();

  const __bf16* Bbase =
      Bt + ((size_t)(y * 128 + wn * 64 + (lane & 15)) << 7) + ((lane >> 4) << 3);
  bf16x8 b[4][4];
#pragma unroll
  for (int ks = 0; ks < 4; ++ks)
#pragma unroll
    for (int ni = 0; ni < 4; ++ni) b[ks][ni] = *(const bf16x8*)(Bbase + (ni << 11) + (ks << 5));

  f32x4 acc[4][4];
#pragma unroll
  for (int mi = 0; mi < 4; ++mi)
#pragma unroll
    for (int ni = 0; ni < 4; ++ni) acc[mi][ni] = f32x4{0.f, 0.f, 0.f, 0.f};

#pragma unroll
  for (int ks = 0; ks < 4; ++ks) {
    bf16x8 a[4];
#pragma unroll
    for (int mi = 0; mi < 4; ++mi) {
      int row = wm * 64 + mi * 16 + (lane & 15);
      int byte = (row * 256 + ks * 64 + ((lane >> 4) << 4)) ^ ((row & 7) << 4);
      a[mi] = *(const bf16x8*)((const char*)As + byte);
    }
#pragma unroll
    for (int mi = 0; mi < 4; ++mi)
#pragma unroll
      for (int ni = 0; ni < 4; ++ni)
        acc[mi][ni] =
            __builtin_amdgcn_mfma_f32_16x16x32_bf16(a[mi], b[ks][ni], acc[mi][ni], 0, 0, 0);
  }

  const int cstore = y * 128;
  if constexpr (sizeof(CT) == 2) {
#pragma unroll
    for (int p = 0; p < 2; ++p) {
      __syncthreads();
      int rl = (wm << 5) | ((lane >> 4) << 2);
#pragma unroll
      for (int q = 0; q < 2; ++q) {
        int mi = 2 * p + q;
#pragma unroll
        for (int ni = 0; ni < 4; ++ni) {
          int col = wn * 64 + ni * 16 + (lane & 15);
          float bv = bias ? bias[cstore + col] : 0.f;
#pragma unroll
          for (int r = 0; r < 4; ++r) {
            float xv = acc[mi][ni][r] + bv;
            if (act) xv = silu_f(xv);
            Cs[(rl + q * 16 + r) * 136 + col] = (__bf16)xv;
          }
        }
      }
      __syncthreads();
#pragma unroll
      for (int rr = 0; rr < 4; ++rr) {
        int row = (tid >> 4) + rr * 16;
        int chunk = tid & 15;
        bf16x8 v = *(const bf16x8*)(Cs + row * 136 + chunk * 8);
        int grow = row0 + (row >> 5) * 64 + (2 * p + ((row >> 4) & 1)) * 16 + (row & 15);
        if (grow < M)
          *(bf16x8*)(C + (size_t)grow * ldc + cstore + chunk * 8) = v;
      }
    }
  } else {
#pragma unroll
    for (int mi = 0; mi < 4; ++mi) {
      int rbase = row0 + wm * 64 + mi * 16 + ((lane >> 4) << 2);
#pragma unroll
      for (int ni = 0; ni < 4; ++ni) {
        int gcol = cstore + wn * 64 + ni * 16 + (lane & 15);
        float bv = bias ? bias[cstore + wn * 64 + ni * 16 + (lane & 15)] : 0.f;
#pragma unroll
        for (int r = 0; r < 4; ++r) {
          int grow = rbase + r;
          if (grow < M) {
            float xv = acc[mi][ni][r] + bv;
            if (act) xv = silu_f(xv);
            C[(size_t)grow * ldc + gcol] = (CT)xv;
          }
        }
      }
    }
  }
}

// ---------------- big GEMM: y=0 -> vec3 [NL][128]; y=1 -> vtT; y=2 -> vsT (transposed) ----
// vtT/vsT layout: [node][h][8] bf16 -> node_kernel reads one 16B chunk per node.
__global__ __launch_bounds__(256, 3) void gemm_big(const __bf16* __restrict__ A,
                                                   const __bf16* __restrict__ Bt,
                                                   __bf16* __restrict__ vec3,
                                                   __bf16* __restrict__ vtT,
                                                   __bf16* __restrict__ vsT, int nx) {
  __shared__ __bf16 As[128 * 128];
  __bf16* Cs = As;
  const int bid = blockIdx.x;
  const int xi = bid & 7;
  const int rem = bid >> 3;
  const int y = rem % 3;
  const int x = (rem / 3) * 8 + xi;
  if (x >= nx) return;
  const int tid = threadIdx.x;
  const int lane = tid & 63;
  const int wave = tid >> 6;
  const int wm = wave >> 1, wn = wave & 1;
  const int row0 = x * 128;

#pragma unroll
  for (int i = 0; i < 8; ++i) {
    int c = tid + i * 256;
    int row = c >> 4, k8 = c & 15;
    int k8s = k8 ^ (row & 7);
    const __bf16* src = A + (size_t)(row0 + row) * 128 + k8s * 8;
    __builtin_amdgcn_global_load_lds((const __attribute__((address_space(1))) void*)src,
                                     (__attribute__((address_space(3))) void*)(As + c * 8),
                                     16, 0, 0);
  }
  __syncthreads();

  const __bf16* Bbase =
      Bt + ((size_t)(y * 128 + wn * 64 + (lane & 15)) << 7) + ((lane >> 4) << 3);
  bf16x8 b[4][4];
#pragma unroll
  for (int ks = 0; ks < 4; ++ks)
#pragma unroll
    for (int ni = 0; ni < 4; ++ni) b[ks][ni] = *(const bf16x8*)(Bbase + (ni << 11) + (ks << 5));

  f32x4 acc[4][4];
#pragma unroll
  for (int mi = 0; mi < 4; ++mi)
#pragma unroll
    for (int ni = 0; ni < 4; ++ni) acc[mi][ni] = f32x4{0.f, 0.f, 0.f, 0.f};

#pragma unroll
  for (int ks = 0; ks < 4; ++ks) {
    bf16x8 a[4];
#pragma unroll
    for (int mi = 0; mi < 4; ++mi) {
      int row = wm * 64 + mi * 16 + (lane & 15);
      int byte = (row * 256 + ks * 64 + ((lane >> 4) << 4)) ^ ((row & 7) << 4);
      a[mi] = *(const bf16x8*)((const char*)As + byte);
    }
#pragma unroll
    for (int mi = 0; mi < 4; ++mi)
#pragma unroll
      for (int ni = 0; ni < 4; ++ni)
        acc[mi][ni] =
            __builtin_amdgcn_mfma_f32_16x16x32_bf16(a[mi], b[ks][ni], acc[mi][ni], 0, 0, 0);
  }

  __bf16* T = (y == 1) ? vtT : vsT;
#pragma unroll
  for (int p = 0; p < 2; ++p) {
    __syncthreads();
    int rl = (wm << 5) | ((lane >> 4) << 2);
#pragma unroll
    for (int q = 0; q < 2; ++q) {
      int mi = 2 * p + q;
#pragma unroll
      for (int ni = 0; ni < 4; ++ni) {
        int col = wn * 64 + ni * 16 + (lane & 15);
#pragma unroll
        for (int r = 0; r < 4; ++r)
          Cs[(rl + q * 16 + r) * 136 + col] = (__bf16)acc[mi][ni][r];
      }
    }
    __syncthreads();
    if (y == 0) {
      // normal store: vec3 [NL][128]
#pragma unroll
      for (int rr = 0; rr < 4; ++rr) {
        int row = (tid >> 4) + rr * 16;
        int chunk = tid & 15;
        bf16x8 v = *(const bf16x8*)(Cs + row * 136 + chunk * 8);
        int grow = row0 + (row >> 5) * 64 + (2 * p + ((row >> 4) & 1)) * 16 + (row & 15);
        *(bf16x8*)(vec3 + (size_t)grow * 128 + chunk * 8) = v;
      }
    } else {
      // transposed store: T[node][h][8]; Cs holds 8 complete nodes this stage
#pragma unroll
      for (int j = 0; j < 4; ++j) {
        int idx = tid + 256 * j;
        int node_idx = idx >> 7;  // 0..7
        int h = idx & 127;
        int wmm = node_idx >> 2, qq = (node_idx >> 1) & 1, w = node_idx & 1;
        int base = wmm * 32 + qq * 16 + w * 8;
        bf16x8 v;
#pragma unroll
        for (int l = 0; l < 8; ++l) v[l] = Cs[(base + l) * 136 + h];
        int g = (row0 >> 3) + wmm * 8 + (2 * p + qq) * 2 + w;
        *(bf16x8*)(T + (size_t)g * 1024 + h * 8) = v;
      }
    }
  }
}

// helper: swizzled grid size
static inline int swz_grid(int nx, int ny) { return ((nx + 7) / 8) * ny * 8; }

// ---------------- message (CSR-ordered streams): attn + vm[p] ----------------
__global__ __launch_bounds__(256) void msg_kernel(const __bf16* __restrict__ qkv,
                                                  const __bf16* __restrict__ fm,
                                                  const float* __restrict__ r_ij,
                                                  const int* __restrict__ ei,
                                                  const int* __restrict__ elist,
                                                  __bf16* __restrict__ vm) {
  int p = blockIdx.x * 2 + (threadIdx.x >> 7);
  int h = threadIdx.x & 127;
  int e = elist[p];
  int src = ei[e], dst = ei[N_EDGES + e];
  float qv = (float)qkv[(size_t)dst * 384 + h];
  float kv = (float)qkv[(size_t)src * 384 + 128 + h];
  float vv = (float)qkv[(size_t)src * 384 + 256 + h];
  float t = qv * kv * (float)fm[(size_t)p * 384 + h];
#pragma unroll
  for (int off = 8; off >= 1; off >>= 1) t += __shfl_xor(t, off, 16);
  float r = r_ij[e];
  float cut = 0.5f * (__cosf(0.6283185307f * r) + 1.f);
  cut = (r < 5.f) ? cut : 0.f;
  float attn = silu_f(t) * cut;
  vm[(size_t)p * H + h] = (__bf16)(vv * (float)fm[(size_t)p * 384 + 128 + h] * attn);
}

// ---------------- CSR build: histogram, scan, fill ----------------
__global__ __launch_bounds__(256) void hist_kernel(const int* __restrict__ ei,
                                                   int* __restrict__ cnt) {
  int e = blockIdx.x * 256 + threadIdx.x;
  if (e < N_EDGES) atomicAdd(&cnt[ei[N_EDGES + e]], 1);
}

__global__ __launch_bounds__(1024) void scan_kernel(const int* __restrict__ cnt,
                                                    int* __restrict__ rowptr) {
  __shared__ int wsum[16];
  int t = threadIdx.x;
  int base = t * 10;
  int local[10];
  int s = 0;
#pragma unroll
  for (int i = 0; i < 10; ++i) {
    int v = (base + i < N_NODES) ? cnt[base + i] : 0;
    local[i] = s;
    s += v;
  }
  int lane = t & 63, wave = t >> 6;
  int inc = s;
#pragma unroll
  for (int off = 1; off < 64; off <<= 1) {
    int u = __shfl_up(inc, off, 64);
    if (lane >= off) inc += u;
  }
  if (lane == 63) wsum[wave] = inc;
  __syncthreads();
  if (t == 0) {
    int acc = 0;
#pragma unroll
    for (int w = 0; w < 16; ++w) { int v = wsum[w]; wsum[w] = acc; acc += v; }
  }
  __syncthreads();
  int excl = inc - s + wsum[wave];
#pragma unroll
  for (int i = 0; i < 10; ++i)
    if (base + i <= N_NODES) rowptr[base + i] = excl + local[i];
}

__global__ __launch_bounds__(256) void fill_kernel(const int* __restrict__ ei,
                                                   const int* __restrict__ rowptr,
                                                   int* __restrict__ cursor,
                                                   int* __restrict__ elist) {
  int e = blockIdx.x * 256 + threadIdx.x;
  if (e < N_EDGES) {
    int d = ei[N_EDGES + e];
    int p = atomicAdd(&cursor[d], 1);
    elist[rowptr[d] + p] = e;
  }
}

// ---------------- node kernel: gather (x_agg, dvec) + edge update (df), node-major ----------
// vm/s/fm streamed sequentially (CSR order); vtT/vsT as single 16B loads.
__global__ __launch_bounds__(256) void node_kernel(const __bf16* __restrict__ vm,
                                                   const __bf16* __restrict__ s,
                                                   const __bf16* __restrict__ vecw,
                                                   const __bf16* __restrict__ vtT,
                                                   const __bf16* __restrict__ vsT,
                                                   const __bf16* __restrict__ fm,
                                                   const float* __restrict__ d_ij,
                                                   const int* __restrict__ ei,
                                                   const int* __restrict__ rowptr,
                                                   const int* __restrict__ elist,
                                                   __bf16* __restrict__ x_agg,
                                                   float* __restrict__ dvec,
                                                   float* __restrict__ df) {
  int n = blockIdx.x * 2 + (threadIdx.x >> 7);
  int h = threadIdx.x & 127;
  if (n >= N_NODES) return;
  int beg = rowptr[n], end = rowptr[n + 1];

  bf16x8 vt8 = *(const bf16x8*)(vtT + (size_t)n * 1024 + h * 8);
  float vt[L];
#pragma unroll
  for (int l = 0; l < L; l++) vt[l] = (float)vt8[l];

  float ax = 0.f;
  float av[L] = {};
  for (int p = beg; p < end; ++p) {
    int e = elist[p];
    int src = ei[e];
    const float* dd = d_ij + (size_t)e * L;
    float d[L], sd2 = 0.f;
#pragma unroll
    for (int l = 0; l < L; l++) {
      d[l] = dd[l];
      sd2 += d[l] * d[l];
    }
    ax += (float)vm[(size_t)p * H + h];
    float s1 = (float)s[(size_t)p * 256 + h];
    float s2 = (float)s[(size_t)p * 256 + 128 + h];
    bf16x8 vs8 = *(const bf16x8*)(vsT + (size_t)src * 1024 + h * 8);
    const __bf16* vrow = vecw + (size_t)src * L * H + h;
    float dot = 0.f, p1 = 0.f, p2 = 0.f;
#pragma unroll
    for (int l = 0; l < L; l++) {
      float vw = (float)vrow[l * H];
      av[l] += vw * s1 + s2 * d[l];
      float bb = (float)vs8[l];
      dot += vt[l] * bb;
      p1 += vt[l] * d[l];
      p2 += bb * d[l];
    }
    float wdot = dot - p1 * p2 * (2.f - sd2);
    df[(size_t)e * H + h] = (float)fm[(size_t)p * 384 + 256 + h] * wdot;
  }
  x_agg[(size_t)n * H + h] = (__bf16)ax;
  float* drow = dvec + (size_t)n * L * H + h;
#pragma unroll
  for (int l = 0; l < L; l++) drow[l * H] = av[l];
}

// ---------------- final node update (vec3 [NL][128]) ----------------
__global__ __launch_bounds__(256) void final_kernel(const float* __restrict__ o,
                                                    const float* __restrict__ vdot,
                                                    const __bf16* __restrict__ vec3,
                                                    float* __restrict__ dx,
                                                    float* __restrict__ dvec, int n_nodes) {
  int n = blockIdx.x * 2 + (threadIdx.x >> 7);
  int h = threadIdx.x & 127;
  if (n >= n_nodes) return;
  float o1 = o[(size_t)n * 384 + h];
  float o2 = o[(size_t)n * 384 + 128 + h];
  float o3 = o[(size_t)n * 384 + 256 + h];
  dx[(size_t)n * H + h] = vdot[(size_t)n * H + h] * o2 + o3;
  float* drow = dvec + (size_t)n * L * H + h;
  const __bf16* v3 = vec3 + (size_t)n * 1024 + h;
#pragma unroll
  for (int l = 0; l < L; l++) drow[l * H] += (float)v3[l * 128] * o1;
}

extern "C" void kernel_launch(void* const* d_in, const int* in_sizes, int n_in, void* d_out,
                              int out_size, void* d_ws, size_t ws_size, hipStream_t stream) {
  const float* x = (const float*)d_in[0];
  const float* vec = (const float*)d_in[1];
  const float* f_ij = (const float*)d_in[2];
  const float* d_ij = (const float*)d_in[3];
  const float* r_ij = (const float*)d_in[4];
  const int* ei = (const int*)d_in[5];
  const float* ln_g = (const float*)d_in[6];
  const float* ln_b = (const float*)d_in[7];
  const float* vln_w = (const float*)d_in[8];
  const float* W_vec = (const float*)d_in[9];
  const float* W_q = (const float*)d_in[10];
  const float* b_q = (const float*)d_in[11];
  const float* W_k = (const float*)d_in[12];
  const float* b_k = (const float*)d_in[13];
  const float* W_v = (const float*)d_in[14];
  const float* b_v = (const float*)d_in[15];
  const float* W_dk = (const float*)d_in[16];
  const float* b_dk = (const float*)d_in[17];
  const float* W_dv = (const float*)d_in[18];
  const float* b_dv = (const float*)d_in[19];
  const float* W_s = (const float*)d_in[20];
  const float* b_s = (const float*)d_in[21];
  const float* W_f = (const float*)d_in[22];
  const float* b_f = (const float*)d_in[23];
  const float* W_src = (const float*)d_in[24];
  const float* W_trg = (const float*)d_in[25];
  const float* W_o = (const float*)d_in[26];
  const float* b_o = (const float*)d_in[27];

  float* out = (float*)d_out;
  float* dx = out;
  float* dvec = out + (size_t)N_NODES * H;
  float* df = dvec + (size_t)N_NODES * L * H;

  // ---- workspace plan (offsets in f32 slots) ----
  float* ws = (float*)d_ws;
  __bf16* vecw = (__bf16*)ws;                 // NL*128 bf16
  __bf16* vec3 = (__bf16*)(ws + 5120000);     // NL*128 bf16
  __bf16* vtT = (__bf16*)(ws + 10240000);     // N*1024 bf16 [node][h][8]
  __bf16* vsT = (__bf16*)(ws + 15360000);     // N*1024 bf16
  __bf16* fm = (__bf16*)(ws + 20480000);      // E*384 bf16 (p-order): [dk | dv | dfw]
  __bf16* vm = (__bf16*)(ws + 32768000);      // E*128 bf16 (p-order)
  __bf16* s_buf = (__bf16*)(ws + 36864000);   // E*256 bf16 (p-order)
  __bf16* qkv = (__bf16*)(ws + 45056000);     // N*384 bf16 (region reused as o_buf f32)
  __bf16* xln = (__bf16*)(ws + 48896000);     // N*128 bf16 (+tail slack)
  __bf16* xagg = (__bf16*)(ws + 49536000);    // N*128 bf16 (+tail slack)
  float* vdot = ws + 50176000;                // N*128 f32
  __bf16* Wt = (__bf16*)(ws + 51456000);      // [2048][128] bf16
  float* bqkv = ws + 51456000 + 131072;       // 384
  float* bfm = bqkv + 384;                    // 384
  int* rowptr = (int*)(bfm + 384);            // 10,001
  int* elist = rowptr + 10001;                // 64,000
  int* cnt = elist + 64000;                   // 10,000
  int* cursor = cnt + 10000;                  // 10,000
  __bf16* fijb = (__bf16*)(ws + 51800000);    // E*128 bf16 (p-order)

  float* o_buf = ws + 45056000;  // overwrites qkv after it's consumed (step 6)

  dim3 b256(256);

  // CSR build (depends only on ei)
  hipMemsetAsync(cnt, 0, N_NODES * sizeof(int), stream);
  hipMemsetAsync(cursor, 0, N_NODES * sizeof(int), stream);
  hist_kernel<<<dim3((N_EDGES + 255) / 256), b256, 0, stream>>>(ei, cnt);
  scan_kernel<<<dim3(1), dim3(1024), 0, stream>>>(cnt, rowptr);
  fill_kernel<<<dim3((N_EDGES + 255) / 256), b256, 0, stream>>>(ei, rowptr, cursor, elist);

  // 0. weight convert/transpose + bias concat; f_ij gathered into CSR order -> bf16
  wconv_kernel<<<dim3(258), b256, 0, stream>>>(W_vec, W_q, W_k, W_v, W_dk, W_dv, W_s, W_trg,
                                               W_src, W_f, W_o, b_q, b_k, b_v, b_dk, b_dv, b_f,
                                               Wt, bqkv, bfm);
  gatherf2b_kernel<<<dim3(N_EDGES / 8), b256, 0, stream>>>(f_ij, elist, fijb);
  // 1. x_ln = layernorm(x) -> bf16
  ln_kernel<<<dim3((N_NODES + 3) / 4), b256, 0, stream>>>(x, ln_g, ln_b, xln, N_NODES);
  // 2. vecw = vec * vln_w (bf16)
  vecw_kernel<<<dim3(2048), b256, 0, stream>>>(vec, vln_w, vecw, (size_t)NL * H / 8);
  // 3a. vdot (dedicated, no-spill kernel; Wt rows 0..255 = vec1|vec2)
  vdot_gemm<<<dim3(625), b256, 0, stream>>>(vecw, Wt, vdot);
  // 3b. big: vec3 + transposed vt/vs (Wt rows 256..639); XCD-swizzled, ny=3
  gemm_big<<<dim3(swz_grid(625, 3)), b256, 0, stream>>>(vecw, Wt + (size_t)256 * 128, vec3,
                                                        vtT, vsT, 625);
  // 4. qkv = xln @ [Wq|Wk|Wv] + b (bf16 out)
  gemm_v9<__bf16><<<dim3(swz_grid(79, 3)), b256, 0, stream>>>(
      xln, Wt + (size_t)640 * 128, bqkv, qkv, N_NODES, 79, 3, 384, 0);
  // 5. fm = silu(fijb @ [Wdk|Wdv|Wf] + b) (p-order rows)
  gemm_v9<__bf16><<<dim3(swz_grid(500, 3)), b256, 0, stream>>>(
      fijb, Wt + (size_t)1024 * 128, bfm, fm, N_EDGES, 500, 3, 384, 1);
  // 6. message -> vm[p] (sequential fm reads)
  msg_kernel<<<dim3(N_EDGES / 2), b256, 0, stream>>>(qkv, fm, r_ij, ei, elist, vm);
  // 7. s = silu(vm @ W_s + b) (p-order)
  gemm_v9<__bf16><<<dim3(swz_grid(500, 2)), b256, 0, stream>>>(
      vm, Wt + (size_t)1408 * 128, b_s, s_buf, N_EDGES, 500, 2, 256, 1);
  // 8. node-major: gather (x_agg, dvec) + edge update (df); vm/s/fm streamed
  node_kernel<<<dim3(N_NODES / 2), b256, 0, stream>>>(vm, s_buf, vecw, vtT, vsT, fm, d_ij, ei,
                                                      rowptr, elist, xagg, dvec, df);
  // 9. o = xagg @ W_o + b (f32 out; overwrites qkv region: consumed in 6)
  gemm_v9<float><<<dim3(swz_grid(79, 3)), b256, 0, stream>>>(
      xagg, Wt + (size_t)1664 * 128, b_o, o_buf, N_NODES, 79, 3, 384, 0);
  // 10. final: dx, dvec += vec3*o1
  final_kernel<<<dim3(5000), b256, 0, stream>>>(o_buf, vdot, vec3, dx, dvec, N_NODES);
}